// Round 1
// baseline (693.868 us; speedup 1.0000x reference)
//
#include <hip/hip_runtime.h>
#include <math.h>

// Problem constants (B=1)
#define S_LEN 2048
#define E_DIM 768
#define NH    12
#define HD    64
#define LOG_MU (-7.6246189861593985f)   // -ln(2048)
#define LN_EPS 1e-12f

// ---------------------------------------------------------------------------
// Block-wide reduction (blockDim.x == 256 -> 4 waves of 64)
template<bool IS_MAX>
__device__ __forceinline__ float block_reduce(float v, float* red) {
#pragma unroll
    for (int off = 32; off > 0; off >>= 1) {
        float o = __shfl_down(v, off, 64);
        v = IS_MAX ? fmaxf(v, o) : (v + o);
    }
    int lane = threadIdx.x & 63, w = threadIdx.x >> 6;
    __syncthreads();                 // protect shared buffer reuse across calls
    if (lane == 0) red[w] = v;
    __syncthreads();
    float r = red[0];
#pragma unroll
    for (int i = 1; i < 4; ++i) r = IS_MAX ? fmaxf(r, red[i]) : (r + red[i]);
    return r;
}

// ---------------------------------------------------------------------------
// K1: fused QKV projection.  X[S,E] @ W[E,E] + b -> head layout [H][S][D]
// grid (E/64=12, S/64=32, 3), block 256
__global__ __launch_bounds__(256) void gemm_qkv(
    const float* __restrict__ X,
    const float* __restrict__ Wq, const float* __restrict__ bq,
    const float* __restrict__ Wk, const float* __restrict__ bk,
    const float* __restrict__ Wv, const float* __restrict__ bv,
    float* __restrict__ Qo, float* __restrict__ Ko, float* __restrict__ Vo)
{
    const float* W; const float* bias; float* out;
    if (blockIdx.z == 0)      { W = Wq; bias = bq; out = Qo; }
    else if (blockIdx.z == 1) { W = Wk; bias = bk; out = Ko; }
    else                      { W = Wv; bias = bv; out = Vo; }

    const int col0 = blockIdx.x * 64;   // output channel tile (one head)
    const int row0 = blockIdx.y * 64;   // sequence tile
    __shared__ float As[16][64];        // As[k][row]
    __shared__ float Bs[16][64];        // Bs[k][col]
    const int tid = threadIdx.x;
    const int tx = tid & 15, ty = tid >> 4;
    float acc[4][4] = {};

    for (int kt = 0; kt < E_DIM; kt += 16) {
        {   // A tile (transposed into LDS)
            int r = tid >> 2, c4 = (tid & 3) * 4;
            const float4 a = *(const float4*)&X[(size_t)(row0 + r) * E_DIM + kt + c4];
            As[c4 + 0][r] = a.x; As[c4 + 1][r] = a.y;
            As[c4 + 2][r] = a.z; As[c4 + 3][r] = a.w;
        }
        {   // B tile
            int kk = tid >> 4, c4 = (tid & 15) * 4;
            *(float4*)&Bs[kk][c4] = *(const float4*)&W[(size_t)(kt + kk) * E_DIM + col0 + c4];
        }
        __syncthreads();
#pragma unroll
        for (int kk = 0; kk < 16; ++kk) {
            float4 a4 = *(float4*)&As[kk][ty * 4];
            float4 b4 = *(float4*)&Bs[kk][tx * 4];
            float a[4] = {a4.x, a4.y, a4.z, a4.w};
            float b[4] = {b4.x, b4.y, b4.z, b4.w};
#pragma unroll
            for (int i = 0; i < 4; ++i)
#pragma unroll
                for (int j = 0; j < 4; ++j) acc[i][j] += a[i] * b[j];
        }
        __syncthreads();
    }
    const int h = blockIdx.x;           // E/64 == NH
#pragma unroll
    for (int i = 0; i < 4; ++i) {
        int srow = row0 + ty * 4 + i;
        int d0 = tx * 4;
        float4 o;
        o.x = acc[i][0] + bias[col0 + d0 + 0];
        o.y = acc[i][1] + bias[col0 + d0 + 1];
        o.z = acc[i][2] + bias[col0 + d0 + 2];
        o.w = acc[i][3] + bias[col0 + d0 + 3];
        *(float4*)&out[((size_t)h * S_LEN + srow) * HD + d0] = o;
    }
}

// ---------------------------------------------------------------------------
// K2: scores[h][i][j] = (Q[h][i] . K[h][j]) / 8
// grid (S/64=32 (j), S/64=32 (i), NH), block 256
__global__ __launch_bounds__(256) void score_gemm(
    const float* __restrict__ Q, const float* __restrict__ K, float* __restrict__ Sc)
{
    const int j0 = blockIdx.x * 64;
    const int i0 = blockIdx.y * 64;
    const int h  = blockIdx.z;
    __shared__ float Qs[16][64];   // [k][i]
    __shared__ float Ks[16][64];   // [k][j]
    const int tid = threadIdx.x;
    const int tx = tid & 15, ty = tid >> 4;
    const float* Qb = Q + (size_t)h * S_LEN * HD;
    const float* Kb = K + (size_t)h * S_LEN * HD;
    float acc[4][4] = {};

    for (int dt = 0; dt < HD; dt += 16) {
        int r = tid >> 2, c4 = (tid & 3) * 4;
        {
            const float4 a = *(const float4*)&Qb[(size_t)(i0 + r) * HD + dt + c4];
            Qs[c4 + 0][r] = a.x; Qs[c4 + 1][r] = a.y;
            Qs[c4 + 2][r] = a.z; Qs[c4 + 3][r] = a.w;
        }
        {
            const float4 a = *(const float4*)&Kb[(size_t)(j0 + r) * HD + dt + c4];
            Ks[c4 + 0][r] = a.x; Ks[c4 + 1][r] = a.y;
            Ks[c4 + 2][r] = a.z; Ks[c4 + 3][r] = a.w;
        }
        __syncthreads();
#pragma unroll
        for (int kk = 0; kk < 16; ++kk) {
            float4 a4 = *(float4*)&Qs[kk][ty * 4];
            float4 b4 = *(float4*)&Ks[kk][tx * 4];
            float a[4] = {a4.x, a4.y, a4.z, a4.w};
            float b[4] = {b4.x, b4.y, b4.z, b4.w};
#pragma unroll
            for (int i = 0; i < 4; ++i)
#pragma unroll
                for (int j = 0; j < 4; ++j) acc[i][j] += a[i] * b[j];
        }
        __syncthreads();
    }
    float* out = Sc + ((size_t)h * S_LEN + i0) * S_LEN + j0;
#pragma unroll
    for (int i = 0; i < 4; ++i) {
        float4 o;
        o.x = acc[i][0] * 0.125f; o.y = acc[i][1] * 0.125f;
        o.z = acc[i][2] * 0.125f; o.w = acc[i][3] * 0.125f;
        *(float4*)&out[(size_t)(ty * 4 + i) * S_LEN + tx * 4] = o;
    }
}

// ---------------------------------------------------------------------------
// K3: u[h][i] = log_mu - LSE_j(s[h][i][j] + v[h][j]);  grid (S, NH), block 256
__global__ __launch_bounds__(256) void row_lse(
    const float* __restrict__ Sc, const float* __restrict__ vvec, float* __restrict__ u)
{
    __shared__ float red[4];
    const int i = blockIdx.x, h = blockIdx.y;
    const float* row = Sc + ((size_t)h * S_LEN + i) * S_LEN;
    const float* vh  = vvec + (size_t)h * S_LEN;
    const int t = threadIdx.x;
    float x[8];
    float m = -INFINITY;
#pragma unroll
    for (int r = 0; r < 8; ++r) {
        x[r] = row[t + r * 256] + vh[t + r * 256];
        m = fmaxf(m, x[r]);
    }
    m = block_reduce<true>(m, red);
    float l = 0.f;
#pragma unroll
    for (int r = 0; r < 8; ++r) l += __expf(x[r] - m);
    l = block_reduce<false>(l, red);
    if (t == 0) u[(size_t)h * S_LEN + i] = LOG_MU - (m + __logf(l));
}

// ---------------------------------------------------------------------------
// K4a: column-LSE partials over a 256-row chunk. grid (S/256=8, 8, NH), block 256
__global__ __launch_bounds__(256) void col_lse_part(
    const float* __restrict__ Sc, const float* __restrict__ u,
    float* __restrict__ pm, float* __restrict__ pl)
{
    const int j = blockIdx.x * 256 + threadIdx.x;
    const int chunk = blockIdx.y;
    const int h = blockIdx.z;
    const float* base = Sc + (size_t)h * S_LEN * S_LEN;
    const float* uh = u + (size_t)h * S_LEN;
    float m = -INFINITY, l = 0.f;
    const int i0 = chunk * 256;
    for (int ii = 0; ii < 256; ++ii) {
        int i = i0 + ii;
        float x = base[(size_t)i * S_LEN + j] + uh[i];
        float nm = fmaxf(m, x);
        l = l * __expf(m - nm) + __expf(x - nm);
        m = nm;
    }
    pm[((size_t)h * 8 + chunk) * S_LEN + j] = m;
    pl[((size_t)h * 8 + chunk) * S_LEN + j] = l;
}

// K4b: combine 8 partials -> v[h][j]. grid (S/256=8, NH), block 256
__global__ __launch_bounds__(256) void col_lse_combine(
    const float* __restrict__ pm, const float* __restrict__ pl, float* __restrict__ vvec)
{
    const int j = blockIdx.x * 256 + threadIdx.x;
    const int h = blockIdx.y;
    float M = -INFINITY;
#pragma unroll
    for (int c = 0; c < 8; ++c) M = fmaxf(M, pm[((size_t)h * 8 + c) * S_LEN + j]);
    float L = 0.f;
#pragma unroll
    for (int c = 0; c < 8; ++c)
        L += pl[((size_t)h * 8 + c) * S_LEN + j] * __expf(pm[((size_t)h * 8 + c) * S_LEN + j] - M);
    vvec[(size_t)h * S_LEN + j] = LOG_MU - (M + __logf(L));
}

// ---------------------------------------------------------------------------
// K5: ctx = (n * exp(s + u_i + v_j)) @ V, stored merged [s][E] (col = h*64+d)
// grid (S/64=32, NH), block 256
__global__ __launch_bounds__(256) void attn_av(
    const float* __restrict__ Sc, const float* __restrict__ u,
    const float* __restrict__ vvec, const float* __restrict__ Vh,
    float* __restrict__ ctx)
{
    const int i0 = blockIdx.x * 64;
    const int h  = blockIdx.y;
    __shared__ float Ps[16][64];   // [jj][i]  (attn tile, transposed)
    __shared__ float Vs[16][64];   // [jj][d]
    const float* sbase = Sc + (size_t)h * S_LEN * S_LEN;
    const float* uh = u + (size_t)h * S_LEN;
    const float* vh = vvec + (size_t)h * S_LEN;
    const float* Vb = Vh + (size_t)h * S_LEN * HD;
    const int tid = threadIdx.x;
    const int tx = tid & 15, ty = tid >> 4;
    float acc[4][4] = {};

    for (int jt = 0; jt < S_LEN; jt += 16) {
        {   // attn tile: exp on the fly, transposed into LDS
            int r = tid >> 2, c4 = (tid & 3) * 4;
            const float4 a = *(const float4*)&sbase[(size_t)(i0 + r) * S_LEN + jt + c4];
            float ui = uh[i0 + r];
            Ps[c4 + 0][r] = __expf(a.x + ui + vh[jt + c4 + 0]) * 2048.f;
            Ps[c4 + 1][r] = __expf(a.y + ui + vh[jt + c4 + 1]) * 2048.f;
            Ps[c4 + 2][r] = __expf(a.z + ui + vh[jt + c4 + 2]) * 2048.f;
            Ps[c4 + 3][r] = __expf(a.w + ui + vh[jt + c4 + 3]) * 2048.f;
        }
        {   // V tile
            int kk = tid >> 4, c4 = (tid & 15) * 4;
            *(float4*)&Vs[kk][c4] = *(const float4*)&Vb[(size_t)(jt + kk) * HD + c4];
        }
        __syncthreads();
#pragma unroll
        for (int kk = 0; kk < 16; ++kk) {
            float4 a4 = *(float4*)&Ps[kk][ty * 4];
            float4 b4 = *(float4*)&Vs[kk][tx * 4];
            float a[4] = {a4.x, a4.y, a4.z, a4.w};
            float b[4] = {b4.x, b4.y, b4.z, b4.w};
#pragma unroll
            for (int i = 0; i < 4; ++i)
#pragma unroll
                for (int j = 0; j < 4; ++j) acc[i][j] += a[i] * b[j];
        }
        __syncthreads();
    }
#pragma unroll
    for (int i = 0; i < 4; ++i) {
        int srow = i0 + ty * 4 + i;
        float4 o = {acc[i][0], acc[i][1], acc[i][2], acc[i][3]};
        *(float4*)&ctx[(size_t)srow * E_DIM + h * HD + tx * 4] = o;
    }
}

// ---------------------------------------------------------------------------
// K6: y = ctx @ Wo + bo + X.  grid (E/64=12, S/64=32), block 256
__global__ __launch_bounds__(256) void gemm_out(
    const float* __restrict__ Cm, const float* __restrict__ Wo,
    const float* __restrict__ bo, const float* __restrict__ X,
    float* __restrict__ Y)
{
    const int col0 = blockIdx.x * 64;
    const int row0 = blockIdx.y * 64;
    __shared__ float As[16][64];
    __shared__ float Bs[16][64];
    const int tid = threadIdx.x;
    const int tx = tid & 15, ty = tid >> 4;
    float acc[4][4] = {};

    for (int kt = 0; kt < E_DIM; kt += 16) {
        {
            int r = tid >> 2, c4 = (tid & 3) * 4;
            const float4 a = *(const float4*)&Cm[(size_t)(row0 + r) * E_DIM + kt + c4];
            As[c4 + 0][r] = a.x; As[c4 + 1][r] = a.y;
            As[c4 + 2][r] = a.z; As[c4 + 3][r] = a.w;
        }
        {
            int kk = tid >> 4, c4 = (tid & 15) * 4;
            *(float4*)&Bs[kk][c4] = *(const float4*)&Wo[(size_t)(kt + kk) * E_DIM + col0 + c4];
        }
        __syncthreads();
#pragma unroll
        for (int kk = 0; kk < 16; ++kk) {
            float4 a4 = *(float4*)&As[kk][ty * 4];
            float4 b4 = *(float4*)&Bs[kk][tx * 4];
            float a[4] = {a4.x, a4.y, a4.z, a4.w};
            float b[4] = {b4.x, b4.y, b4.z, b4.w};
#pragma unroll
            for (int i = 0; i < 4; ++i)
#pragma unroll
                for (int j = 0; j < 4; ++j) acc[i][j] += a[i] * b[j];
        }
        __syncthreads();
    }
#pragma unroll
    for (int i = 0; i < 4; ++i) {
        int srow = row0 + ty * 4 + i;
        int c0 = col0 + tx * 4;
        const float4 xr = *(const float4*)&X[(size_t)srow * E_DIM + c0];
        float4 o;
        o.x = acc[i][0] + bo[c0 + 0] + xr.x;
        o.y = acc[i][1] + bo[c0 + 1] + xr.y;
        o.z = acc[i][2] + bo[c0 + 2] + xr.z;
        o.w = acc[i][3] + bo[c0 + 3] + xr.w;
        *(float4*)&Y[(size_t)srow * E_DIM + c0] = o;
    }
}

// ---------------------------------------------------------------------------
// K7: LayerNorm per row.  grid (S), block 256 (3 elems/thread)
__global__ __launch_bounds__(256) void layernorm(
    const float* __restrict__ Y, const float* __restrict__ g,
    const float* __restrict__ b, float* __restrict__ out)
{
    __shared__ float red[4];
    const int srow = blockIdx.x;
    const float* yr = Y + (size_t)srow * E_DIM;
    const int t = threadIdx.x;
    float xs[3];
    float sum = 0.f;
#pragma unroll
    for (int r = 0; r < 3; ++r) { xs[r] = yr[t + r * 256]; sum += xs[r]; }
    sum = block_reduce<false>(sum, red);
    const float mu = sum * (1.f / 768.f);
    float vs = 0.f;
#pragma unroll
    for (int r = 0; r < 3; ++r) { float d = xs[r] - mu; vs += d * d; }
    vs = block_reduce<false>(vs, red);
    const float inv = rsqrtf(vs * (1.f / 768.f) + LN_EPS);
#pragma unroll
    for (int r = 0; r < 3; ++r) {
        int c = t + r * 256;
        out[(size_t)srow * E_DIM + c] = g[c] * (xs[r] - mu) * inv + b[c];
    }
}

// ---------------------------------------------------------------------------
extern "C" void kernel_launch(void* const* d_in, const int* in_sizes, int n_in,
                              void* d_out, int out_size, void* d_ws, size_t ws_size,
                              hipStream_t stream) {
    const float* X    = (const float*)d_in[0];
    const float* Wq   = (const float*)d_in[1];
    const float* bq   = (const float*)d_in[2];
    const float* Wk   = (const float*)d_in[3];
    const float* bk   = (const float*)d_in[4];
    const float* Wv   = (const float*)d_in[5];
    const float* bv   = (const float*)d_in[6];
    const float* Wo   = (const float*)d_in[7];
    const float* bo   = (const float*)d_in[8];
    const float* ln_g = (const float*)d_in[9];
    const float* ln_b = (const float*)d_in[10];
    float* out = (float*)d_out;

    // Workspace layout (floats). Total ~58.6M floats ~= 235 MB.
    float* ws = (float*)d_ws;
    const size_t hsd = (size_t)NH * S_LEN * HD;       // 1,572,864
    float* Q   = ws;                       // [H][S][D]
    float* K   = Q + hsd;
    float* V   = K + hsd;
    float* Sc  = V + hsd;                  // [H][S][S]  201 MB
    float* u   = Sc + (size_t)NH * S_LEN * S_LEN;   // [H][S]
    float* vv  = u + (size_t)NH * S_LEN;            // [H][S]
    float* pm  = vv + (size_t)NH * S_LEN;           // [H][8][S]
    float* pl  = pm + (size_t)NH * 8 * S_LEN;
    float* ctx = pl + (size_t)NH * 8 * S_LEN;       // [S][E]
    float* Y   = ctx + (size_t)S_LEN * E_DIM;       // [S][E]

    // v starts at zero (ws is poisoned 0xAA by the harness)
    hipMemsetAsync(vv, 0, (size_t)NH * S_LEN * sizeof(float), stream);

    gemm_qkv<<<dim3(E_DIM / 64, S_LEN / 64, 3), 256, 0, stream>>>(
        X, Wq, bq, Wk, bk, Wv, bv, Q, K, V);

    score_gemm<<<dim3(S_LEN / 64, S_LEN / 64, NH), 256, 0, stream>>>(Q, K, Sc);

    for (int it = 0; it < 3; ++it) {
        row_lse<<<dim3(S_LEN, NH), 256, 0, stream>>>(Sc, vv, u);
        col_lse_part<<<dim3(S_LEN / 256, 8, NH), 256, 0, stream>>>(Sc, u, pm, pl);
        col_lse_combine<<<dim3(S_LEN / 256, NH), 256, 0, stream>>>(pm, pl, vv);
    }

    attn_av<<<dim3(S_LEN / 64, NH), 256, 0, stream>>>(Sc, u, vv, V, ctx);

    gemm_out<<<dim3(E_DIM / 64, S_LEN / 64), 256, 0, stream>>>(ctx, Wo, bo, X, Y);

    layernorm<<<S_LEN, 256, 0, stream>>>(Y, ln_g, ln_b, out);
}

// Round 2
// 436.192 us; speedup vs baseline: 1.5907x; 1.5907x over previous
//
#include <hip/hip_runtime.h>
#include <math.h>

#define S_LEN 2048
#define E_DIM 768
#define NH    12
#define HD    64
#define MU    (1.0f/2048.0f)
#define LN_EPS 1e-12f

typedef __attribute__((ext_vector_type(8))) short bf16x8;   // 8 bf16 (4 VGPRs)
typedef __attribute__((ext_vector_type(4))) float f32x4;    // MFMA accumulator

__device__ __forceinline__ unsigned short f2bf(float f) {   // RNE fp32->bf16
    unsigned u = __float_as_uint(f);
    u += 0x7fff + ((u >> 16) & 1);
    return (unsigned short)(u >> 16);
}
__device__ __forceinline__ float bf2f(short h) {
    return __uint_as_float(((unsigned)(unsigned short)h) << 16);
}

// ---------------------------------------------------------------------------
// Quantize X -> bf16 (row-major [S][E])
__global__ __launch_bounds__(256) void quant_x(const float* __restrict__ X,
                                               unsigned short* __restrict__ Xb) {
    int i = blockIdx.x * 256 + threadIdx.x;              // one float4 per thread
    const float4 v = ((const float4*)X)[i];
    ushort4 o = { f2bf(v.x), f2bf(v.y), f2bf(v.z), f2bf(v.w) };
    ((ushort4*)Xb)[i] = o;
}

// Quantize + transpose the 4 weight matrices: W[k][n] fp32 -> Wt[z][n][k] bf16
// grid (24, 24, 4), block 256
__global__ __launch_bounds__(256) void quant_wt(
    const float* __restrict__ W0, const float* __restrict__ W1,
    const float* __restrict__ W2, const float* __restrict__ W3,
    unsigned short* __restrict__ Wt) {
    const float* W = (blockIdx.z == 0) ? W0 : (blockIdx.z == 1) ? W1
                   : (blockIdx.z == 2) ? W2 : W3;
    __shared__ unsigned short t[32][33];
    const int n0 = blockIdx.x * 32, k0 = blockIdx.y * 32;
    const int c = threadIdx.x & 31, r8 = threadIdx.x >> 5;
#pragma unroll
    for (int rr = 0; rr < 32; rr += 8) {
        int k = k0 + r8 + rr;
        t[c][r8 + rr] = f2bf(W[(size_t)k * E_DIM + n0 + c]);   // transposed into LDS
    }
    __syncthreads();
    unsigned short* out = Wt + (size_t)blockIdx.z * E_DIM * E_DIM;
#pragma unroll
    for (int rr = 0; rr < 32; rr += 8) {
        int n = n0 + r8 + rr;
        out[(size_t)n * E_DIM + k0 + c] = t[r8 + rr][c];
    }
}

// ---------------------------------------------------------------------------
// QKV projection via bf16 MFMA.  Q,K -> bf16 [H][S][64]; V -> fp32 [H][S][64]
// grid (NH, S/64, 3), block 256 (4 waves; wave w = 16 seq rows)
__global__ __launch_bounds__(256) void qkv_mfma(
    const unsigned short* __restrict__ Xb, const unsigned short* __restrict__ Wt,
    const float* __restrict__ bq, const float* __restrict__ bk, const float* __restrict__ bv,
    unsigned short* __restrict__ Qb, unsigned short* __restrict__ Kb,
    float* __restrict__ Vf) {
    const int z = blockIdx.z;
    const float* bias = (z == 0) ? bq : (z == 1) ? bk : bv;
    const int h = blockIdx.x;
    const int wave = threadIdx.x >> 6, lane = threadIdx.x & 63;
    const int q = lane >> 4, c = lane & 15;
    const int i0 = blockIdx.y * 64 + wave * 16;
    const unsigned short* Wz = Wt + (size_t)z * E_DIM * E_DIM;
    f32x4 acc[4] = {};
    for (int kt = 0; kt < E_DIM; kt += 32) {
        bf16x8 a = *(const bf16x8*)&Xb[(size_t)(i0 + c) * E_DIM + kt + q * 8];
#pragma unroll
        for (int s = 0; s < 4; ++s) {
            bf16x8 b = *(const bf16x8*)&Wz[(size_t)(h * 64 + s * 16 + c) * E_DIM + kt + q * 8];
            acc[s] = __builtin_amdgcn_mfma_f32_16x16x32_bf16(a, b, acc[s], 0, 0, 0);
        }
    }
#pragma unroll
    for (int s = 0; s < 4; ++s) {
        int d = s * 16 + c;
        float bb = bias[h * 64 + d];
#pragma unroll
        for (int r = 0; r < 4; ++r) {
            int i = i0 + q * 4 + r;
            float val = acc[s][r] + bb;
            size_t off = ((size_t)h * S_LEN + i) * HD + d;
            if (z == 0)      Qb[off] = f2bf(val);
            else if (z == 1) Kb[off] = f2bf(val);
            else             Vf[off] = val;
        }
    }
}

// ---------------------------------------------------------------------------
// E = exp(Q.K^T / 8) in bf16, via MFMA; LDS repack for 16B coalesced stores.
// grid (S/64 (j), S/64 (i), NH), block 256
__global__ __launch_bounds__(256) void score_exp(
    const unsigned short* __restrict__ Qb, const unsigned short* __restrict__ Kb,
    unsigned short* __restrict__ E) {
    const int h = blockIdx.z;
    const int i0 = blockIdx.y * 64, j0 = blockIdx.x * 64;
    const int wave = threadIdx.x >> 6, lane = threadIdx.x & 63;
    const int q = lane >> 4, c = lane & 15;
    __shared__ unsigned short Es[64][72];                 // +8 pad: conflict-free b128 reads
    const unsigned short* Qh = Qb + (size_t)h * S_LEN * HD;
    const unsigned short* Kh = Kb + (size_t)h * S_LEN * HD;
    f32x4 acc[4] = {};
#pragma unroll
    for (int dt = 0; dt < HD; dt += 32) {
        bf16x8 a = *(const bf16x8*)&Qh[(size_t)(i0 + wave * 16 + c) * HD + dt + q * 8];
#pragma unroll
        for (int s = 0; s < 4; ++s) {
            bf16x8 b = *(const bf16x8*)&Kh[(size_t)(j0 + s * 16 + c) * HD + dt + q * 8];
            acc[s] = __builtin_amdgcn_mfma_f32_16x16x32_bf16(a, b, acc[s], 0, 0, 0);
        }
    }
#pragma unroll
    for (int s = 0; s < 4; ++s)
#pragma unroll
        for (int r = 0; r < 4; ++r)
            Es[wave * 16 + q * 4 + r][s * 16 + c] = f2bf(__expf(acc[s][r] * 0.125f));
    __syncthreads();
    const int row = threadIdx.x >> 2, cc = (threadIdx.x & 3) * 16;
    unsigned short* out = E + ((size_t)h * S_LEN + i0 + row) * S_LEN + j0 + cc;
    *(bf16x8*)&out[0] = *(const bf16x8*)&Es[row][cc];
    *(bf16x8*)&out[8] = *(const bf16x8*)&Es[row][cc + 8];
}

// ---------------------------------------------------------------------------
// a[h][i] = mu / sum_j E[h][i][j] * b[h][j]   (b == ones when use_b == 0)
// grid (S/4, NH), block 256: one wave per row
__global__ __launch_bounds__(256) void row_gemv(
    const unsigned short* __restrict__ E, const float* __restrict__ bvec,
    float* __restrict__ aout, int use_b) {
    const int h = blockIdx.y;
    const int wave = threadIdx.x >> 6, lane = threadIdx.x & 63;
    const int row = blockIdx.x * 4 + wave;
    const unsigned short* er = E + ((size_t)h * S_LEN + row) * S_LEN;
    const float* bh = bvec + (size_t)h * S_LEN;
    float sum = 0.f;
#pragma unroll
    for (int ch = 0; ch < 4; ++ch) {
        int j = ch * 512 + lane * 8;
        bf16x8 e = *(const bf16x8*)&er[j];
        if (use_b) {
            float4 b0 = *(const float4*)&bh[j];
            float4 b1 = *(const float4*)&bh[j + 4];
            sum += bf2f(e[0]) * b0.x + bf2f(e[1]) * b0.y + bf2f(e[2]) * b0.z + bf2f(e[3]) * b0.w;
            sum += bf2f(e[4]) * b1.x + bf2f(e[5]) * b1.y + bf2f(e[6]) * b1.z + bf2f(e[7]) * b1.w;
        } else {
            sum += bf2f(e[0]) + bf2f(e[1]) + bf2f(e[2]) + bf2f(e[3])
                 + bf2f(e[4]) + bf2f(e[5]) + bf2f(e[6]) + bf2f(e[7]);
        }
    }
#pragma unroll
    for (int off = 32; off; off >>= 1) sum += __shfl_down(sum, off, 64);
    if (lane == 0) aout[(size_t)h * S_LEN + row] = MU / sum;
}

// ---------------------------------------------------------------------------
// Column pass partials: t[h][chunk][j] = sum_{i in chunk(32)} E[h][i][j]*a[h][i]
// grid (64, NH), block 256 (thread -> 8 consecutive j)
__global__ __launch_bounds__(256) void col_part(
    const unsigned short* __restrict__ E, const float* __restrict__ a,
    float* __restrict__ tpart) {
    const int h = blockIdx.y, chunk = blockIdx.x;
    __shared__ float la[32];
    if (threadIdx.x < 32) la[threadIdx.x] = a[(size_t)h * S_LEN + chunk * 32 + threadIdx.x];
    __syncthreads();
    const int j0 = threadIdx.x * 8;
    const unsigned short* eb = E + ((size_t)h * S_LEN + chunk * 32) * S_LEN + j0;
    float acc[8] = {};
    for (int ii = 0; ii < 32; ++ii) {
        float ai = la[ii];                                // LDS broadcast (free)
        bf16x8 e = *(const bf16x8*)&eb[(size_t)ii * S_LEN];
#pragma unroll
        for (int k = 0; k < 8; ++k) acc[k] += bf2f(e[k]) * ai;
    }
    float* out = tpart + ((size_t)h * 64 + chunk) * S_LEN + j0;
    float4 o0 = {acc[0], acc[1], acc[2], acc[3]};
    float4 o1 = {acc[4], acc[5], acc[6], acc[7]};
    *(float4*)&out[0] = o0;  *(float4*)&out[4] = o1;
}

// b[h][j] = mu / sum_chunk t[h][chunk][j].  grid (NH*S/256), block 256
__global__ __launch_bounds__(256) void col_combine(
    const float* __restrict__ tpart, float* __restrict__ bout) {
    int g = blockIdx.x * 256 + threadIdx.x;
    int h = g >> 11, j = g & 2047;
    float s = 0.f;
#pragma unroll 8
    for (int c = 0; c < 64; ++c) s += tpart[((size_t)h * 64 + c) * S_LEN + j];
    bout[g] = MU / s;
}

// ---------------------------------------------------------------------------
// V't[h][d][j] = bf16( b[h][j] * V[h][j][d] )   (transposed for MFMA B-operand)
// grid (S/64, NH), block 256
__global__ __launch_bounds__(256) void scale_v(
    const float* __restrict__ Vf, const float* __restrict__ b,
    unsigned short* __restrict__ Vt) {
    const int h = blockIdx.y, j0 = blockIdx.x * 64;
    __shared__ unsigned short t[64][72];
    {
        const int r = threadIdx.x >> 2, dc = (threadIdx.x & 3) * 16;
        float bj = b[(size_t)h * S_LEN + j0 + r];
        const float* vrow = Vf + ((size_t)h * S_LEN + j0 + r) * HD + dc;
#pragma unroll
        for (int k = 0; k < 16; ++k) t[dc + k][r] = f2bf(vrow[k] * bj);
    }
    __syncthreads();
    const int d = threadIdx.x >> 2, jc = (threadIdx.x & 3) * 16;
    unsigned short* out = Vt + ((size_t)h * HD + d) * S_LEN + j0 + jc;
    *(bf16x8*)&out[0] = *(const bf16x8*)&t[d][jc];
    *(bf16x8*)&out[8] = *(const bf16x8*)&t[d][jc + 8];
}

// ---------------------------------------------------------------------------
// ctx_bf16[i][h*64+d] = a_i * n * sum_j E[h][i][j] * V't[h][d][j]  (MFMA)
// grid (S/64, NH), block 256
__global__ __launch_bounds__(256) void attn_av(
    const unsigned short* __restrict__ E, const float* __restrict__ a,
    const unsigned short* __restrict__ Vt, unsigned short* __restrict__ ctxb) {
    const int h = blockIdx.y;
    const int wave = threadIdx.x >> 6, lane = threadIdx.x & 63;
    const int q = lane >> 4, c = lane & 15;
    const int i0 = blockIdx.x * 64 + wave * 16;
    const unsigned short* Eh = E + (size_t)h * S_LEN * S_LEN;
    const unsigned short* Vh = Vt + (size_t)h * HD * S_LEN;
    f32x4 acc[4] = {};
    for (int jt = 0; jt < S_LEN; jt += 32) {
        bf16x8 av = *(const bf16x8*)&Eh[(size_t)(i0 + c) * S_LEN + jt + q * 8];
#pragma unroll
        for (int s = 0; s < 4; ++s) {
            bf16x8 bv = *(const bf16x8*)&Vh[(size_t)(s * 16 + c) * S_LEN + jt + q * 8];
            acc[s] = __builtin_amdgcn_mfma_f32_16x16x32_bf16(av, bv, acc[s], 0, 0, 0);
        }
    }
    float ais[4];
#pragma unroll
    for (int r = 0; r < 4; ++r) ais[r] = a[(size_t)h * S_LEN + i0 + q * 4 + r] * 2048.f;
#pragma unroll
    for (int s = 0; s < 4; ++s)
#pragma unroll
        for (int r = 0; r < 4; ++r) {
            int i = i0 + q * 4 + r;
            ctxb[(size_t)i * E_DIM + h * 64 + s * 16 + c] = f2bf(acc[s][r] * ais[r]);
        }
}

// ---------------------------------------------------------------------------
// Y = ctx @ Wo + bo + X (fp32), via MFMA.  grid (E/64, S/64), block 256
__global__ __launch_bounds__(256) void out_mfma(
    const unsigned short* __restrict__ ctxb, const unsigned short* __restrict__ Wt,
    const float* __restrict__ bo, const float* __restrict__ X, float* __restrict__ Y) {
    const int n0 = blockIdx.x * 64;
    const int wave = threadIdx.x >> 6, lane = threadIdx.x & 63;
    const int q = lane >> 4, c = lane & 15;
    const int i0 = blockIdx.y * 64 + wave * 16;
    const unsigned short* Wo3 = Wt + (size_t)3 * E_DIM * E_DIM;
    f32x4 acc[4] = {};
    for (int kt = 0; kt < E_DIM; kt += 32) {
        bf16x8 a = *(const bf16x8*)&ctxb[(size_t)(i0 + c) * E_DIM + kt + q * 8];
#pragma unroll
        for (int s = 0; s < 4; ++s) {
            bf16x8 b = *(const bf16x8*)&Wo3[(size_t)(n0 + s * 16 + c) * E_DIM + kt + q * 8];
            acc[s] = __builtin_amdgcn_mfma_f32_16x16x32_bf16(a, b, acc[s], 0, 0, 0);
        }
    }
#pragma unroll
    for (int s = 0; s < 4; ++s) {
        int n = n0 + s * 16 + c;
        float bn = bo[n];
#pragma unroll
        for (int r = 0; r < 4; ++r) {
            int i = i0 + q * 4 + r;
            Y[(size_t)i * E_DIM + n] = acc[s][r] + bn + X[(size_t)i * E_DIM + n];
        }
    }
}

// ---------------------------------------------------------------------------
// LayerNorm per row.  grid (S), block 256 (3 elems/thread)
__global__ __launch_bounds__(256) void layernorm(
    const float* __restrict__ Y, const float* __restrict__ g,
    const float* __restrict__ b, float* __restrict__ out) {
    __shared__ float red[4];
    const int srow = blockIdx.x;
    const float* yr = Y + (size_t)srow * E_DIM;
    const int t = threadIdx.x;
    float xs[3];
    float sum = 0.f;
#pragma unroll
    for (int r = 0; r < 3; ++r) { xs[r] = yr[t + r * 256]; sum += xs[r]; }
#pragma unroll
    for (int off = 32; off; off >>= 1) sum += __shfl_down(sum, off, 64);
    if ((t & 63) == 0) red[t >> 6] = sum;
    __syncthreads();
    sum = red[0] + red[1] + red[2] + red[3];
    const float mu = sum * (1.f / 768.f);
    float vs = 0.f;
#pragma unroll
    for (int r = 0; r < 3; ++r) { float d = xs[r] - mu; vs += d * d; }
    __syncthreads();
#pragma unroll
    for (int off = 32; off; off >>= 1) vs += __shfl_down(vs, off, 64);
    if ((t & 63) == 0) red[t >> 6] = vs;
    __syncthreads();
    vs = red[0] + red[1] + red[2] + red[3];
    const float inv = rsqrtf(vs * (1.f / 768.f) + LN_EPS);
#pragma unroll
    for (int r = 0; r < 3; ++r) {
        int c = t + r * 256;
        out[(size_t)srow * E_DIM + c] = g[c] * (xs[r] - mu) * inv + b[c];
    }
}

// ---------------------------------------------------------------------------
extern "C" void kernel_launch(void* const* d_in, const int* in_sizes, int n_in,
                              void* d_out, int out_size, void* d_ws, size_t ws_size,
                              hipStream_t stream) {
    const float* X    = (const float*)d_in[0];
    const float* Wq   = (const float*)d_in[1];
    const float* bq   = (const float*)d_in[2];
    const float* Wk   = (const float*)d_in[3];
    const float* bk   = (const float*)d_in[4];
    const float* Wv   = (const float*)d_in[5];
    const float* bv   = (const float*)d_in[6];
    const float* Wo   = (const float*)d_in[7];
    const float* bo   = (const float*)d_in[8];
    const float* ln_g = (const float*)d_in[9];
    const float* ln_b = (const float*)d_in[10];
    float* out = (float*)d_out;

    // Workspace carve-up (256B aligned), total ~140 MB
    char* p = (char*)d_ws;
    auto alloc = [&](size_t bytes) { char* r = p; p += (bytes + 255) & ~(size_t)255; return r; };
    unsigned short* Xb   = (unsigned short*)alloc((size_t)S_LEN * E_DIM * 2);
    unsigned short* Wt   = (unsigned short*)alloc((size_t)4 * E_DIM * E_DIM * 2);
    unsigned short* Qb   = (unsigned short*)alloc((size_t)NH * S_LEN * HD * 2);
    unsigned short* Kb   = (unsigned short*)alloc((size_t)NH * S_LEN * HD * 2);
    float*          Vf   = (float*)alloc((size_t)NH * S_LEN * HD * 4);
    unsigned short* E    = (unsigned short*)alloc((size_t)NH * S_LEN * S_LEN * 2);
    float*          av   = (float*)alloc((size_t)NH * S_LEN * 4);
    float*          bv_  = (float*)alloc((size_t)NH * S_LEN * 4);
    float*          tp   = (float*)alloc((size_t)NH * 64 * S_LEN * 4);
    unsigned short* Vt   = (unsigned short*)alloc((size_t)NH * HD * S_LEN * 2);
    unsigned short* ctxb = (unsigned short*)alloc((size_t)S_LEN * E_DIM * 2);
    float*          Y    = (float*)alloc((size_t)S_LEN * E_DIM * 4);

    quant_x<<<S_LEN * E_DIM / 1024, 256, 0, stream>>>(X, Xb);
    quant_wt<<<dim3(24, 24, 4), 256, 0, stream>>>(Wq, Wk, Wv, Wo, Wt);
    qkv_mfma<<<dim3(NH, S_LEN / 64, 3), 256, 0, stream>>>(Xb, Wt, bq, bk, bv, Qb, Kb, Vf);
    score_exp<<<dim3(S_LEN / 64, S_LEN / 64, NH), 256, 0, stream>>>(Qb, Kb, E);

    // Sinkhorn: u,v,u,v,u,v  (multiplicative domain)
    row_gemv<<<dim3(S_LEN / 4, NH), 256, 0, stream>>>(E, bv_, av, 0);   // a1 (b=1)
    col_part<<<dim3(64, NH), 256, 0, stream>>>(E, av, tp);
    col_combine<<<NH * S_LEN / 256, 256, 0, stream>>>(tp, bv_);         // b1
    row_gemv<<<dim3(S_LEN / 4, NH), 256, 0, stream>>>(E, bv_, av, 1);   // a2
    col_part<<<dim3(64, NH), 256, 0, stream>>>(E, av, tp);
    col_combine<<<NH * S_LEN / 256, 256, 0, stream>>>(tp, bv_);         // b2
    row_gemv<<<dim3(S_LEN / 4, NH), 256, 0, stream>>>(E, bv_, av, 1);   // a3
    col_part<<<dim3(64, NH), 256, 0, stream>>>(E, av, tp);
    col_combine<<<NH * S_LEN / 256, 256, 0, stream>>>(tp, bv_);         // b3

    scale_v<<<dim3(S_LEN / 64, NH), 256, 0, stream>>>(Vf, bv_, Vt);
    attn_av<<<dim3(S_LEN / 64, NH), 256, 0, stream>>>(E, av, Vt, ctxb);
    out_mfma<<<dim3(E_DIM / 64, S_LEN / 64), 256, 0, stream>>>(ctxb, Wt, bo, X, Y);
    layernorm<<<S_LEN, 256, 0, stream>>>(Y, ln_g, ln_b, out);
}

// Round 3
// 387.872 us; speedup vs baseline: 1.7889x; 1.1246x over previous
//
#include <hip/hip_runtime.h>
#include <math.h>

#define S_LEN 2048
#define E_DIM 768
#define NH    12
#define HD    64
#define MU    (1.0f/2048.0f)
#define LN_EPS 1e-12f

typedef __attribute__((ext_vector_type(8))) short bf16x8;   // 8 bf16 (4 VGPRs)
typedef __attribute__((ext_vector_type(4))) float f32x4;    // MFMA accumulator
typedef __attribute__((ext_vector_type(2))) float f32x2;
typedef long i64_t;                                          // 8 fp8 (2 VGPRs)

__device__ __forceinline__ unsigned short f2bf(float f) {   // RNE fp32->bf16
    unsigned u = __float_as_uint(f);
    u += 0x7fff + ((u >> 16) & 1);
    return (unsigned short)(u >> 16);
}

// ---- fp8 e4m3 (OCP) helpers: HW cvt when available, bit-trick fallback ----
__device__ __forceinline__ unsigned char fp8_enc(float f) {
#if __has_builtin(__builtin_amdgcn_cvt_pk_fp8_f32)
    return (unsigned char)(__builtin_amdgcn_cvt_pk_fp8_f32(f, f, 0, false) & 0xFF);
#else
    float m = fminf(fabsf(f), 448.f) * 0x1p-120f;
    unsigned b = __float_as_uint(m);
    unsigned s = (__float_as_uint(f) >> 24) & 0x80u;
    b += 0x7FFFFu + ((b >> 20) & 1u);
    return (unsigned char)(s | ((b >> 20) & 0x7Fu));
#endif
}
__device__ __forceinline__ float fp8_dec1(unsigned char u) {
    unsigned bits = ((u & 0x80u) << 24) | ((u & 0x7Fu) << 20);
    return __uint_as_float(bits) * 0x1p+120f;
}
__device__ __forceinline__ f32x2 fp8_dec_lo(unsigned v) {
#if __has_builtin(__builtin_amdgcn_cvt_pk_f32_fp8)
    return __builtin_amdgcn_cvt_pk_f32_fp8(v, false);
#else
    f32x2 r; r.x = fp8_dec1(v & 0xFF); r.y = fp8_dec1((v >> 8) & 0xFF); return r;
#endif
}
__device__ __forceinline__ f32x2 fp8_dec_hi(unsigned v) {
#if __has_builtin(__builtin_amdgcn_cvt_pk_f32_fp8)
    return __builtin_amdgcn_cvt_pk_f32_fp8(v, true);
#else
    f32x2 r; r.x = fp8_dec1((v >> 16) & 0xFF); r.y = fp8_dec1(v >> 24); return r;
#endif
}

// ---------------------------------------------------------------------------
__global__ __launch_bounds__(256) void quant_x(const float* __restrict__ X,
                                               unsigned short* __restrict__ Xb) {
    int i = blockIdx.x * 256 + threadIdx.x;
    const float4 v = ((const float4*)X)[i];
    ushort4 o = { f2bf(v.x), f2bf(v.y), f2bf(v.z), f2bf(v.w) };
    ((ushort4*)Xb)[i] = o;
}

// W[k][n] fp32 -> Wt[z][n][k] bf16.  grid (24,24,4), block 256
__global__ __launch_bounds__(256) void quant_wt(
    const float* __restrict__ W0, const float* __restrict__ W1,
    const float* __restrict__ W2, const float* __restrict__ W3,
    unsigned short* __restrict__ Wt) {
    const float* W = (blockIdx.z == 0) ? W0 : (blockIdx.z == 1) ? W1
                   : (blockIdx.z == 2) ? W2 : W3;
    __shared__ unsigned short t[32][33];
    const int n0 = blockIdx.x * 32, k0 = blockIdx.y * 32;
    const int c = threadIdx.x & 31, r8 = threadIdx.x >> 5;
#pragma unroll
    for (int rr = 0; rr < 32; rr += 8) {
        int k = k0 + r8 + rr;
        t[c][r8 + rr] = f2bf(W[(size_t)k * E_DIM + n0 + c]);
    }
    __syncthreads();
    unsigned short* out = Wt + (size_t)blockIdx.z * E_DIM * E_DIM;
#pragma unroll
    for (int rr = 0; rr < 32; rr += 8) {
        int n = n0 + r8 + rr;
        out[(size_t)n * E_DIM + k0 + c] = t[r8 + rr][c];
    }
}

// ---------------------------------------------------------------------------
// QKV via bf16 MFMA.  Q,K -> bf16 [H][S][64]; V -> fp32 [H][S][64]
// grid (NH, S/64, 3), block 256
__global__ __launch_bounds__(256) void qkv_mfma(
    const unsigned short* __restrict__ Xb, const unsigned short* __restrict__ Wt,
    const float* __restrict__ bq, const float* __restrict__ bk, const float* __restrict__ bv,
    unsigned short* __restrict__ Qb, unsigned short* __restrict__ Kb,
    float* __restrict__ Vf) {
    const int z = blockIdx.z;
    const float* bias = (z == 0) ? bq : (z == 1) ? bk : bv;
    const int h = blockIdx.x;
    const int wave = threadIdx.x >> 6, lane = threadIdx.x & 63;
    const int q = lane >> 4, c = lane & 15;
    const int i0 = blockIdx.y * 64 + wave * 16;
    const unsigned short* Wz = Wt + (size_t)z * E_DIM * E_DIM;
    f32x4 acc[4] = {};
    for (int kt = 0; kt < E_DIM; kt += 32) {
        bf16x8 a = *(const bf16x8*)&Xb[(size_t)(i0 + c) * E_DIM + kt + q * 8];
#pragma unroll
        for (int s = 0; s < 4; ++s) {
            bf16x8 b = *(const bf16x8*)&Wz[(size_t)(h * 64 + s * 16 + c) * E_DIM + kt + q * 8];
            acc[s] = __builtin_amdgcn_mfma_f32_16x16x32_bf16(a, b, acc[s], 0, 0, 0);
        }
    }
#pragma unroll
    for (int s = 0; s < 4; ++s) {
        int d = s * 16 + c;
        float bb = bias[h * 64 + d];
#pragma unroll
        for (int r = 0; r < 4; ++r) {
            int i = i0 + q * 4 + r;
            float val = acc[s][r] + bb;
            size_t off = ((size_t)h * S_LEN + i) * HD + d;
            if (z == 0)      Qb[off] = f2bf(val);
            else if (z == 1) Kb[off] = f2bf(val);
            else             Vf[off] = val;
        }
    }
}

// ---------------------------------------------------------------------------
// E = exp(Q.K^T/8) -> fp8 e4m3.  grid (S/64 (j), S/64 (i), NH), block 256
__global__ __launch_bounds__(256) void score_exp(
    const unsigned short* __restrict__ Qb, const unsigned short* __restrict__ Kb,
    unsigned char* __restrict__ E) {
    const int h = blockIdx.z;
    const int i0 = blockIdx.y * 64, j0 = blockIdx.x * 64;
    const int wave = threadIdx.x >> 6, lane = threadIdx.x & 63;
    const int q = lane >> 4, c = lane & 15;
    __shared__ unsigned char Es[64][80];          // 80B rows: 16B-aligned, spread banks
    const unsigned short* Qh = Qb + (size_t)h * S_LEN * HD;
    const unsigned short* Kh = Kb + (size_t)h * S_LEN * HD;
    f32x4 acc[4] = {};
#pragma unroll
    for (int dt = 0; dt < HD; dt += 32) {
        bf16x8 a = *(const bf16x8*)&Qh[(size_t)(i0 + wave * 16 + c) * HD + dt + q * 8];
#pragma unroll
        for (int s = 0; s < 4; ++s) {
            bf16x8 b = *(const bf16x8*)&Kh[(size_t)(j0 + s * 16 + c) * HD + dt + q * 8];
            acc[s] = __builtin_amdgcn_mfma_f32_16x16x32_bf16(a, b, acc[s], 0, 0, 0);
        }
    }
#pragma unroll
    for (int s = 0; s < 4; ++s)
#pragma unroll
        for (int r = 0; r < 4; ++r)
            Es[wave * 16 + q * 4 + r][s * 16 + c] = fp8_enc(__expf(acc[s][r] * 0.125f));
    __syncthreads();
    const int row = threadIdx.x >> 2, cc = (threadIdx.x & 3) * 16;
    unsigned char* out = E + ((size_t)h * S_LEN + i0 + row) * S_LEN + j0 + cc;
    *(uint4*)out = *(const uint4*)&Es[row][cc];
}

// ---------------------------------------------------------------------------
// a[h][i] = mu / sum_j E[h][i][j]*b[h][j].  grid (S/4, NH), block 256 (wave/row)
__global__ __launch_bounds__(256) void row_gemv(
    const unsigned char* __restrict__ E, const float* __restrict__ bvec,
    float* __restrict__ aout, int use_b) {
    const int h = blockIdx.y;
    const int wave = threadIdx.x >> 6, lane = threadIdx.x & 63;
    const int row = blockIdx.x * 4 + wave;
    const unsigned char* er = E + ((size_t)h * S_LEN + row) * S_LEN;
    const float* bh = bvec + (size_t)h * S_LEN;
    float sum = 0.f;
#pragma unroll
    for (int ch = 0; ch < 2; ++ch) {
        int j = ch * 1024 + lane * 16;
        uint4 e = *(const uint4*)&er[j];
        unsigned w[4] = {e.x, e.y, e.z, e.w};
#pragma unroll
        for (int k = 0; k < 4; ++k) {
            f32x2 lo = fp8_dec_lo(w[k]), hi = fp8_dec_hi(w[k]);
            if (use_b) {
                float4 b0 = *(const float4*)&bh[j + k * 4];
                sum += lo.x * b0.x + lo.y * b0.y + hi.x * b0.z + hi.y * b0.w;
            } else {
                sum += (lo.x + lo.y) + (hi.x + hi.y);
            }
        }
    }
#pragma unroll
    for (int off = 32; off; off >>= 1) sum += __shfl_down(sum, off, 64);
    if (lane == 0) aout[(size_t)h * S_LEN + row] = MU / sum;
}

// ---------------------------------------------------------------------------
// tp[h][chunk][j] = sum_{i in 32-row chunk} E[h][i][j]*a[h][i]
// grid (64, NH), block 128 (thread -> 16 consecutive j)
__global__ __launch_bounds__(128) void col_part(
    const unsigned char* __restrict__ E, const float* __restrict__ a,
    float* __restrict__ tpart) {
    const int h = blockIdx.y, chunk = blockIdx.x;
    __shared__ float la[32];
    if (threadIdx.x < 32) la[threadIdx.x] = a[(size_t)h * S_LEN + chunk * 32 + threadIdx.x];
    __syncthreads();
    const int j0 = threadIdx.x * 16;
    const unsigned char* eb = E + ((size_t)h * S_LEN + chunk * 32) * S_LEN + j0;
    float acc[16] = {};
    for (int ii = 0; ii < 32; ++ii) {
        float ai = la[ii];
        uint4 e = *(const uint4*)&eb[(size_t)ii * S_LEN];
        unsigned w[4] = {e.x, e.y, e.z, e.w};
#pragma unroll
        for (int k = 0; k < 4; ++k) {
            f32x2 lo = fp8_dec_lo(w[k]), hi = fp8_dec_hi(w[k]);
            acc[k * 4 + 0] += lo.x * ai; acc[k * 4 + 1] += lo.y * ai;
            acc[k * 4 + 2] += hi.x * ai; acc[k * 4 + 3] += hi.y * ai;
        }
    }
    float* outp = tpart + ((size_t)h * 64 + chunk) * S_LEN + j0;
#pragma unroll
    for (int k = 0; k < 4; ++k) {
        float4 o = {acc[k * 4], acc[k * 4 + 1], acc[k * 4 + 2], acc[k * 4 + 3]};
        *(float4*)&outp[k * 4] = o;
    }
}

// b[h][j] = mu / sum_chunk tp.  grid (NH*S/256), block 256
__global__ __launch_bounds__(256) void col_combine(
    const float* __restrict__ tpart, float* __restrict__ bout) {
    int g = blockIdx.x * 256 + threadIdx.x;
    int h = g >> 11, j = g & 2047;
    float s = 0.f;
#pragma unroll 8
    for (int c = 0; c < 64; ++c) s += tpart[((size_t)h * 64 + c) * S_LEN + j];
    bout[g] = MU / s;
}

// ---------------------------------------------------------------------------
// V't[h][d][j] = fp8( b[h][j] * V[h][j][d] )  grid (S/64, NH), block 256
__global__ __launch_bounds__(256) void scale_v(
    const float* __restrict__ Vf, const float* __restrict__ b,
    unsigned char* __restrict__ Vt) {
    const int h = blockIdx.y, j0 = blockIdx.x * 64;
    __shared__ unsigned char t[64][80];
    {
        const int r = threadIdx.x >> 2, dc = (threadIdx.x & 3) * 16;
        float bj = b[(size_t)h * S_LEN + j0 + r];
        const float* vrow = Vf + ((size_t)h * S_LEN + j0 + r) * HD + dc;
#pragma unroll
        for (int k = 0; k < 16; ++k) t[dc + k][r] = fp8_enc(vrow[k] * bj);
    }
    __syncthreads();
    const int d = threadIdx.x >> 2, jc = (threadIdx.x & 3) * 16;
    unsigned char* out = Vt + ((size_t)h * HD + d) * S_LEN + j0 + jc;
    *(uint4*)out = *(const uint4*)&t[d][jc];
}

// ---------------------------------------------------------------------------
// ctx[i][h*64+d] = a_i*n * sum_j E[h][i][j]*V't[h][d][j], fp8 MFMA, j-split.
// grid (S/32, NH), block 256: wave = (rt: row-tile 16, jh: j-half 1024)
__global__ __launch_bounds__(256) void attn_av(
    const unsigned char* __restrict__ E, const float* __restrict__ a,
    const unsigned char* __restrict__ Vt, unsigned short* __restrict__ ctxb) {
    const int h = blockIdx.y;
    const int wave = threadIdx.x >> 6, lane = threadIdx.x & 63;
    const int rt = wave & 1, jh = wave >> 1;
    const int q = lane >> 4, c = lane & 15;
    const int i0 = blockIdx.x * 32 + rt * 16;
    const unsigned char* Eh = E + (size_t)h * S_LEN * S_LEN;
    const unsigned char* Vh = Vt + (size_t)h * HD * S_LEN;
    f32x4 acc[4] = {};
    const int jbase = jh * 1024;
    for (int jt = jbase; jt < jbase + 1024; jt += 32) {
        i64_t av = *(const i64_t*)&Eh[(size_t)(i0 + c) * S_LEN + jt + q * 8];
#pragma unroll
        for (int s = 0; s < 4; ++s) {
            i64_t bv = *(const i64_t*)&Vh[(size_t)(s * 16 + c) * S_LEN + jt + q * 8];
            acc[s] = __builtin_amdgcn_mfma_f32_16x16x32_fp8_fp8(av, bv, acc[s], 0, 0, 0);
        }
    }
    __shared__ float lred[2][16][64];
    if (jh == 1) {
#pragma unroll
        for (int s = 0; s < 4; ++s)
#pragma unroll
            for (int r = 0; r < 4; ++r) lred[rt][s * 4 + r][lane] = acc[s][r];
    }
    __syncthreads();
    if (jh == 0) {
        float ais[4];
#pragma unroll
        for (int r = 0; r < 4; ++r) ais[r] = a[(size_t)h * S_LEN + i0 + q * 4 + r] * 2048.f;
#pragma unroll
        for (int s = 0; s < 4; ++s)
#pragma unroll
            for (int r = 0; r < 4; ++r) {
                float v = (acc[s][r] + lred[rt][s * 4 + r][lane]) * ais[r];
                ctxb[(size_t)(i0 + q * 4 + r) * E_DIM + h * 64 + s * 16 + c] = f2bf(v);
            }
    }
}

// ---------------------------------------------------------------------------
// Y = ctx @ Wo + bo + X (fp32).  grid (E/64, S/64), block 256
__global__ __launch_bounds__(256) void out_mfma(
    const unsigned short* __restrict__ ctxb, const unsigned short* __restrict__ Wt,
    const float* __restrict__ bo, const float* __restrict__ X, float* __restrict__ Y) {
    const int n0 = blockIdx.x * 64;
    const int wave = threadIdx.x >> 6, lane = threadIdx.x & 63;
    const int q = lane >> 4, c = lane & 15;
    const int i0 = blockIdx.y * 64 + wave * 16;
    const unsigned short* Wo3 = Wt + (size_t)3 * E_DIM * E_DIM;
    f32x4 acc[4] = {};
    for (int kt = 0; kt < E_DIM; kt += 32) {
        bf16x8 a = *(const bf16x8*)&ctxb[(size_t)(i0 + c) * E_DIM + kt + q * 8];
#pragma unroll
        for (int s = 0; s < 4; ++s) {
            bf16x8 b = *(const bf16x8*)&Wo3[(size_t)(n0 + s * 16 + c) * E_DIM + kt + q * 8];
            acc[s] = __builtin_amdgcn_mfma_f32_16x16x32_bf16(a, b, acc[s], 0, 0, 0);
        }
    }
#pragma unroll
    for (int s = 0; s < 4; ++s) {
        int n = n0 + s * 16 + c;
        float bn = bo[n];
#pragma unroll
        for (int r = 0; r < 4; ++r) {
            int i = i0 + q * 4 + r;
            Y[(size_t)i * E_DIM + n] = acc[s][r] + bn + X[(size_t)i * E_DIM + n];
        }
    }
}

// ---------------------------------------------------------------------------
// LayerNorm per row.  grid (S), block 256
__global__ __launch_bounds__(256) void layernorm(
    const float* __restrict__ Y, const float* __restrict__ g,
    const float* __restrict__ b, float* __restrict__ out) {
    __shared__ float red[4];
    const int srow = blockIdx.x;
    const float* yr = Y + (size_t)srow * E_DIM;
    const int t = threadIdx.x;
    float xs[3];
    float sum = 0.f;
#pragma unroll
    for (int r = 0; r < 3; ++r) { xs[r] = yr[t + r * 256]; sum += xs[r]; }
#pragma unroll
    for (int off = 32; off; off >>= 1) sum += __shfl_down(sum, off, 64);
    if ((t & 63) == 0) red[t >> 6] = sum;
    __syncthreads();
    sum = red[0] + red[1] + red[2] + red[3];
    const float mu = sum * (1.f / 768.f);
    float vs = 0.f;
#pragma unroll
    for (int r = 0; r < 3; ++r) { float d = xs[r] - mu; vs += d * d; }
    __syncthreads();
#pragma unroll
    for (int off = 32; off; off >>= 1) vs += __shfl_down(vs, off, 64);
    if ((t & 63) == 0) red[t >> 6] = vs;
    __syncthreads();
    vs = red[0] + red[1] + red[2] + red[3];
    const float inv = rsqrtf(vs * (1.f / 768.f) + LN_EPS);
#pragma unroll
    for (int r = 0; r < 3; ++r) {
        int c = t + r * 256;
        out[(size_t)srow * E_DIM + c] = g[c] * (xs[r] - mu) * inv + b[c];
    }
}

// ---------------------------------------------------------------------------
extern "C" void kernel_launch(void* const* d_in, const int* in_sizes, int n_in,
                              void* d_out, int out_size, void* d_ws, size_t ws_size,
                              hipStream_t stream) {
    const float* X    = (const float*)d_in[0];
    const float* Wq   = (const float*)d_in[1];
    const float* bq   = (const float*)d_in[2];
    const float* Wk   = (const float*)d_in[3];
    const float* bk   = (const float*)d_in[4];
    const float* Wv   = (const float*)d_in[5];
    const float* bv   = (const float*)d_in[6];
    const float* Wo   = (const float*)d_in[7];
    const float* bo   = (const float*)d_in[8];
    const float* ln_g = (const float*)d_in[9];
    const float* ln_b = (const float*)d_in[10];
    float* out = (float*)d_out;

    char* p = (char*)d_ws;
    auto alloc = [&](size_t bytes) { char* r = p; p += (bytes + 255) & ~(size_t)255; return r; };
    unsigned short* Xb   = (unsigned short*)alloc((size_t)S_LEN * E_DIM * 2);
    unsigned short* Wt   = (unsigned short*)alloc((size_t)4 * E_DIM * E_DIM * 2);
    unsigned short* Qb   = (unsigned short*)alloc((size_t)NH * S_LEN * HD * 2);
    unsigned short* Kb   = (unsigned short*)alloc((size_t)NH * S_LEN * HD * 2);
    float*          Vf   = (float*)alloc((size_t)NH * S_LEN * HD * 4);
    unsigned char*  E    = (unsigned char*)alloc((size_t)NH * S_LEN * S_LEN);   // 50 MB fp8
    float*          av   = (float*)alloc((size_t)NH * S_LEN * 4);
    float*          bv_  = (float*)alloc((size_t)NH * S_LEN * 4);
    float*          tp   = (float*)alloc((size_t)NH * 64 * S_LEN * 4);
    unsigned char*  Vt   = (unsigned char*)alloc((size_t)NH * HD * S_LEN);
    unsigned short* ctxb = (unsigned short*)alloc((size_t)S_LEN * E_DIM * 2);
    float*          Y    = (float*)alloc((size_t)S_LEN * E_DIM * 4);

    quant_x<<<S_LEN * E_DIM / 1024, 256, 0, stream>>>(X, Xb);
    quant_wt<<<dim3(24, 24, 4), 256, 0, stream>>>(Wq, Wk, Wv, Wo, Wt);
    qkv_mfma<<<dim3(NH, S_LEN / 64, 3), 256, 0, stream>>>(Xb, Wt, bq, bk, bv, Qb, Kb, Vf);
    score_exp<<<dim3(S_LEN / 64, S_LEN / 64, NH), 256, 0, stream>>>(Qb, Kb, E);

    // Sinkhorn (multiplicative): a1,b1,a2,b2,a3,b3
    row_gemv<<<dim3(S_LEN / 4, NH), 256, 0, stream>>>(E, bv_, av, 0);
    col_part<<<dim3(64, NH), 128, 0, stream>>>(E, av, tp);
    col_combine<<<NH * S_LEN / 256, 256, 0, stream>>>(tp, bv_);
    row_gemv<<<dim3(S_LEN / 4, NH), 256, 0, stream>>>(E, bv_, av, 1);
    col_part<<<dim3(64, NH), 128, 0, stream>>>(E, av, tp);
    col_combine<<<NH * S_LEN / 256, 256, 0, stream>>>(tp, bv_);
    row_gemv<<<dim3(S_LEN / 4, NH), 256, 0, stream>>>(E, bv_, av, 1);
    col_part<<<dim3(64, NH), 128, 0, stream>>>(E, av, tp);
    col_combine<<<NH * S_LEN / 256, 256, 0, stream>>>(tp, bv_);

    scale_v<<<dim3(S_LEN / 64, NH), 256, 0, stream>>>(Vf, bv_, Vt);
    attn_av<<<dim3(S_LEN / 32, NH), 256, 0, stream>>>(E, av, Vt, ctxb);
    out_mfma<<<dim3(E_DIM / 64, S_LEN / 64), 256, 0, stream>>>(ctxb, Wt, bo, X, Y);
    layernorm<<<S_LEN, 256, 0, stream>>>(Y, ln_g, ln_b, out);
}

// Round 4
// 381.352 us; speedup vs baseline: 1.8195x; 1.0171x over previous
//
#include <hip/hip_runtime.h>
#include <math.h>

#define S_LEN 2048
#define E_DIM 768
#define NH    12
#define HD    64
#define MU    (1.0f/2048.0f)
#define LN_EPS 1e-12f

typedef __attribute__((ext_vector_type(8))) short bf16x8;   // 8 bf16 (4 VGPRs)
typedef __attribute__((ext_vector_type(4))) float f32x4;    // MFMA accumulator
typedef __attribute__((ext_vector_type(2))) float f32x2;
typedef long i64_t;                                          // 8 fp8 (2 VGPRs)

__device__ __forceinline__ unsigned short f2bf(float f) {   // RNE fp32->bf16
    unsigned u = __float_as_uint(f);
    u += 0x7fff + ((u >> 16) & 1);
    return (unsigned short)(u >> 16);
}

// ---- fp8 e4m3 (OCP) helpers ----
__device__ __forceinline__ unsigned char fp8_enc(float f) {
#if __has_builtin(__builtin_amdgcn_cvt_pk_fp8_f32)
    return (unsigned char)(__builtin_amdgcn_cvt_pk_fp8_f32(f, f, 0, false) & 0xFF);
#else
    float m = fminf(fabsf(f), 448.f) * 0x1p-120f;
    unsigned b = __float_as_uint(m);
    unsigned s = (__float_as_uint(f) >> 24) & 0x80u;
    b += 0x7FFFFu + ((b >> 20) & 1u);
    return (unsigned char)(s | ((b >> 20) & 0x7Fu));
#endif
}
__device__ __forceinline__ float fp8_dec1(unsigned char u) {
    unsigned bits = ((u & 0x80u) << 24) | ((u & 0x7Fu) << 20);
    return __uint_as_float(bits) * 0x1p+120f;
}
__device__ __forceinline__ f32x2 fp8_dec_lo(unsigned v) {
#if __has_builtin(__builtin_amdgcn_cvt_pk_f32_fp8)
    return __builtin_amdgcn_cvt_pk_f32_fp8(v, false);
#else
    f32x2 r; r.x = fp8_dec1(v & 0xFF); r.y = fp8_dec1((v >> 8) & 0xFF); return r;
#endif
}
__device__ __forceinline__ f32x2 fp8_dec_hi(unsigned v) {
#if __has_builtin(__builtin_amdgcn_cvt_pk_f32_fp8)
    return __builtin_amdgcn_cvt_pk_f32_fp8(v, true);
#else
    f32x2 r; r.x = fp8_dec1((v >> 16) & 0xFF); r.y = fp8_dec1(v >> 24); return r;
#endif
}

// ---------------------------------------------------------------------------
__global__ __launch_bounds__(256) void quant_x(const float* __restrict__ X,
                                               unsigned short* __restrict__ Xb) {
    int i = blockIdx.x * 256 + threadIdx.x;
    const float4 v = ((const float4*)X)[i];
    ushort4 o = { f2bf(v.x), f2bf(v.y), f2bf(v.z), f2bf(v.w) };
    ((ushort4*)Xb)[i] = o;
}

// W[k][n] fp32 -> Wt[z][n][k] bf16.  grid (24,24,4), block 256
__global__ __launch_bounds__(256) void quant_wt(
    const float* __restrict__ W0, const float* __restrict__ W1,
    const float* __restrict__ W2, const float* __restrict__ W3,
    unsigned short* __restrict__ Wt) {
    const float* W = (blockIdx.z == 0) ? W0 : (blockIdx.z == 1) ? W1
                   : (blockIdx.z == 2) ? W2 : W3;
    __shared__ unsigned short t[32][33];
    const int n0 = blockIdx.x * 32, k0 = blockIdx.y * 32;
    const int c = threadIdx.x & 31, r8 = threadIdx.x >> 5;
#pragma unroll
    for (int rr = 0; rr < 32; rr += 8) {
        int k = k0 + r8 + rr;
        t[c][r8 + rr] = f2bf(W[(size_t)k * E_DIM + n0 + c]);
    }
    __syncthreads();
    unsigned short* out = Wt + (size_t)blockIdx.z * E_DIM * E_DIM;
#pragma unroll
    for (int rr = 0; rr < 32; rr += 8) {
        int n = n0 + r8 + rr;
        out[(size_t)n * E_DIM + k0 + c] = t[r8 + rr][c];
    }
}

// ---------------------------------------------------------------------------
// Fused QKV GEMM, LDS-staged.  X[2048,768]@W[768,768]x3 -> Q,K bf16 / V fp32.
// grid (36 (z*12+h), 16 (row tiles)), block 256. Tile 128x64, BK=64.
__global__ __launch_bounds__(256) void qkv_gemm(
    const unsigned short* __restrict__ Xb, const unsigned short* __restrict__ Wt,
    const float* __restrict__ bq, const float* __restrict__ bk, const float* __restrict__ bv,
    unsigned short* __restrict__ Qb, unsigned short* __restrict__ Kb,
    float* __restrict__ Vf) {
    const int bx = blockIdx.x;
    const int z = bx / 12, h = bx % 12;
    const int row0 = blockIdx.y * 128;
    const int tid = threadIdx.x;
    const int wave = tid >> 6, lane = tid & 63;
    const int wm = wave & 1, wn = wave >> 1;
    const int q = lane >> 4, c = lane & 15;
    __shared__ unsigned short As[128][72];   // +8 pad: 2-way-max bank aliasing
    __shared__ unsigned short Bs[64][72];
    const unsigned short* Wz = Wt + ((size_t)z * E_DIM + h * 64) * E_DIM;
    const int lr = tid >> 3;                 // 0..31 staging row group
    const int lk = (tid & 7) * 8;            // k offset (shorts)
    f32x4 acc[4][2] = {};
    for (int kt = 0; kt < E_DIM; kt += 64) {
        uint4 a[4], b[2];
#pragma unroll
        for (int p = 0; p < 4; ++p)
            a[p] = *(const uint4*)&Xb[(size_t)(row0 + lr + p * 32) * E_DIM + kt + lk];
#pragma unroll
        for (int p = 0; p < 2; ++p)
            b[p] = *(const uint4*)&Wz[(size_t)(lr + p * 32) * E_DIM + kt + lk];
        __syncthreads();
#pragma unroll
        for (int p = 0; p < 4; ++p) *(uint4*)&As[lr + p * 32][lk] = a[p];
#pragma unroll
        for (int p = 0; p < 2; ++p) *(uint4*)&Bs[lr + p * 32][lk] = b[p];
        __syncthreads();
#pragma unroll
        for (int ks = 0; ks < 2; ++ks) {
            bf16x8 af[4], bfr[2];
#pragma unroll
            for (int mi = 0; mi < 4; ++mi)
                af[mi] = *(const bf16x8*)&As[wm * 64 + mi * 16 + c][ks * 32 + q * 8];
#pragma unroll
            for (int ni = 0; ni < 2; ++ni)
                bfr[ni] = *(const bf16x8*)&Bs[wn * 32 + ni * 16 + c][ks * 32 + q * 8];
#pragma unroll
            for (int mi = 0; mi < 4; ++mi)
#pragma unroll
                for (int ni = 0; ni < 2; ++ni)
                    acc[mi][ni] = __builtin_amdgcn_mfma_f32_16x16x32_bf16(
                        af[mi], bfr[ni], acc[mi][ni], 0, 0, 0);
        }
    }
    const float* bias = (z == 0) ? bq : (z == 1) ? bk : bv;
#pragma unroll
    for (int mi = 0; mi < 4; ++mi)
#pragma unroll
        for (int ni = 0; ni < 2; ++ni) {
            const int d = wn * 32 + ni * 16 + c;
            const float bb = bias[h * 64 + d];
#pragma unroll
            for (int r = 0; r < 4; ++r) {
                const int row = row0 + wm * 64 + mi * 16 + q * 4 + r;
                const float val = acc[mi][ni][r] + bb;
                const size_t off = ((size_t)h * S_LEN + row) * HD + d;
                if (z == 0)      Qb[off] = f2bf(val);
                else if (z == 1) Kb[off] = f2bf(val);
                else             Vf[off] = val;
            }
        }
}

// ---------------------------------------------------------------------------
// E = exp(Q.K^T/8) -> fp8; fused row-sum (Sinkhorn pass 1) via atomics.
// grid (S/64 (j), S/64 (i), NH), block 256
__global__ __launch_bounds__(256) void score_exp(
    const unsigned short* __restrict__ Qb, const unsigned short* __restrict__ Kb,
    unsigned char* __restrict__ E, float* __restrict__ rowsum) {
    const int h = blockIdx.z;
    const int i0 = blockIdx.y * 64, j0 = blockIdx.x * 64;
    const int wave = threadIdx.x >> 6, lane = threadIdx.x & 63;
    const int q = lane >> 4, c = lane & 15;
    __shared__ unsigned char Es[64][80];
    const unsigned short* Qh = Qb + (size_t)h * S_LEN * HD;
    const unsigned short* Kh = Kb + (size_t)h * S_LEN * HD;
    f32x4 acc[4] = {};
#pragma unroll
    for (int dt = 0; dt < HD; dt += 32) {
        bf16x8 a = *(const bf16x8*)&Qh[(size_t)(i0 + wave * 16 + c) * HD + dt + q * 8];
#pragma unroll
        for (int s = 0; s < 4; ++s) {
            bf16x8 b = *(const bf16x8*)&Kh[(size_t)(j0 + s * 16 + c) * HD + dt + q * 8];
            acc[s] = __builtin_amdgcn_mfma_f32_16x16x32_bf16(a, b, acc[s], 0, 0, 0);
        }
    }
    float vals[4][4];
#pragma unroll
    for (int s = 0; s < 4; ++s)
#pragma unroll
        for (int r = 0; r < 4; ++r) {
            vals[s][r] = __expf(acc[s][r] * 0.125f);
            Es[wave * 16 + q * 4 + r][s * 16 + c] = fp8_enc(vals[s][r]);
        }
    // row partial sums: reduce over the 16 c-lanes (same q), then one atomic
#pragma unroll
    for (int r = 0; r < 4; ++r) {
        float rs = vals[0][r] + vals[1][r] + vals[2][r] + vals[3][r];
#pragma unroll
        for (int off = 8; off; off >>= 1) rs += __shfl_down(rs, off, 16);
        if (c == 0)
            atomicAdd(&rowsum[(size_t)h * S_LEN + i0 + wave * 16 + q * 4 + r], rs);
    }
    __syncthreads();
    const int row = threadIdx.x >> 2, cc = (threadIdx.x & 3) * 16;
    unsigned char* out = E + ((size_t)h * S_LEN + i0 + row) * S_LEN + j0 + cc;
    *(uint4*)out = *(const uint4*)&Es[row][cc];
}

// a = mu / rowsum.  grid (NH*S/256), block 256
__global__ __launch_bounds__(256) void recip_mu(const float* __restrict__ rs,
                                                float* __restrict__ a) {
    int g = blockIdx.x * 256 + threadIdx.x;
    a[g] = MU / rs[g];
}

// ---------------------------------------------------------------------------
// a[h][i] = mu / sum_j E[h][i][j]*b[h][j].  grid (S/4, NH), block 256
__global__ __launch_bounds__(256) void row_gemv(
    const unsigned char* __restrict__ E, const float* __restrict__ bvec,
    float* __restrict__ aout) {
    const int h = blockIdx.y;
    const int wave = threadIdx.x >> 6, lane = threadIdx.x & 63;
    const int row = blockIdx.x * 4 + wave;
    const unsigned char* er = E + ((size_t)h * S_LEN + row) * S_LEN;
    const float* bh = bvec + (size_t)h * S_LEN;
    float sum = 0.f;
#pragma unroll
    for (int ch = 0; ch < 2; ++ch) {
        int j = ch * 1024 + lane * 16;
        uint4 e = *(const uint4*)&er[j];
        unsigned w[4] = {e.x, e.y, e.z, e.w};
#pragma unroll
        for (int k = 0; k < 4; ++k) {
            f32x2 lo = fp8_dec_lo(w[k]), hi = fp8_dec_hi(w[k]);
            float4 b0 = *(const float4*)&bh[j + k * 4];
            sum += lo.x * b0.x + lo.y * b0.y + hi.x * b0.z + hi.y * b0.w;
        }
    }
#pragma unroll
    for (int off = 32; off; off >>= 1) sum += __shfl_down(sum, off, 64);
    if (lane == 0) aout[(size_t)h * S_LEN + row] = MU / sum;
}

// ---------------------------------------------------------------------------
// tp[h][chunk][j] = sum_{i in 32-row chunk} E[h][i][j]*a[h][i]
// grid (64, NH), block 128 (thread -> 16 consecutive j)
__global__ __launch_bounds__(128) void col_part(
    const unsigned char* __restrict__ E, const float* __restrict__ a,
    float* __restrict__ tpart) {
    const int h = blockIdx.y, chunk = blockIdx.x;
    __shared__ float la[32];
    if (threadIdx.x < 32) la[threadIdx.x] = a[(size_t)h * S_LEN + chunk * 32 + threadIdx.x];
    __syncthreads();
    const int j0 = threadIdx.x * 16;
    const unsigned char* eb = E + ((size_t)h * S_LEN + chunk * 32) * S_LEN + j0;
    float acc[16] = {};
    for (int ii = 0; ii < 32; ++ii) {
        float ai = la[ii];
        uint4 e = *(const uint4*)&eb[(size_t)ii * S_LEN];
        unsigned w[4] = {e.x, e.y, e.z, e.w};
#pragma unroll
        for (int k = 0; k < 4; ++k) {
            f32x2 lo = fp8_dec_lo(w[k]), hi = fp8_dec_hi(w[k]);
            acc[k * 4 + 0] += lo.x * ai; acc[k * 4 + 1] += lo.y * ai;
            acc[k * 4 + 2] += hi.x * ai; acc[k * 4 + 3] += hi.y * ai;
        }
    }
    float* outp = tpart + ((size_t)h * 64 + chunk) * S_LEN + j0;
#pragma unroll
    for (int k = 0; k < 4; ++k) {
        float4 o = {acc[k * 4], acc[k * 4 + 1], acc[k * 4 + 2], acc[k * 4 + 3]};
        *(float4*)&outp[k * 4] = o;
    }
}

// b[h][j] = mu / sum_chunk tp.  grid (NH*S/256), block 256
__global__ __launch_bounds__(256) void col_combine(
    const float* __restrict__ tpart, float* __restrict__ bout) {
    int g = blockIdx.x * 256 + threadIdx.x;
    int h = g >> 11, j = g & 2047;
    float s = 0.f;
#pragma unroll 8
    for (int c = 0; c < 64; ++c) s += tpart[((size_t)h * 64 + c) * S_LEN + j];
    bout[g] = MU / s;
}

// ---------------------------------------------------------------------------
// V't[h][d][j] = fp8( b[h][j] * V[h][j][d] )  grid (S/64, NH), block 256
__global__ __launch_bounds__(256) void scale_v(
    const float* __restrict__ Vf, const float* __restrict__ b,
    unsigned char* __restrict__ Vt) {
    const int h = blockIdx.y, j0 = blockIdx.x * 64;
    __shared__ unsigned char t[64][80];
    {
        const int r = threadIdx.x >> 2, dc = (threadIdx.x & 3) * 16;
        float bj = b[(size_t)h * S_LEN + j0 + r];
        const float* vrow = Vf + ((size_t)h * S_LEN + j0 + r) * HD + dc;
#pragma unroll
        for (int k = 0; k < 16; ++k) t[dc + k][r] = fp8_enc(vrow[k] * bj);
    }
    __syncthreads();
    const int d = threadIdx.x >> 2, jc = (threadIdx.x & 3) * 16;
    unsigned char* out = Vt + ((size_t)h * HD + d) * S_LEN + j0 + jc;
    *(uint4*)out = *(const uint4*)&t[d][jc];
}

// ---------------------------------------------------------------------------
// ctx[i][h*64+d] = a_i*n * sum_j E[h][i][j]*V't[h][d][j], fp8 MFMA, j-split.
// grid (S/32, NH), block 256
__global__ __launch_bounds__(256) void attn_av(
    const unsigned char* __restrict__ E, const float* __restrict__ a,
    const unsigned char* __restrict__ Vt, unsigned short* __restrict__ ctxb) {
    const int h = blockIdx.y;
    const int wave = threadIdx.x >> 6, lane = threadIdx.x & 63;
    const int rt = wave & 1, jh = wave >> 1;
    const int q = lane >> 4, c = lane & 15;
    const int i0 = blockIdx.x * 32 + rt * 16;
    const unsigned char* Eh = E + (size_t)h * S_LEN * S_LEN;
    const unsigned char* Vh = Vt + (size_t)h * HD * S_LEN;
    f32x4 acc[4] = {};
    const int jbase = jh * 1024;
    for (int jt = jbase; jt < jbase + 1024; jt += 32) {
        i64_t av = *(const i64_t*)&Eh[(size_t)(i0 + c) * S_LEN + jt + q * 8];
#pragma unroll
        for (int s = 0; s < 4; ++s) {
            i64_t bv = *(const i64_t*)&Vh[(size_t)(s * 16 + c) * S_LEN + jt + q * 8];
            acc[s] = __builtin_amdgcn_mfma_f32_16x16x32_fp8_fp8(av, bv, acc[s], 0, 0, 0);
        }
    }
    __shared__ float lred[2][16][64];
    if (jh == 1) {
#pragma unroll
        for (int s = 0; s < 4; ++s)
#pragma unroll
            for (int r = 0; r < 4; ++r) lred[rt][s * 4 + r][lane] = acc[s][r];
    }
    __syncthreads();
    if (jh == 0) {
        float ais[4];
#pragma unroll
        for (int r = 0; r < 4; ++r) ais[r] = a[(size_t)h * S_LEN + i0 + q * 4 + r] * 2048.f;
#pragma unroll
        for (int s = 0; s < 4; ++s)
#pragma unroll
            for (int r = 0; r < 4; ++r) {
                float v = (acc[s][r] + lred[rt][s * 4 + r][lane]) * ais[r];
                ctxb[(size_t)(i0 + q * 4 + r) * E_DIM + h * 64 + s * 16 + c] = f2bf(v);
            }
    }
}

// ---------------------------------------------------------------------------
// Y = ctx @ Wo + bo + X, LDS-staged.  grid (12, 16), block 256. Tile 128x64.
__global__ __launch_bounds__(256) void out_gemm(
    const unsigned short* __restrict__ ctxb, const unsigned short* __restrict__ Wt,
    const float* __restrict__ bo, const float* __restrict__ X, float* __restrict__ Y) {
    const int n0 = blockIdx.x * 64;
    const int row0 = blockIdx.y * 128;
    const int tid = threadIdx.x;
    const int wave = tid >> 6, lane = tid & 63;
    const int wm = wave & 1, wn = wave >> 1;
    const int q = lane >> 4, c = lane & 15;
    __shared__ unsigned short As[128][72];
    __shared__ unsigned short Bs[64][72];
    const unsigned short* Wo3 = Wt + (size_t)3 * E_DIM * E_DIM + (size_t)n0 * E_DIM;
    const int lr = tid >> 3;
    const int lk = (tid & 7) * 8;
    f32x4 acc[4][2] = {};
    for (int kt = 0; kt < E_DIM; kt += 64) {
        uint4 a[4], b[2];
#pragma unroll
        for (int p = 0; p < 4; ++p)
            a[p] = *(const uint4*)&ctxb[(size_t)(row0 + lr + p * 32) * E_DIM + kt + lk];
#pragma unroll
        for (int p = 0; p < 2; ++p)
            b[p] = *(const uint4*)&Wo3[(size_t)(lr + p * 32) * E_DIM + kt + lk];
        __syncthreads();
#pragma unroll
        for (int p = 0; p < 4; ++p) *(uint4*)&As[lr + p * 32][lk] = a[p];
#pragma unroll
        for (int p = 0; p < 2; ++p) *(uint4*)&Bs[lr + p * 32][lk] = b[p];
        __syncthreads();
#pragma unroll
        for (int ks = 0; ks < 2; ++ks) {
            bf16x8 af[4], bfr[2];
#pragma unroll
            for (int mi = 0; mi < 4; ++mi)
                af[mi] = *(const bf16x8*)&As[wm * 64 + mi * 16 + c][ks * 32 + q * 8];
#pragma unroll
            for (int ni = 0; ni < 2; ++ni)
                bfr[ni] = *(const bf16x8*)&Bs[wn * 32 + ni * 16 + c][ks * 32 + q * 8];
#pragma unroll
            for (int mi = 0; mi < 4; ++mi)
#pragma unroll
                for (int ni = 0; ni < 2; ++ni)
                    acc[mi][ni] = __builtin_amdgcn_mfma_f32_16x16x32_bf16(
                        af[mi], bfr[ni], acc[mi][ni], 0, 0, 0);
        }
    }
#pragma unroll
    for (int mi = 0; mi < 4; ++mi)
#pragma unroll
        for (int ni = 0; ni < 2; ++ni) {
            const int n = n0 + wn * 32 + ni * 16 + c;
            const float bn = bo[n];
#pragma unroll
            for (int r = 0; r < 4; ++r) {
                const int row = row0 + wm * 64 + mi * 16 + q * 4 + r;
                Y[(size_t)row * E_DIM + n] =
                    acc[mi][ni][r] + bn + X[(size_t)row * E_DIM + n];
            }
        }
}

// ---------------------------------------------------------------------------
// LayerNorm per row.  grid (S), block 256
__global__ __launch_bounds__(256) void layernorm(
    const float* __restrict__ Y, const float* __restrict__ g,
    const float* __restrict__ b, float* __restrict__ out) {
    __shared__ float red[4];
    const int srow = blockIdx.x;
    const float* yr = Y + (size_t)srow * E_DIM;
    const int t = threadIdx.x;
    float xs[3];
    float sum = 0.f;
#pragma unroll
    for (int r = 0; r < 3; ++r) { xs[r] = yr[t + r * 256]; sum += xs[r]; }
#pragma unroll
    for (int off = 32; off; off >>= 1) sum += __shfl_down(sum, off, 64);
    if ((t & 63) == 0) red[t >> 6] = sum;
    __syncthreads();
    sum = red[0] + red[1] + red[2] + red[3];
    const float mu = sum * (1.f / 768.f);
    float vs = 0.f;
#pragma unroll
    for (int r = 0; r < 3; ++r) { float d = xs[r] - mu; vs += d * d; }
    __syncthreads();
#pragma unroll
    for (int off = 32; off; off >>= 1) vs += __shfl_down(vs, off, 64);
    if ((t & 63) == 0) red[t >> 6] = vs;
    __syncthreads();
    vs = red[0] + red[1] + red[2] + red[3];
    const float inv = rsqrtf(vs * (1.f / 768.f) + LN_EPS);
#pragma unroll
    for (int r = 0; r < 3; ++r) {
        int c = t + r * 256;
        out[(size_t)srow * E_DIM + c] = g[c] * (xs[r] - mu) * inv + b[c];
    }
}

// ---------------------------------------------------------------------------
extern "C" void kernel_launch(void* const* d_in, const int* in_sizes, int n_in,
                              void* d_out, int out_size, void* d_ws, size_t ws_size,
                              hipStream_t stream) {
    const float* X    = (const float*)d_in[0];
    const float* Wq   = (const float*)d_in[1];
    const float* bq   = (const float*)d_in[2];
    const float* Wk   = (const float*)d_in[3];
    const float* bk   = (const float*)d_in[4];
    const float* Wv   = (const float*)d_in[5];
    const float* bv   = (const float*)d_in[6];
    const float* Wo   = (const float*)d_in[7];
    const float* bo   = (const float*)d_in[8];
    const float* ln_g = (const float*)d_in[9];
    const float* ln_b = (const float*)d_in[10];
    float* out = (float*)d_out;

    char* p = (char*)d_ws;
    auto alloc = [&](size_t bytes) { char* r = p; p += (bytes + 255) & ~(size_t)255; return r; };
    unsigned short* Xb   = (unsigned short*)alloc((size_t)S_LEN * E_DIM * 2);
    unsigned short* Wt   = (unsigned short*)alloc((size_t)4 * E_DIM * E_DIM * 2);
    unsigned short* Qb   = (unsigned short*)alloc((size_t)NH * S_LEN * HD * 2);
    unsigned short* Kb   = (unsigned short*)alloc((size_t)NH * S_LEN * HD * 2);
    float*          Vf   = (float*)alloc((size_t)NH * S_LEN * HD * 4);
    unsigned char*  E    = (unsigned char*)alloc((size_t)NH * S_LEN * S_LEN);   // 50 MB fp8
    float*          rsum = (float*)alloc((size_t)NH * S_LEN * 4);
    float*          av   = (float*)alloc((size_t)NH * S_LEN * 4);
    float*          bv_  = (float*)alloc((size_t)NH * S_LEN * 4);
    float*          tp   = (float*)alloc((size_t)NH * 64 * S_LEN * 4);
    unsigned char*  Vt   = (unsigned char*)alloc((size_t)NH * HD * S_LEN);
    unsigned short* ctxb = (unsigned short*)alloc((size_t)S_LEN * E_DIM * 2);
    float*          Y    = (float*)alloc((size_t)S_LEN * E_DIM * 4);

    quant_x<<<S_LEN * E_DIM / 1024, 256, 0, stream>>>(X, Xb);
    quant_wt<<<dim3(24, 24, 4), 256, 0, stream>>>(Wq, Wk, Wv, Wo, Wt);
    qkv_gemm<<<dim3(36, 16), 256, 0, stream>>>(Xb, Wt, bq, bk, bv, Qb, Kb, Vf);

    hipMemsetAsync(rsum, 0, (size_t)NH * S_LEN * sizeof(float), stream);
    score_exp<<<dim3(S_LEN / 64, S_LEN / 64, NH), 256, 0, stream>>>(Qb, Kb, E, rsum);
    recip_mu<<<NH * S_LEN / 256, 256, 0, stream>>>(rsum, av);                    // a1

    col_part<<<dim3(64, NH), 128, 0, stream>>>(E, av, tp);
    col_combine<<<NH * S_LEN / 256, 256, 0, stream>>>(tp, bv_);                  // b1
    row_gemv<<<dim3(S_LEN / 4, NH), 256, 0, stream>>>(E, bv_, av);               // a2
    col_part<<<dim3(64, NH), 128, 0, stream>>>(E, av, tp);
    col_combine<<<NH * S_LEN / 256, 256, 0, stream>>>(tp, bv_);                  // b2
    row_gemv<<<dim3(S_LEN / 4, NH), 256, 0, stream>>>(E, bv_, av);               // a3
    col_part<<<dim3(64, NH), 128, 0, stream>>>(E, av, tp);
    col_combine<<<NH * S_LEN / 256, 256, 0, stream>>>(tp, bv_);                  // b3

    scale_v<<<dim3(S_LEN / 64, NH), 256, 0, stream>>>(Vf, bv_, Vt);
    attn_av<<<dim3(S_LEN / 32, NH), 256, 0, stream>>>(E, av, Vt, ctxb);
    out_gemm<<<dim3(12, 16), 256, 0, stream>>>(ctxb, Wt, bo, X, Y);
    layernorm<<<S_LEN, 256, 0, stream>>>(Y, ln_g, ln_b, out);
}

// Round 5
// 372.279 us; speedup vs baseline: 1.8638x; 1.0244x over previous
//
#include <hip/hip_runtime.h>
#include <math.h>

#define S_LEN 2048
#define E_DIM 768
#define NH    12
#define HD    64
#define MU    (1.0f/2048.0f)
#define LN_EPS 1e-12f

typedef __attribute__((ext_vector_type(8))) short bf16x8;   // 8 bf16 (4 VGPRs)
typedef __attribute__((ext_vector_type(4))) float f32x4;    // MFMA accumulator
typedef __attribute__((ext_vector_type(2))) float f32x2;
typedef long i64_t;                                          // 8 fp8 (2 VGPRs)

__device__ __forceinline__ unsigned short f2bf(float f) {   // RNE fp32->bf16
    unsigned u = __float_as_uint(f);
    u += 0x7fff + ((u >> 16) & 1);
    return (unsigned short)(u >> 16);
}

// ---- fp8 e4m3 (OCP) helpers ----
__device__ __forceinline__ unsigned char fp8_enc(float f) {
#if __has_builtin(__builtin_amdgcn_cvt_pk_fp8_f32)
    return (unsigned char)(__builtin_amdgcn_cvt_pk_fp8_f32(f, f, 0, false) & 0xFF);
#else
    float m = fminf(fabsf(f), 448.f) * 0x1p-120f;
    unsigned b = __float_as_uint(m);
    unsigned s = (__float_as_uint(f) >> 24) & 0x80u;
    b += 0x7FFFFu + ((b >> 20) & 1u);
    return (unsigned char)(s | ((b >> 20) & 0x7Fu));
#endif
}
__device__ __forceinline__ float fp8_dec1(unsigned char u) {
    unsigned bits = ((u & 0x80u) << 24) | ((u & 0x7Fu) << 20);
    return __uint_as_float(bits) * 0x1p+120f;
}
__device__ __forceinline__ f32x2 fp8_dec_lo(unsigned v) {
#if __has_builtin(__builtin_amdgcn_cvt_pk_f32_fp8)
    return __builtin_amdgcn_cvt_pk_f32_fp8(v, false);
#else
    f32x2 r; r.x = fp8_dec1(v & 0xFF); r.y = fp8_dec1((v >> 8) & 0xFF); return r;
#endif
}
__device__ __forceinline__ f32x2 fp8_dec_hi(unsigned v) {
#if __has_builtin(__builtin_amdgcn_cvt_pk_f32_fp8)
    return __builtin_amdgcn_cvt_pk_f32_fp8(v, true);
#else
    f32x2 r; r.x = fp8_dec1((v >> 16) & 0xFF); r.y = fp8_dec1(v >> 24); return r;
#endif
}

// ---------------------------------------------------------------------------
__global__ __launch_bounds__(256) void quant_x(const float* __restrict__ X,
                                               unsigned short* __restrict__ Xb) {
    int i = blockIdx.x * 256 + threadIdx.x;
    const float4 v = ((const float4*)X)[i];
    ushort4 o = { f2bf(v.x), f2bf(v.y), f2bf(v.z), f2bf(v.w) };
    ((ushort4*)Xb)[i] = o;
}

// W[k][n] fp32 -> Wt[z][n][k] bf16.  grid (24,24,4), block 256
__global__ __launch_bounds__(256) void quant_wt(
    const float* __restrict__ W0, const float* __restrict__ W1,
    const float* __restrict__ W2, const float* __restrict__ W3,
    unsigned short* __restrict__ Wt) {
    const float* W = (blockIdx.z == 0) ? W0 : (blockIdx.z == 1) ? W1
                   : (blockIdx.z == 2) ? W2 : W3;
    __shared__ unsigned short t[32][33];
    const int n0 = blockIdx.x * 32, k0 = blockIdx.y * 32;
    const int c = threadIdx.x & 31, r8 = threadIdx.x >> 5;
#pragma unroll
    for (int rr = 0; rr < 32; rr += 8) {
        int k = k0 + r8 + rr;
        t[c][r8 + rr] = f2bf(W[(size_t)k * E_DIM + n0 + c]);
    }
    __syncthreads();
    unsigned short* out = Wt + (size_t)blockIdx.z * E_DIM * E_DIM;
#pragma unroll
    for (int rr = 0; rr < 32; rr += 8) {
        int n = n0 + r8 + rr;
        out[(size_t)n * E_DIM + k0 + c] = t[r8 + rr][c];
    }
}

// ---------------------------------------------------------------------------
// Fused QKV as one GEMM: X[2048,768] @ Wt[0..3*768)[n][k] -> N=2304 outputs.
// 128x128 tile, BK=64, register-prefetch pipeline. grid (18, 16), block 256.
__global__ __launch_bounds__(256) void qkv_gemm(
    const unsigned short* __restrict__ Xb, const unsigned short* __restrict__ Wt,
    const float* __restrict__ bq, const float* __restrict__ bk, const float* __restrict__ bv,
    unsigned short* __restrict__ Qb, unsigned short* __restrict__ Kb,
    float* __restrict__ Vf) {
    const int n0 = blockIdx.x * 128;       // global output column (0..2304)
    const int row0 = blockIdx.y * 128;
    const int tid = threadIdx.x;
    const int wave = tid >> 6, lane = tid & 63;
    const int wm = wave & 1, wn = wave >> 1;
    const int q = lane >> 4, c = lane & 15;
    __shared__ unsigned short As[128][72];
    __shared__ unsigned short Bs[128][72];
    const int lr = tid >> 3;               // 0..31
    const int lk = (tid & 7) * 8;          // k offset in shorts
    uint4 a[4], b[4];
#pragma unroll
    for (int p = 0; p < 4; ++p) {
        a[p] = *(const uint4*)&Xb[(size_t)(row0 + lr + p * 32) * E_DIM + lk];
        b[p] = *(const uint4*)&Wt[(size_t)(n0 + lr + p * 32) * E_DIM + lk];
    }
    f32x4 acc[4][4] = {};
    for (int kt = 0; kt < E_DIM; kt += 64) {
        __syncthreads();
#pragma unroll
        for (int p = 0; p < 4; ++p) {
            *(uint4*)&As[lr + p * 32][lk] = a[p];
            *(uint4*)&Bs[lr + p * 32][lk] = b[p];
        }
        __syncthreads();
        if (kt + 64 < E_DIM) {
#pragma unroll
            for (int p = 0; p < 4; ++p) {
                a[p] = *(const uint4*)&Xb[(size_t)(row0 + lr + p * 32) * E_DIM + kt + 64 + lk];
                b[p] = *(const uint4*)&Wt[(size_t)(n0 + lr + p * 32) * E_DIM + kt + 64 + lk];
            }
        }
#pragma unroll
        for (int ks = 0; ks < 2; ++ks) {
            bf16x8 af[4], bfr[4];
#pragma unroll
            for (int mi = 0; mi < 4; ++mi)
                af[mi] = *(const bf16x8*)&As[wm * 64 + mi * 16 + c][ks * 32 + q * 8];
#pragma unroll
            for (int ni = 0; ni < 4; ++ni)
                bfr[ni] = *(const bf16x8*)&Bs[wn * 64 + ni * 16 + c][ks * 32 + q * 8];
#pragma unroll
            for (int mi = 0; mi < 4; ++mi)
#pragma unroll
                for (int ni = 0; ni < 4; ++ni)
                    acc[mi][ni] = __builtin_amdgcn_mfma_f32_16x16x32_bf16(
                        af[mi], bfr[ni], acc[mi][ni], 0, 0, 0);
        }
    }
#pragma unroll
    for (int ni = 0; ni < 4; ++ni) {
        const int N0 = n0 + wn * 64 + ni * 16;      // wave-uniform tile base
        const int z = N0 / E_DIM;
        const int nz = N0 - z * E_DIM;
        const int hh = nz >> 6, dbase = nz & 63;
        const float* bias = (z == 0) ? bq : (z == 1) ? bk : bv;
        const float bb = bias[hh * 64 + dbase + c];
#pragma unroll
        for (int mi = 0; mi < 4; ++mi)
#pragma unroll
            for (int r = 0; r < 4; ++r) {
                const int row = row0 + wm * 64 + mi * 16 + q * 4 + r;
                const float val = acc[mi][ni][r] + bb;
                const size_t off = ((size_t)hh * S_LEN + row) * HD + dbase + c;
                if (z == 0)      Qb[off] = f2bf(val);
                else if (z == 1) Kb[off] = f2bf(val);
                else             Vf[off] = val;
            }
    }
}

// ---------------------------------------------------------------------------
// E = exp(Q.K^T/8) -> fp8; per-block row partial sums -> rp[h][jtile][i].
// grid (S/64 (j), S/64 (i), NH), block 256
__global__ __launch_bounds__(256) void score_exp(
    const unsigned short* __restrict__ Qb, const unsigned short* __restrict__ Kb,
    unsigned char* __restrict__ E, float* __restrict__ rp) {
    const int h = blockIdx.z;
    const int i0 = blockIdx.y * 64, j0 = blockIdx.x * 64;
    const int wave = threadIdx.x >> 6, lane = threadIdx.x & 63;
    const int q = lane >> 4, c = lane & 15;
    __shared__ unsigned char Es[64][80];
    const unsigned short* Qh = Qb + (size_t)h * S_LEN * HD;
    const unsigned short* Kh = Kb + (size_t)h * S_LEN * HD;
    f32x4 acc[4] = {};
#pragma unroll
    for (int dt = 0; dt < HD; dt += 32) {
        bf16x8 a = *(const bf16x8*)&Qh[(size_t)(i0 + wave * 16 + c) * HD + dt + q * 8];
#pragma unroll
        for (int s = 0; s < 4; ++s) {
            bf16x8 b = *(const bf16x8*)&Kh[(size_t)(j0 + s * 16 + c) * HD + dt + q * 8];
            acc[s] = __builtin_amdgcn_mfma_f32_16x16x32_bf16(a, b, acc[s], 0, 0, 0);
        }
    }
    float vals[4][4];
#pragma unroll
    for (int s = 0; s < 4; ++s)
#pragma unroll
        for (int r = 0; r < 4; ++r) {
            vals[s][r] = __expf(acc[s][r] * 0.125f);
            Es[wave * 16 + q * 4 + r][s * 16 + c] = fp8_enc(vals[s][r]);
        }
    // per-row partial over this block's 64 j: reduce across the 16 c-lanes
#pragma unroll
    for (int r = 0; r < 4; ++r) {
        float rs = (vals[0][r] + vals[1][r]) + (vals[2][r] + vals[3][r]);
#pragma unroll
        for (int off = 8; off; off >>= 1) rs += __shfl_down(rs, off, 16);
        if (c == 0)
            rp[((size_t)h * 32 + blockIdx.x) * S_LEN + i0 + wave * 16 + q * 4 + r] = rs;
    }
    __syncthreads();
    const int row = threadIdx.x >> 2, cc = (threadIdx.x & 3) * 16;
    unsigned char* out = E + ((size_t)h * S_LEN + i0 + row) * S_LEN + j0 + cc;
    *(uint4*)out = *(const uint4*)&Es[row][cc];
}

// a[h][i] = mu / sum_jt rp[h][jt][i].  grid (NH*S/256), block 256
__global__ __launch_bounds__(256) void row_combine(const float* __restrict__ rp,
                                                   float* __restrict__ a) {
    int g = blockIdx.x * 256 + threadIdx.x;
    int h = g >> 11, i = g & 2047;
    float s = 0.f;
#pragma unroll 8
    for (int jt = 0; jt < 32; ++jt) s += rp[((size_t)h * 32 + jt) * S_LEN + i];
    a[g] = MU / s;
}

// ---------------------------------------------------------------------------
// a[h][i] = mu / sum_j E[h][i][j]*b[h][j].  grid (S/4, NH), block 256
__global__ __launch_bounds__(256) void row_gemv(
    const unsigned char* __restrict__ E, const float* __restrict__ bvec,
    float* __restrict__ aout) {
    const int h = blockIdx.y;
    const int wave = threadIdx.x >> 6, lane = threadIdx.x & 63;
    const int row = blockIdx.x * 4 + wave;
    const unsigned char* er = E + ((size_t)h * S_LEN + row) * S_LEN;
    const float* bh = bvec + (size_t)h * S_LEN;
    float sum = 0.f;
#pragma unroll
    for (int ch = 0; ch < 2; ++ch) {
        int j = ch * 1024 + lane * 16;
        uint4 e = *(const uint4*)&er[j];
        unsigned w[4] = {e.x, e.y, e.z, e.w};
#pragma unroll
        for (int k = 0; k < 4; ++k) {
            f32x2 lo = fp8_dec_lo(w[k]), hi = fp8_dec_hi(w[k]);
            float4 b0 = *(const float4*)&bh[j + k * 4];
            sum += lo.x * b0.x + lo.y * b0.y + hi.x * b0.z + hi.y * b0.w;
        }
    }
#pragma unroll
    for (int off = 32; off; off >>= 1) sum += __shfl_down(sum, off, 64);
    if (lane == 0) aout[(size_t)h * S_LEN + row] = MU / sum;
}

// ---------------------------------------------------------------------------
// tp[h][chunk][j] = sum_{i in 32-row chunk} E[h][i][j]*a[h][i]
// grid (64, NH), block 128; 4-row load batching for MLP
__global__ __launch_bounds__(128) void col_part(
    const unsigned char* __restrict__ E, const float* __restrict__ a,
    float* __restrict__ tpart) {
    const int h = blockIdx.y, chunk = blockIdx.x;
    __shared__ float la[32];
    if (threadIdx.x < 32) la[threadIdx.x] = a[(size_t)h * S_LEN + chunk * 32 + threadIdx.x];
    __syncthreads();
    const int j0 = threadIdx.x * 16;
    const unsigned char* eb = E + ((size_t)h * S_LEN + chunk * 32) * S_LEN + j0;
    float acc[16] = {};
    for (int ii = 0; ii < 32; ii += 4) {
        uint4 e0 = *(const uint4*)&eb[(size_t)(ii + 0) * S_LEN];
        uint4 e1 = *(const uint4*)&eb[(size_t)(ii + 1) * S_LEN];
        uint4 e2 = *(const uint4*)&eb[(size_t)(ii + 2) * S_LEN];
        uint4 e3 = *(const uint4*)&eb[(size_t)(ii + 3) * S_LEN];
        float a0 = la[ii], a1 = la[ii + 1], a2 = la[ii + 2], a3 = la[ii + 3];
        unsigned w0[4] = {e0.x, e0.y, e0.z, e0.w};
        unsigned w1[4] = {e1.x, e1.y, e1.z, e1.w};
        unsigned w2[4] = {e2.x, e2.y, e2.z, e2.w};
        unsigned w3[4] = {e3.x, e3.y, e3.z, e3.w};
#pragma unroll
        for (int k = 0; k < 4; ++k) {
            f32x2 lo, hi;
            lo = fp8_dec_lo(w0[k]); hi = fp8_dec_hi(w0[k]);
            acc[k*4+0] += lo.x*a0; acc[k*4+1] += lo.y*a0; acc[k*4+2] += hi.x*a0; acc[k*4+3] += hi.y*a0;
            lo = fp8_dec_lo(w1[k]); hi = fp8_dec_hi(w1[k]);
            acc[k*4+0] += lo.x*a1; acc[k*4+1] += lo.y*a1; acc[k*4+2] += hi.x*a1; acc[k*4+3] += hi.y*a1;
            lo = fp8_dec_lo(w2[k]); hi = fp8_dec_hi(w2[k]);
            acc[k*4+0] += lo.x*a2; acc[k*4+1] += lo.y*a2; acc[k*4+2] += hi.x*a2; acc[k*4+3] += hi.y*a2;
            lo = fp8_dec_lo(w3[k]); hi = fp8_dec_hi(w3[k]);
            acc[k*4+0] += lo.x*a3; acc[k*4+1] += lo.y*a3; acc[k*4+2] += hi.x*a3; acc[k*4+3] += hi.y*a3;
        }
    }
    float* outp = tpart + ((size_t)h * 64 + chunk) * S_LEN + j0;
#pragma unroll
    for (int k = 0; k < 4; ++k) {
        float4 o = {acc[k * 4], acc[k * 4 + 1], acc[k * 4 + 2], acc[k * 4 + 3]};
        *(float4*)&outp[k * 4] = o;
    }
}

// b[h][j] = mu / sum_chunk tp.  grid (NH*S/256), block 256
__global__ __launch_bounds__(256) void col_combine(
    const float* __restrict__ tpart, float* __restrict__ bout) {
    int g = blockIdx.x * 256 + threadIdx.x;
    int h = g >> 11, j = g & 2047;
    float s = 0.f;
#pragma unroll 8
    for (int c = 0; c < 64; ++c) s += tpart[((size_t)h * 64 + c) * S_LEN + j];
    bout[g] = MU / s;
}

// ---------------------------------------------------------------------------
// V't[h][d][j] = fp8( b[h][j] * V[h][j][d] )  grid (S/64, NH), block 256
__global__ __launch_bounds__(256) void scale_v(
    const float* __restrict__ Vf, const float* __restrict__ b,
    unsigned char* __restrict__ Vt) {
    const int h = blockIdx.y, j0 = blockIdx.x * 64;
    __shared__ unsigned char t[64][80];
    {
        const int r = threadIdx.x >> 2, dc = (threadIdx.x & 3) * 16;
        float bj = b[(size_t)h * S_LEN + j0 + r];
        const float* vrow = Vf + ((size_t)h * S_LEN + j0 + r) * HD + dc;
#pragma unroll
        for (int k = 0; k < 16; ++k) t[dc + k][r] = fp8_enc(vrow[k] * bj);
    }
    __syncthreads();
    const int d = threadIdx.x >> 2, jc = (threadIdx.x & 3) * 16;
    unsigned char* out = Vt + ((size_t)h * HD + d) * S_LEN + j0 + jc;
    *(uint4*)out = *(const uint4*)&t[d][jc];
}

// ---------------------------------------------------------------------------
// ctx[i][h*64+d] = a_i*n * sum_j E[h][i][j]*V't[h][d][j].  fp8 MFMA,
// 4-way j-split (one wave per 512-j quarter), pipelined loads.
// grid (S/16 = 128, NH), block 256
__global__ __launch_bounds__(256) void attn_av(
    const unsigned char* __restrict__ E, const float* __restrict__ a,
    const unsigned char* __restrict__ Vt, unsigned short* __restrict__ ctxb) {
    const int h = blockIdx.y;
    const int wave = threadIdx.x >> 6, lane = threadIdx.x & 63;
    const int q = lane >> 4, c = lane & 15;
    const int i0 = blockIdx.x * 16;
    const unsigned char* Eh = E + (size_t)h * S_LEN * S_LEN + (size_t)(i0 + c) * S_LEN;
    const unsigned char* Vh = Vt + (size_t)h * HD * S_LEN;
    const int jb = wave * 512;
    f32x4 acc[4] = {};
    i64_t av = *(const i64_t*)&Eh[jb + q * 8];
    i64_t bv[4];
#pragma unroll
    for (int s = 0; s < 4; ++s) bv[s] = *(const i64_t*)&Vh[(size_t)(s * 16 + c) * S_LEN + jb + q * 8];
    for (int jt = jb; jt < jb + 512; jt += 32) {
        i64_t av_n = av, bn0 = bv[0], bn1 = bv[1], bn2 = bv[2], bn3 = bv[3];
        if (jt + 32 < jb + 512) {
            av_n = *(const i64_t*)&Eh[jt + 32 + q * 8];
            bn0 = *(const i64_t*)&Vh[(size_t)(0 * 16 + c) * S_LEN + jt + 32 + q * 8];
            bn1 = *(const i64_t*)&Vh[(size_t)(1 * 16 + c) * S_LEN + jt + 32 + q * 8];
            bn2 = *(const i64_t*)&Vh[(size_t)(2 * 16 + c) * S_LEN + jt + 32 + q * 8];
            bn3 = *(const i64_t*)&Vh[(size_t)(3 * 16 + c) * S_LEN + jt + 32 + q * 8];
        }
        acc[0] = __builtin_amdgcn_mfma_f32_16x16x32_fp8_fp8(av, bv[0], acc[0], 0, 0, 0);
        acc[1] = __builtin_amdgcn_mfma_f32_16x16x32_fp8_fp8(av, bv[1], acc[1], 0, 0, 0);
        acc[2] = __builtin_amdgcn_mfma_f32_16x16x32_fp8_fp8(av, bv[2], acc[2], 0, 0, 0);
        acc[3] = __builtin_amdgcn_mfma_f32_16x16x32_fp8_fp8(av, bv[3], acc[3], 0, 0, 0);
        av = av_n; bv[0] = bn0; bv[1] = bn1; bv[2] = bn2; bv[3] = bn3;
    }
    __shared__ float lred[4][16][64];
#pragma unroll
    for (int s = 0; s < 4; ++s)
#pragma unroll
        for (int r = 0; r < 4; ++r) lred[wave][s * 4 + r][lane] = acc[s][r];
    __syncthreads();
    if (wave == 0) {
        float ais[4];
#pragma unroll
        for (int r = 0; r < 4; ++r) ais[r] = a[(size_t)h * S_LEN + i0 + q * 4 + r] * 2048.f;
#pragma unroll
        for (int s = 0; s < 4; ++s)
#pragma unroll
            for (int r = 0; r < 4; ++r) {
                float v = ((lred[0][s * 4 + r][lane] + lred[1][s * 4 + r][lane]) +
                           (lred[2][s * 4 + r][lane] + lred[3][s * 4 + r][lane])) * ais[r];
                ctxb[(size_t)(i0 + q * 4 + r) * E_DIM + h * 64 + s * 16 + c] = f2bf(v);
            }
    }
}

// ---------------------------------------------------------------------------
// Y = ctx @ Wo + bo + X, 128x64 tile, register-prefetch.  grid (12, 16), block 256
__global__ __launch_bounds__(256) void out_gemm(
    const unsigned short* __restrict__ ctxb, const unsigned short* __restrict__ Wt,
    const float* __restrict__ bo, const float* __restrict__ X, float* __restrict__ Y) {
    const int n0 = blockIdx.x * 64;
    const int row0 = blockIdx.y * 128;
    const int tid = threadIdx.x;
    const int wave = tid >> 6, lane = tid & 63;
    const int wm = wave & 1, wn = wave >> 1;
    const int q = lane >> 4, c = lane & 15;
    __shared__ unsigned short As[128][72];
    __shared__ unsigned short Bs[64][72];
    const unsigned short* Wo3 = Wt + (size_t)3 * E_DIM * E_DIM + (size_t)n0 * E_DIM;
    const int lr = tid >> 3;
    const int lk = (tid & 7) * 8;
    uint4 a[4], b[2];
#pragma unroll
    for (int p = 0; p < 4; ++p)
        a[p] = *(const uint4*)&ctxb[(size_t)(row0 + lr + p * 32) * E_DIM + lk];
#pragma unroll
    for (int p = 0; p < 2; ++p)
        b[p] = *(const uint4*)&Wo3[(size_t)(lr + p * 32) * E_DIM + lk];
    f32x4 acc[4][2] = {};
    for (int kt = 0; kt < E_DIM; kt += 64) {
        __syncthreads();
#pragma unroll
        for (int p = 0; p < 4; ++p) *(uint4*)&As[lr + p * 32][lk] = a[p];
#pragma unroll
        for (int p = 0; p < 2; ++p) *(uint4*)&Bs[lr + p * 32][lk] = b[p];
        __syncthreads();
        if (kt + 64 < E_DIM) {
#pragma unroll
            for (int p = 0; p < 4; ++p)
                a[p] = *(const uint4*)&ctxb[(size_t)(row0 + lr + p * 32) * E_DIM + kt + 64 + lk];
#pragma unroll
            for (int p = 0; p < 2; ++p)
                b[p] = *(const uint4*)&Wo3[(size_t)(lr + p * 32) * E_DIM + kt + 64 + lk];
        }
#pragma unroll
        for (int ks = 0; ks < 2; ++ks) {
            bf16x8 af[4], bfr[2];
#pragma unroll
            for (int mi = 0; mi < 4; ++mi)
                af[mi] = *(const bf16x8*)&As[wm * 64 + mi * 16 + c][ks * 32 + q * 8];
#pragma unroll
            for (int ni = 0; ni < 2; ++ni)
                bfr[ni] = *(const bf16x8*)&Bs[wn * 32 + ni * 16 + c][ks * 32 + q * 8];
#pragma unroll
            for (int mi = 0; mi < 4; ++mi)
#pragma unroll
                for (int ni = 0; ni < 2; ++ni)
                    acc[mi][ni] = __builtin_amdgcn_mfma_f32_16x16x32_bf16(
                        af[mi], bfr[ni], acc[mi][ni], 0, 0, 0);
        }
    }
#pragma unroll
    for (int mi = 0; mi < 4; ++mi)
#pragma unroll
        for (int ni = 0; ni < 2; ++ni) {
            const int n = n0 + wn * 32 + ni * 16 + c;
            const float bn = bo[n];
#pragma unroll
            for (int r = 0; r < 4; ++r) {
                const int row = row0 + wm * 64 + mi * 16 + q * 4 + r;
                Y[(size_t)row * E_DIM + n] =
                    acc[mi][ni][r] + bn + X[(size_t)row * E_DIM + n];
            }
        }
}

// ---------------------------------------------------------------------------
// LayerNorm per row.  grid (S), block 256
__global__ __launch_bounds__(256) void layernorm(
    const float* __restrict__ Y, const float* __restrict__ g,
    const float* __restrict__ b, float* __restrict__ out) {
    __shared__ float red[4];
    const int srow = blockIdx.x;
    const float* yr = Y + (size_t)srow * E_DIM;
    const int t = threadIdx.x;
    float xs[3];
    float sum = 0.f;
#pragma unroll
    for (int r = 0; r < 3; ++r) { xs[r] = yr[t + r * 256]; sum += xs[r]; }
#pragma unroll
    for (int off = 32; off; off >>= 1) sum += __shfl_down(sum, off, 64);
    if ((t & 63) == 0) red[t >> 6] = sum;
    __syncthreads();
    sum = red[0] + red[1] + red[2] + red[3];
    const float mu = sum * (1.f / 768.f);
    float vs = 0.f;
#pragma unroll
    for (int r = 0; r < 3; ++r) { float d = xs[r] - mu; vs += d * d; }
    __syncthreads();
#pragma unroll
    for (int off = 32; off; off >>= 1) vs += __shfl_down(vs, off, 64);
    if ((t & 63) == 0) red[t >> 6] = vs;
    __syncthreads();
    vs = red[0] + red[1] + red[2] + red[3];
    const float inv = rsqrtf(vs * (1.f / 768.f) + LN_EPS);
#pragma unroll
    for (int r = 0; r < 3; ++r) {
        int c = t + r * 256;
        out[(size_t)srow * E_DIM + c] = g[c] * (xs[r] - mu) * inv + b[c];
    }
}

// ---------------------------------------------------------------------------
extern "C" void kernel_launch(void* const* d_in, const int* in_sizes, int n_in,
                              void* d_out, int out_size, void* d_ws, size_t ws_size,
                              hipStream_t stream) {
    const float* X    = (const float*)d_in[0];
    const float* Wq   = (const float*)d_in[1];
    const float* bq   = (const float*)d_in[2];
    const float* Wk   = (const float*)d_in[3];
    const float* bk   = (const float*)d_in[4];
    const float* Wv   = (const float*)d_in[5];
    const float* bv   = (const float*)d_in[6];
    const float* Wo   = (const float*)d_in[7];
    const float* bo   = (const float*)d_in[8];
    const float* ln_g = (const float*)d_in[9];
    const float* ln_b = (const float*)d_in[10];
    float* out = (float*)d_out;

    char* p = (char*)d_ws;
    auto alloc = [&](size_t bytes) { char* r = p; p += (bytes + 255) & ~(size_t)255; return r; };
    unsigned short* Xb   = (unsigned short*)alloc((size_t)S_LEN * E_DIM * 2);
    unsigned short* Wt   = (unsigned short*)alloc((size_t)4 * E_DIM * E_DIM * 2);
    unsigned short* Qb   = (unsigned short*)alloc((size_t)NH * S_LEN * HD * 2);
    unsigned short* Kb   = (unsigned short*)alloc((size_t)NH * S_LEN * HD * 2);
    float*          Vf   = (float*)alloc((size_t)NH * S_LEN * HD * 4);
    unsigned char*  E    = (unsigned char*)alloc((size_t)NH * S_LEN * S_LEN);   // 50 MB fp8
    float*          rp   = (float*)alloc((size_t)NH * 32 * S_LEN * 4);          // row partials
    float*          av   = (float*)alloc((size_t)NH * S_LEN * 4);
    float*          bv_  = (float*)alloc((size_t)NH * S_LEN * 4);
    float*          tp   = (float*)alloc((size_t)NH * 64 * S_LEN * 4);
    unsigned char*  Vt   = (unsigned char*)alloc((size_t)NH * HD * S_LEN);
    unsigned short* ctxb = (unsigned short*)alloc((size_t)S_LEN * E_DIM * 2);
    float*          Y    = (float*)alloc((size_t)S_LEN * E_DIM * 4);

    quant_x<<<S_LEN * E_DIM / 1024, 256, 0, stream>>>(X, Xb);
    quant_wt<<<dim3(24, 24, 4), 256, 0, stream>>>(Wq, Wk, Wv, Wo, Wt);
    qkv_gemm<<<dim3(18, 16), 256, 0, stream>>>(Xb, Wt, bq, bk, bv, Qb, Kb, Vf);

    score_exp<<<dim3(S_LEN / 64, S_LEN / 64, NH), 256, 0, stream>>>(Qb, Kb, E, rp);
    row_combine<<<NH * S_LEN / 256, 256, 0, stream>>>(rp, av);                   // a1

    col_part<<<dim3(64, NH), 128, 0, stream>>>(E, av, tp);
    col_combine<<<NH * S_LEN / 256, 256, 0, stream>>>(tp, bv_);                  // b1
    row_gemv<<<dim3(S_LEN / 4, NH), 256, 0, stream>>>(E, bv_, av);               // a2
    col_part<<<dim3(64, NH), 128, 0, stream>>>(E, av, tp);
    col_combine<<<NH * S_LEN / 256, 256, 0, stream>>>(tp, bv_);                  // b2
    row_gemv<<<dim3(S_LEN / 4, NH), 256, 0, stream>>>(E, bv_, av);               // a3
    col_part<<<dim3(64, NH), 128, 0, stream>>>(E, av, tp);
    col_combine<<<NH * S_LEN / 256, 256, 0, stream>>>(tp, bv_);                  // b3

    scale_v<<<dim3(S_LEN / 64, NH), 256, 0, stream>>>(Vf, bv_, Vt);
    attn_av<<<dim3(S_LEN / 16, NH), 256, 0, stream>>>(E, av, Vt, ctxb);
    out_gemm<<<dim3(12, 16), 256, 0, stream>>>(ctxb, Wt, bo, X, Y);
    layernorm<<<S_LEN, 256, 0, stream>>>(Y, ln_g, ln_b, out);
}

// Round 6
// 310.191 us; speedup vs baseline: 2.2369x; 1.2002x over previous
//
#include <hip/hip_runtime.h>
#include <math.h>

#define S_LEN 2048
#define E_DIM 768
#define NH    12
#define HD    64
#define MU    (1.0f/2048.0f)
#define LN_EPS 1e-12f

typedef __attribute__((ext_vector_type(8))) short bf16x8;   // 8 bf16 (4 VGPRs)
typedef __attribute__((ext_vector_type(4))) float f32x4;    // MFMA accumulator
typedef __attribute__((ext_vector_type(2))) float f32x2;
typedef long i64_t;                                          // 8 fp8 (2 VGPRs)

__device__ __forceinline__ unsigned short f2bf(float f) {   // RNE fp32->bf16
    unsigned u = __float_as_uint(f);
    u += 0x7fff + ((u >> 16) & 1);
    return (unsigned short)(u >> 16);
}
__device__ __forceinline__ float bf2f(unsigned short h) {
    return __uint_as_float(((unsigned)h) << 16);
}

// ---- fp8 e4m3 (OCP) helpers ----
__device__ __forceinline__ unsigned char fp8_enc(float f) {
#if __has_builtin(__builtin_amdgcn_cvt_pk_fp8_f32)
    return (unsigned char)(__builtin_amdgcn_cvt_pk_fp8_f32(f, f, 0, false) & 0xFF);
#else
    float m = fminf(fabsf(f), 448.f) * 0x1p-120f;
    unsigned b = __float_as_uint(m);
    unsigned s = (__float_as_uint(f) >> 24) & 0x80u;
    b += 0x7FFFFu + ((b >> 20) & 1u);
    return (unsigned char)(s | ((b >> 20) & 0x7Fu));
#endif
}
__device__ __forceinline__ float fp8_dec1(unsigned char u) {
    unsigned bits = ((u & 0x80u) << 24) | ((u & 0x7Fu) << 20);
    return __uint_as_float(bits) * 0x1p+120f;
}
__device__ __forceinline__ f32x2 fp8_dec_lo(unsigned v) {
#if __has_builtin(__builtin_amdgcn_cvt_pk_f32_fp8)
    return __builtin_amdgcn_cvt_pk_f32_fp8(v, false);
#else
    f32x2 r; r.x = fp8_dec1(v & 0xFF); r.y = fp8_dec1((v >> 8) & 0xFF); return r;
#endif
}
__device__ __forceinline__ f32x2 fp8_dec_hi(unsigned v) {
#if __has_builtin(__builtin_amdgcn_cvt_pk_f32_fp8)
    return __builtin_amdgcn_cvt_pk_f32_fp8(v, true);
#else
    f32x2 r; r.x = fp8_dec1((v >> 16) & 0xFF); r.y = fp8_dec1(v >> 24); return r;
#endif
}

// ---- async global->LDS, 16 B per lane (dest = wave-uniform base + lane*16) ----
#if defined(__has_builtin)
#if __has_builtin(__builtin_amdgcn_global_load_lds)
#define HAS_GLL 1
#endif
#endif
#if HAS_GLL
__device__ __forceinline__ void gll16(const void* g, void* l) {
    __builtin_amdgcn_global_load_lds(
        (__attribute__((address_space(1))) void*)(void*)g,
        (__attribute__((address_space(3))) void*)l, 16, 0, 0);
}
#endif

// ---------------------------------------------------------------------------
__global__ __launch_bounds__(256) void quant_x(const float* __restrict__ X,
                                               unsigned short* __restrict__ Xb) {
    int i = blockIdx.x * 256 + threadIdx.x;
    const float4 v = ((const float4*)X)[i];
    ushort4 o = { f2bf(v.x), f2bf(v.y), f2bf(v.z), f2bf(v.w) };
    ((ushort4*)Xb)[i] = o;
}

// W[k][n] fp32 -> Wt[z][n][k] bf16.  grid (24,24,4), block 256
__global__ __launch_bounds__(256) void quant_wt(
    const float* __restrict__ W0, const float* __restrict__ W1,
    const float* __restrict__ W2, const float* __restrict__ W3,
    unsigned short* __restrict__ Wt) {
    const float* W = (blockIdx.z == 0) ? W0 : (blockIdx.z == 1) ? W1
                   : (blockIdx.z == 2) ? W2 : W3;
    __shared__ unsigned short t[32][33];
    const int n0 = blockIdx.x * 32, k0 = blockIdx.y * 32;
    const int c = threadIdx.x & 31, r8 = threadIdx.x >> 5;
#pragma unroll
    for (int rr = 0; rr < 32; rr += 8) {
        int k = k0 + r8 + rr;
        t[c][r8 + rr] = f2bf(W[(size_t)k * E_DIM + n0 + c]);
    }
    __syncthreads();
    unsigned short* out = Wt + (size_t)blockIdx.z * E_DIM * E_DIM;
#pragma unroll
    for (int rr = 0; rr < 32; rr += 8) {
        int n = n0 + r8 + rr;
        out[(size_t)n * E_DIM + k0 + c] = t[r8 + rr][c];
    }
}

// ---------------------------------------------------------------------------
// Fused QKV GEMM, global_load_lds staging, tile 128x64, BK=64.
// grid (36 n-tiles, 16 row-tiles), block 256.  All outputs bf16 [h][s][64].
__global__ __launch_bounds__(256) void qkv_gemm(
    const unsigned short* __restrict__ Xb, const unsigned short* __restrict__ Wt,
    const float* __restrict__ bq, const float* __restrict__ bk, const float* __restrict__ bv,
    unsigned short* __restrict__ Qb, unsigned short* __restrict__ Kb,
    unsigned short* __restrict__ Vb) {
    __shared__ unsigned short As[128 * 64];     // unpadded: required by gll
    __shared__ unsigned short Bs[64 * 64];
    const int n0 = blockIdx.x * 64;
    const int row0 = blockIdx.y * 128;
    const int tid = threadIdx.x;
    const int wave = tid >> 6, lane = tid & 63;
    const int wm = wave & 1, wn = wave >> 1;
    const int q = lane >> 4, c = lane & 15;
    const int lrow = lane >> 3, lk8 = (lane & 7) * 8;
    const unsigned short* Wb = Wt + (size_t)n0 * E_DIM;
    f32x4 acc[4][2] = {};
    for (int kt = 0; kt < E_DIM; kt += 64) {
        __syncthreads();
#if HAS_GLL
#pragma unroll
        for (int p = 0; p < 4; ++p)
            gll16(&Xb[(size_t)(row0 + p * 32 + wave * 8 + lrow) * E_DIM + kt + lk8],
                  &As[(p * 32 + wave * 8) * 64]);
#pragma unroll
        for (int p = 0; p < 2; ++p)
            gll16(&Wb[(size_t)(p * 32 + wave * 8 + lrow) * E_DIM + kt + lk8],
                  &Bs[(p * 32 + wave * 8) * 64]);
#else
        {
            uint4 ta[4], tb[2];
#pragma unroll
            for (int p = 0; p < 4; ++p)
                ta[p] = *(const uint4*)&Xb[(size_t)(row0 + p * 32 + wave * 8 + lrow) * E_DIM + kt + lk8];
#pragma unroll
            for (int p = 0; p < 2; ++p)
                tb[p] = *(const uint4*)&Wb[(size_t)(p * 32 + wave * 8 + lrow) * E_DIM + kt + lk8];
#pragma unroll
            for (int p = 0; p < 4; ++p) *(uint4*)&As[(p * 32 + wave * 8 + lrow) * 64 + lk8] = ta[p];
#pragma unroll
            for (int p = 0; p < 2; ++p) *(uint4*)&Bs[(p * 32 + wave * 8 + lrow) * 64 + lk8] = tb[p];
        }
#endif
        __syncthreads();
#pragma unroll
        for (int ks = 0; ks < 2; ++ks) {
            bf16x8 af[4], bfr[2];
#pragma unroll
            for (int mi = 0; mi < 4; ++mi)
                af[mi] = *(const bf16x8*)&As[(wm * 64 + mi * 16 + c) * 64 + ks * 32 + q * 8];
#pragma unroll
            for (int ni = 0; ni < 2; ++ni)
                bfr[ni] = *(const bf16x8*)&Bs[(wn * 32 + ni * 16 + c) * 64 + ks * 32 + q * 8];
#pragma unroll
            for (int mi = 0; mi < 4; ++mi)
#pragma unroll
                for (int ni = 0; ni < 2; ++ni)
                    acc[mi][ni] = __builtin_amdgcn_mfma_f32_16x16x32_bf16(
                        af[mi], bfr[ni], acc[mi][ni], 0, 0, 0);
        }
    }
    const int z = n0 / E_DIM;
    const int h = (n0 % E_DIM) >> 6;
    const float* bias = (z == 0) ? bq : (z == 1) ? bk : bv;
    unsigned short* outp = (z == 0) ? Qb : (z == 1) ? Kb : Vb;
    __syncthreads();
    unsigned short* Cs = As;                    // reuse 16 KB for repack
#pragma unroll
    for (int ni = 0; ni < 2; ++ni) {
        const int col = wn * 32 + ni * 16 + c;
        const float bb = bias[h * 64 + col];
#pragma unroll
        for (int mi = 0; mi < 4; ++mi)
#pragma unroll
            for (int r = 0; r < 4; ++r)
                Cs[(wm * 64 + mi * 16 + q * 4 + r) * 64 + col] = f2bf(acc[mi][ni][r] + bb);
    }
    __syncthreads();
#pragma unroll
    for (int pp = 0; pp < 4; ++pp) {
        int row = pp * 32 + (tid >> 3);
        *(uint4*)&outp[((size_t)h * S_LEN + row0 + row) * HD + (tid & 7) * 8] =
            *(const uint4*)&Cs[row * 64 + (tid & 7) * 8];
    }
}

// ---------------------------------------------------------------------------
// E = exp(Q.K^T/8) -> fp8, 64x128 tile (full 128-B line writes); fused row
// partials rp[h][jt16][i].  grid (16 j, 32 i, 12 h), block 256.
__global__ __launch_bounds__(256) void score_exp(
    const unsigned short* __restrict__ Qb, const unsigned short* __restrict__ Kb,
    unsigned char* __restrict__ E, float* __restrict__ rp) {
    const int h = blockIdx.z;
    const int i0 = blockIdx.y * 64, j0 = blockIdx.x * 128;
    const int wave = threadIdx.x >> 6, lane = threadIdx.x & 63;
    const int q = lane >> 4, c = lane & 15;
    __shared__ unsigned char Es[64 * 128];
    const unsigned short* Qh = Qb + (size_t)h * S_LEN * HD;
    const unsigned short* Kh = Kb + (size_t)h * S_LEN * HD;
    f32x4 acc[8] = {};
#pragma unroll
    for (int dt = 0; dt < HD; dt += 32) {
        bf16x8 a = *(const bf16x8*)&Qh[(size_t)(i0 + wave * 16 + c) * HD + dt + q * 8];
#pragma unroll
        for (int s = 0; s < 8; ++s) {
            bf16x8 b = *(const bf16x8*)&Kh[(size_t)(j0 + s * 16 + c) * HD + dt + q * 8];
            acc[s] = __builtin_amdgcn_mfma_f32_16x16x32_bf16(a, b, acc[s], 0, 0, 0);
        }
    }
    float vals[8][4];
#pragma unroll
    for (int s = 0; s < 8; ++s)
#pragma unroll
        for (int r = 0; r < 4; ++r) {
            vals[s][r] = __expf(acc[s][r] * 0.125f);
            Es[(wave * 16 + q * 4 + r) * 128 + s * 16 + c] = fp8_enc(vals[s][r]);
        }
#pragma unroll
    for (int r = 0; r < 4; ++r) {
        float rs = 0.f;
#pragma unroll
        for (int s = 0; s < 8; ++s) rs += vals[s][r];
#pragma unroll
        for (int off = 8; off; off >>= 1) rs += __shfl_down(rs, off, 16);
        if (c == 0)
            rp[((size_t)h * 16 + blockIdx.x) * S_LEN + i0 + wave * 16 + q * 4 + r] = rs;
    }
    __syncthreads();
#pragma unroll
    for (int pp = 0; pp < 2; ++pp) {
        int row = pp * 32 + (threadIdx.x >> 3);
        *(uint4*)&E[((size_t)h * S_LEN + i0 + row) * S_LEN + j0 + (threadIdx.x & 7) * 16] =
            *(const uint4*)&Es[row * 128 + (threadIdx.x & 7) * 16];
    }
}

// ---------------------------------------------------------------------------
// tp[h][chunk][j] = sum_{i in 32-row chunk} E[h][i][j]*a[h][i]
// use_rp: derive a for this chunk from rp (fused first row pass, a=mu/rowsum)
// grid (64, 12), block 128
__global__ __launch_bounds__(128) void col_part(
    const unsigned char* __restrict__ E, const float* __restrict__ a,
    const float* __restrict__ rp, float* __restrict__ tpart, int use_rp) {
    const int h = blockIdx.y, chunk = blockIdx.x;
    __shared__ float la[32];
    if (use_rp) {
        int row = threadIdx.x >> 2, seg = threadIdx.x & 3;
        float s = 0.f;
#pragma unroll
        for (int jt = 0; jt < 4; ++jt)
            s += rp[((size_t)h * 16 + seg * 4 + jt) * S_LEN + chunk * 32 + row];
        s += __shfl_down(s, 2, 4);
        s += __shfl_down(s, 1, 4);
        if (seg == 0) la[row] = MU / s;
    } else {
        if (threadIdx.x < 32) la[threadIdx.x] = a[(size_t)h * S_LEN + chunk * 32 + threadIdx.x];
    }
    __syncthreads();
    const int j0 = threadIdx.x * 16;
    const unsigned char* eb = E + ((size_t)h * S_LEN + chunk * 32) * S_LEN + j0;
    float acc[16] = {};
    for (int ii = 0; ii < 32; ii += 8) {
        uint4 e[8];
#pragma unroll
        for (int t = 0; t < 8; ++t) e[t] = *(const uint4*)&eb[(size_t)(ii + t) * S_LEN];
#pragma unroll
        for (int t = 0; t < 8; ++t) {
            float ai = la[ii + t];
            unsigned w[4] = {e[t].x, e[t].y, e[t].z, e[t].w};
#pragma unroll
            for (int k = 0; k < 4; ++k) {
                f32x2 lo = fp8_dec_lo(w[k]), hi = fp8_dec_hi(w[k]);
                acc[k * 4 + 0] += lo.x * ai; acc[k * 4 + 1] += lo.y * ai;
                acc[k * 4 + 2] += hi.x * ai; acc[k * 4 + 3] += hi.y * ai;
            }
        }
    }
    float* outp = tpart + ((size_t)h * 64 + chunk) * S_LEN + j0;
#pragma unroll
    for (int k = 0; k < 4; ++k) {
        float4 o = {acc[k * 4], acc[k * 4 + 1], acc[k * 4 + 2], acc[k * 4 + 3]};
        *(float4*)&outp[k * 4] = o;
    }
}

// b[h][j] = mu / sum_chunk tp.  grid (NH*S/256), block 256
__global__ __launch_bounds__(256) void col_combine(
    const float* __restrict__ tpart, float* __restrict__ bout) {
    int g = blockIdx.x * 256 + threadIdx.x;
    int h = g >> 11, j = g & 2047;
    float s = 0.f;
#pragma unroll 8
    for (int c = 0; c < 64; ++c) s += tpart[((size_t)h * 64 + c) * S_LEN + j];
    bout[g] = MU / s;
}

// ---------------------------------------------------------------------------
// a[h][i] = mu / sum_j E[h][i][j]*b[h][j].  grid (S/4, 12), block 256
__global__ __launch_bounds__(256) void row_gemv(
    const unsigned char* __restrict__ E, const float* __restrict__ bvec,
    float* __restrict__ aout) {
    const int h = blockIdx.y;
    const int wave = threadIdx.x >> 6, lane = threadIdx.x & 63;
    const int row = blockIdx.x * 4 + wave;
    const unsigned char* er = E + ((size_t)h * S_LEN + row) * S_LEN;
    const float* bh = bvec + (size_t)h * S_LEN;
    float sum = 0.f;
#pragma unroll
    for (int ch = 0; ch < 2; ++ch) {
        int j = ch * 1024 + lane * 16;
        uint4 e = *(const uint4*)&er[j];
        unsigned w[4] = {e.x, e.y, e.z, e.w};
#pragma unroll
        for (int k = 0; k < 4; ++k) {
            f32x2 lo = fp8_dec_lo(w[k]), hi = fp8_dec_hi(w[k]);
            float4 b0 = *(const float4*)&bh[j + k * 4];
            sum += lo.x * b0.x + lo.y * b0.y + hi.x * b0.z + hi.y * b0.w;
        }
    }
#pragma unroll
    for (int off = 32; off; off >>= 1) sum += __shfl_down(sum, off, 64);
    if (lane == 0) aout[(size_t)h * S_LEN + row] = MU / sum;
}

// ---------------------------------------------------------------------------
// V't[h][d][j] = fp8( b[h][j] * V[h][j][d] ), V bf16.  grid (S/64, 12), 256
__global__ __launch_bounds__(256) void scale_v(
    const unsigned short* __restrict__ Vb, const float* __restrict__ b,
    unsigned char* __restrict__ Vt) {
    const int h = blockIdx.y, j0 = blockIdx.x * 64;
    __shared__ unsigned char t[64][80];
    {
        const int r = threadIdx.x >> 2, dc = (threadIdx.x & 3) * 16;
        float bj = b[(size_t)h * S_LEN + j0 + r];
        const unsigned short* vrow = Vb + ((size_t)h * S_LEN + j0 + r) * HD + dc;
#pragma unroll
        for (int k = 0; k < 16; ++k) t[dc + k][r] = fp8_enc(bf2f(vrow[k]) * bj);
    }
    __syncthreads();
    const int d = threadIdx.x >> 2, jc = (threadIdx.x & 3) * 16;
    unsigned char* out = Vt + ((size_t)h * HD + d) * S_LEN + j0 + jc;
    *(uint4*)out = *(const uint4*)&t[d][jc];
}

// ---------------------------------------------------------------------------
// ctx[i][h*64+d] = a_i*n * sum_j E[h][i][j]*V't[h][d][j].  fp8 MFMA,
// 4-way j-split, pipelined.  grid (128, 12), block 256
__global__ __launch_bounds__(256) void attn_av(
    const unsigned char* __restrict__ E, const float* __restrict__ a,
    const unsigned char* __restrict__ Vt, unsigned short* __restrict__ ctxb) {
    const int h = blockIdx.y;
    const int wave = threadIdx.x >> 6, lane = threadIdx.x & 63;
    const int q = lane >> 4, c = lane & 15;
    const int i0 = blockIdx.x * 16;
    const unsigned char* Eh = E + (size_t)h * S_LEN * S_LEN + (size_t)(i0 + c) * S_LEN;
    const unsigned char* Vh = Vt + (size_t)h * HD * S_LEN;
    const int jb = wave * 512;
    f32x4 acc[4] = {};
    i64_t av = *(const i64_t*)&Eh[jb + q * 8];
    i64_t bv[4];
#pragma unroll
    for (int s = 0; s < 4; ++s) bv[s] = *(const i64_t*)&Vh[(size_t)(s * 16 + c) * S_LEN + jb + q * 8];
    for (int jt = jb; jt < jb + 512; jt += 32) {
        i64_t av_n = av, bn0 = bv[0], bn1 = bv[1], bn2 = bv[2], bn3 = bv[3];
        if (jt + 32 < jb + 512) {
            av_n = *(const i64_t*)&Eh[jt + 32 + q * 8];
            bn0 = *(const i64_t*)&Vh[(size_t)(0 * 16 + c) * S_LEN + jt + 32 + q * 8];
            bn1 = *(const i64_t*)&Vh[(size_t)(1 * 16 + c) * S_LEN + jt + 32 + q * 8];
            bn2 = *(const i64_t*)&Vh[(size_t)(2 * 16 + c) * S_LEN + jt + 32 + q * 8];
            bn3 = *(const i64_t*)&Vh[(size_t)(3 * 16 + c) * S_LEN + jt + 32 + q * 8];
        }
        acc[0] = __builtin_amdgcn_mfma_f32_16x16x32_fp8_fp8(av, bv[0], acc[0], 0, 0, 0);
        acc[1] = __builtin_amdgcn_mfma_f32_16x16x32_fp8_fp8(av, bv[1], acc[1], 0, 0, 0);
        acc[2] = __builtin_amdgcn_mfma_f32_16x16x32_fp8_fp8(av, bv[2], acc[2], 0, 0, 0);
        acc[3] = __builtin_amdgcn_mfma_f32_16x16x32_fp8_fp8(av, bv[3], acc[3], 0, 0, 0);
        av = av_n; bv[0] = bn0; bv[1] = bn1; bv[2] = bn2; bv[3] = bn3;
    }
    __shared__ float lred[4][16][64];
#pragma unroll
    for (int s = 0; s < 4; ++s)
#pragma unroll
        for (int r = 0; r < 4; ++r) lred[wave][s * 4 + r][lane] = acc[s][r];
    __syncthreads();
    if (wave == 0) {
        float ais[4];
#pragma unroll
        for (int r = 0; r < 4; ++r) ais[r] = a[(size_t)h * S_LEN + i0 + q * 4 + r] * 2048.f;
#pragma unroll
        for (int s = 0; s < 4; ++s)
#pragma unroll
            for (int r = 0; r < 4; ++r) {
                float v = ((lred[0][s * 4 + r][lane] + lred[1][s * 4 + r][lane]) +
                           (lred[2][s * 4 + r][lane] + lred[3][s * 4 + r][lane])) * ais[r];
                ctxb[(size_t)(i0 + q * 4 + r) * E_DIM + h * 64 + s * 16 + c] = f2bf(v);
            }
    }
}

// ---------------------------------------------------------------------------
// Y = ctx @ Wo + bo + X (fp32), gll staging, tile 128x64.  grid (12, 16), 256
__global__ __launch_bounds__(256) void out_gemm(
    const unsigned short* __restrict__ ctxb, const unsigned short* __restrict__ Wt,
    const float* __restrict__ bo, const float* __restrict__ X, float* __restrict__ Y) {
    __shared__ unsigned short As[128 * 64];
    __shared__ unsigned short Bs[64 * 64];
    __shared__ float Csf[64 * 64];
    const int n0 = blockIdx.x * 64;
    const int row0 = blockIdx.y * 128;
    const int tid = threadIdx.x;
    const int wave = tid >> 6, lane = tid & 63;
    const int wm = wave & 1, wn = wave >> 1;
    const int q = lane >> 4, c = lane & 15;
    const int lrow = lane >> 3, lk8 = (lane & 7) * 8;
    const unsigned short* Wo3 = Wt + (size_t)3 * E_DIM * E_DIM + (size_t)n0 * E_DIM;
    f32x4 acc[4][2] = {};
    for (int kt = 0; kt < E_DIM; kt += 64) {
        __syncthreads();
#if HAS_GLL
#pragma unroll
        for (int p = 0; p < 4; ++p)
            gll16(&ctxb[(size_t)(row0 + p * 32 + wave * 8 + lrow) * E_DIM + kt + lk8],
                  &As[(p * 32 + wave * 8) * 64]);
#pragma unroll
        for (int p = 0; p < 2; ++p)
            gll16(&Wo3[(size_t)(p * 32 + wave * 8 + lrow) * E_DIM + kt + lk8],
                  &Bs[(p * 32 + wave * 8) * 64]);
#else
        {
            uint4 ta[4], tb[2];
#pragma unroll
            for (int p = 0; p < 4; ++p)
                ta[p] = *(const uint4*)&ctxb[(size_t)(row0 + p * 32 + wave * 8 + lrow) * E_DIM + kt + lk8];
#pragma unroll
            for (int p = 0; p < 2; ++p)
                tb[p] = *(const uint4*)&Wo3[(size_t)(p * 32 + wave * 8 + lrow) * E_DIM + kt + lk8];
#pragma unroll
            for (int p = 0; p < 4; ++p) *(uint4*)&As[(p * 32 + wave * 8 + lrow) * 64 + lk8] = ta[p];
#pragma unroll
            for (int p = 0; p < 2; ++p) *(uint4*)&Bs[(p * 32 + wave * 8 + lrow) * 64 + lk8] = tb[p];
        }
#endif
        __syncthreads();
#pragma unroll
        for (int ks = 0; ks < 2; ++ks) {
            bf16x8 af[4], bfr[2];
#pragma unroll
            for (int mi = 0; mi < 4; ++mi)
                af[mi] = *(const bf16x8*)&As[(wm * 64 + mi * 16 + c) * 64 + ks * 32 + q * 8];
#pragma unroll
            for (int ni = 0; ni < 2; ++ni)
                bfr[ni] = *(const bf16x8*)&Bs[(wn * 32 + ni * 16 + c) * 64 + ks * 32 + q * 8];
#pragma unroll
            for (int mi = 0; mi < 4; ++mi)
#pragma unroll
                for (int ni = 0; ni < 2; ++ni)
                    acc[mi][ni] = __builtin_amdgcn_mfma_f32_16x16x32_bf16(
                        af[mi], bfr[ni], acc[mi][ni], 0, 0, 0);
        }
    }
#pragma unroll
    for (int pp = 0; pp < 2; ++pp) {
        __syncthreads();
        if (wm == pp) {
#pragma unroll
            for (int mi = 0; mi < 4; ++mi)
#pragma unroll
                for (int ni = 0; ni < 2; ++ni)
#pragma unroll
                    for (int r = 0; r < 4; ++r)
                        Csf[(mi * 16 + q * 4 + r) * 64 + wn * 32 + ni * 16 + c] = acc[mi][ni][r];
        }
        __syncthreads();
#pragma unroll
        for (int sp = 0; sp < 4; ++sp) {
            int row = sp * 16 + (tid >> 4);
            int col = (tid & 15) * 4;
            int grow = row0 + pp * 64 + row;
            float4 v = *(const float4*)&Csf[row * 64 + col];
            const float4 xr = *(const float4*)&X[(size_t)grow * E_DIM + n0 + col];
            const float4 bb = *(const float4*)&bo[n0 + col];
            float4 o = {v.x + bb.x + xr.x, v.y + bb.y + xr.y,
                        v.z + bb.z + xr.z, v.w + bb.w + xr.w};
            *(float4*)&Y[(size_t)grow * E_DIM + n0 + col] = o;
        }
    }
}

// ---------------------------------------------------------------------------
// LayerNorm per row.  grid (S), block 256
__global__ __launch_bounds__(256) void layernorm(
    const float* __restrict__ Y, const float* __restrict__ g,
    const float* __restrict__ b, float* __restrict__ out) {
    __shared__ float red[4];
    const int srow = blockIdx.x;
    const float* yr = Y + (size_t)srow * E_DIM;
    const int t = threadIdx.x;
    float xs[3];
    float sum = 0.f;
#pragma unroll
    for (int r = 0; r < 3; ++r) { xs[r] = yr[t + r * 256]; sum += xs[r]; }
#pragma unroll
    for (int off = 32; off; off >>= 1) sum += __shfl_down(sum, off, 64);
    if ((t & 63) == 0) red[t >> 6] = sum;
    __syncthreads();
    sum = red[0] + red[1] + red[2] + red[3];
    const float mu = sum * (1.f / 768.f);
    float vs = 0.f;
#pragma unroll
    for (int r = 0; r < 3; ++r) { float d = xs[r] - mu; vs += d * d; }
    __syncthreads();
#pragma unroll
    for (int off = 32; off; off >>= 1) vs += __shfl_down(vs, off, 64);
    if ((t & 63) == 0) red[t >> 6] = vs;
    __syncthreads();
    vs = red[0] + red[1] + red[2] + red[3];
    const float inv = rsqrtf(vs * (1.f / 768.f) + LN_EPS);
#pragma unroll
    for (int r = 0; r < 3; ++r) {
        int c = t + r * 256;
        out[(size_t)srow * E_DIM + c] = g[c] * (xs[r] - mu) * inv + b[c];
    }
}

// ---------------------------------------------------------------------------
extern "C" void kernel_launch(void* const* d_in, const int* in_sizes, int n_in,
                              void* d_out, int out_size, void* d_ws, size_t ws_size,
                              hipStream_t stream) {
    const float* X    = (const float*)d_in[0];
    const float* Wq   = (const float*)d_in[1];
    const float* bq   = (const float*)d_in[2];
    const float* Wk   = (const float*)d_in[3];
    const float* bk   = (const float*)d_in[4];
    const float* Wv   = (const float*)d_in[5];
    const float* bv   = (const float*)d_in[6];
    const float* Wo   = (const float*)d_in[7];
    const float* bo   = (const float*)d_in[8];
    const float* ln_g = (const float*)d_in[9];
    const float* ln_b = (const float*)d_in[10];
    float* out = (float*)d_out;

    char* p = (char*)d_ws;
    auto alloc = [&](size_t bytes) { char* r = p; p += (bytes + 255) & ~(size_t)255; return r; };
    unsigned short* Xb   = (unsigned short*)alloc((size_t)S_LEN * E_DIM * 2);
    unsigned short* Wt   = (unsigned short*)alloc((size_t)4 * E_DIM * E_DIM * 2);
    unsigned short* Qb   = (unsigned short*)alloc((size_t)NH * S_LEN * HD * 2);
    unsigned short* Kb   = (unsigned short*)alloc((size_t)NH * S_LEN * HD * 2);
    unsigned short* Vb   = (unsigned short*)alloc((size_t)NH * S_LEN * HD * 2);
    unsigned char*  E    = (unsigned char*)alloc((size_t)NH * S_LEN * S_LEN);   // 48 MB fp8
    float*          rp   = (float*)alloc((size_t)NH * 16 * S_LEN * 4);
    float*          av   = (float*)alloc((size_t)NH * S_LEN * 4);
    float*          bv_  = (float*)alloc((size_t)NH * S_LEN * 4);
    float*          tp   = (float*)alloc((size_t)NH * 64 * S_LEN * 4);
    unsigned char*  Vt   = (unsigned char*)alloc((size_t)NH * HD * S_LEN);
    unsigned short* ctxb = (unsigned short*)alloc((size_t)S_LEN * E_DIM * 2);
    float*          Y    = (float*)alloc((size_t)S_LEN * E_DIM * 4);

    quant_x<<<S_LEN * E_DIM / 1024, 256, 0, stream>>>(X, Xb);
    quant_wt<<<dim3(24, 24, 4), 256, 0, stream>>>(Wq, Wk, Wv, Wo, Wt);
    qkv_gemm<<<dim3(36, 16), 256, 0, stream>>>(Xb, Wt, bq, bk, bv, Qb, Kb, Vb);
    score_exp<<<dim3(16, 32, NH), 256, 0, stream>>>(Qb, Kb, E, rp);

    // Sinkhorn: a1 fused into first col pass via rp
    col_part<<<dim3(64, NH), 128, 0, stream>>>(E, av, rp, tp, 1);
    col_combine<<<NH * S_LEN / 256, 256, 0, stream>>>(tp, bv_);                  // b1
    row_gemv<<<dim3(S_LEN / 4, NH), 256, 0, stream>>>(E, bv_, av);               // a2
    col_part<<<dim3(64, NH), 128, 0, stream>>>(E, av, rp, tp, 0);
    col_combine<<<NH * S_LEN / 256, 256, 0, stream>>>(tp, bv_);                  // b2
    row_gemv<<<dim3(S_LEN / 4, NH), 256, 0, stream>>>(E, bv_, av);               // a3
    col_part<<<dim3(64, NH), 128, 0, stream>>>(E, av, rp, tp, 0);
    col_combine<<<NH * S_LEN / 256, 256, 0, stream>>>(tp, bv_);                  // b3

    scale_v<<<dim3(S_LEN / 64, NH), 256, 0, stream>>>(Vb, bv_, Vt);
    attn_av<<<dim3(S_LEN / 16, NH), 256, 0, stream>>>(E, av, Vt, ctxb);
    out_gemm<<<dim3(12, 16), 256, 0, stream>>>(ctxb, Wt, bo, X, Y);
    layernorm<<<S_LEN, 256, 0, stream>>>(Y, ln_g, ln_b, out);
}

// Round 7
// 278.005 us; speedup vs baseline: 2.4959x; 1.1158x over previous
//
#include <hip/hip_runtime.h>
#include <math.h>

#define S_LEN 2048
#define E_DIM 768
#define NH    12
#define HD    64
#define MU    (1.0f/2048.0f)
#define LN_EPS 1e-12f

typedef __attribute__((ext_vector_type(8))) short bf16x8;   // 8 bf16 (4 VGPRs)
typedef __attribute__((ext_vector_type(4))) float f32x4;    // MFMA accumulator
typedef __attribute__((ext_vector_type(2))) float f32x2;
typedef long i64_t;                                          // 8 fp8 (2 VGPRs)

__device__ __forceinline__ unsigned short f2bf(float f) {   // RNE fp32->bf16
    unsigned u = __float_as_uint(f);
    u += 0x7fff + ((u >> 16) & 1);
    return (unsigned short)(u >> 16);
}
__device__ __forceinline__ float bf2f(unsigned short h) {
    return __uint_as_float(((unsigned)h) << 16);
}

// ---- fp8 e4m3 (OCP) helpers ----
__device__ __forceinline__ unsigned char fp8_enc(float f) {
#if __has_builtin(__builtin_amdgcn_cvt_pk_fp8_f32)
    return (unsigned char)(__builtin_amdgcn_cvt_pk_fp8_f32(f, f, 0, false) & 0xFF);
#else
    float m = fminf(fabsf(f), 448.f) * 0x1p-120f;
    unsigned b = __float_as_uint(m);
    unsigned s = (__float_as_uint(f) >> 24) & 0x80u;
    b += 0x7FFFFu + ((b >> 20) & 1u);
    return (unsigned char)(s | ((b >> 20) & 0x7Fu));
#endif
}
// pack 4 floats -> 4 fp8 bytes in one dword
__device__ __forceinline__ unsigned fp8_pack4(float e0, float e1, float e2, float e3) {
#if __has_builtin(__builtin_amdgcn_cvt_pk_fp8_f32)
    unsigned u = __builtin_amdgcn_cvt_pk_fp8_f32(e0, e1, 0, false);
    u = __builtin_amdgcn_cvt_pk_fp8_f32(e2, e3, u, true);
    return u;
#else
    return (unsigned)fp8_enc(e0) | ((unsigned)fp8_enc(e1) << 8) |
           ((unsigned)fp8_enc(e2) << 16) | ((unsigned)fp8_enc(e3) << 24);
#endif
}
__device__ __forceinline__ float fp8_dec1(unsigned char u) {
    unsigned bits = ((u & 0x80u) << 24) | ((u & 0x7Fu) << 20);
    return __uint_as_float(bits) * 0x1p+120f;
}
__device__ __forceinline__ f32x2 fp8_dec_lo(unsigned v) {
#if __has_builtin(__builtin_amdgcn_cvt_pk_f32_fp8)
    return __builtin_amdgcn_cvt_pk_f32_fp8(v, false);
#else
    f32x2 r; r.x = fp8_dec1(v & 0xFF); r.y = fp8_dec1((v >> 8) & 0xFF); return r;
#endif
}
__device__ __forceinline__ f32x2 fp8_dec_hi(unsigned v) {
#if __has_builtin(__builtin_amdgcn_cvt_pk_f32_fp8)
    return __builtin_amdgcn_cvt_pk_f32_fp8(v, true);
#else
    f32x2 r; r.x = fp8_dec1((v >> 16) & 0xFF); r.y = fp8_dec1(v >> 24); return r;
#endif
}

// ---- async global->LDS, 16 B per lane (dest = wave-uniform base + lane*16) ----
#if defined(__has_builtin)
#if __has_builtin(__builtin_amdgcn_global_load_lds)
#define HAS_GLL 1
#endif
#endif
#if HAS_GLL
__device__ __forceinline__ void gll16(const void* g, void* l) {
    __builtin_amdgcn_global_load_lds(
        (__attribute__((address_space(1))) void*)(void*)g,
        (__attribute__((address_space(3))) void*)l, 16, 0, 0);
}
#endif

// ---------------------------------------------------------------------------
__global__ __launch_bounds__(256) void quant_x(const float* __restrict__ X,
                                               unsigned short* __restrict__ Xb) {
    int i = blockIdx.x * 256 + threadIdx.x;
    const float4 v = ((const float4*)X)[i];
    ushort4 o = { f2bf(v.x), f2bf(v.y), f2bf(v.z), f2bf(v.w) };
    ((ushort4*)Xb)[i] = o;
}

// W[k][n] fp32 -> Wt[z][n][k] bf16.  grid (24,24,4), block 256
__global__ __launch_bounds__(256) void quant_wt(
    const float* __restrict__ W0, const float* __restrict__ W1,
    const float* __restrict__ W2, const float* __restrict__ W3,
    unsigned short* __restrict__ Wt) {
    const float* W = (blockIdx.z == 0) ? W0 : (blockIdx.z == 1) ? W1
                   : (blockIdx.z == 2) ? W2 : W3;
    __shared__ unsigned short t[32][33];
    const int n0 = blockIdx.x * 32, k0 = blockIdx.y * 32;
    const int c = threadIdx.x & 31, r8 = threadIdx.x >> 5;
#pragma unroll
    for (int rr = 0; rr < 32; rr += 8) {
        int k = k0 + r8 + rr;
        t[c][r8 + rr] = f2bf(W[(size_t)k * E_DIM + n0 + c]);
    }
    __syncthreads();
    unsigned short* out = Wt + (size_t)blockIdx.z * E_DIM * E_DIM;
#pragma unroll
    for (int rr = 0; rr < 32; rr += 8) {
        int n = n0 + r8 + rr;
        out[(size_t)n * E_DIM + k0 + c] = t[r8 + rr][c];
    }
}

// ---------------------------------------------------------------------------
// Fused QKV GEMM, global_load_lds staging, tile 128x64, BK=64.
// grid (36 n-tiles, 16 row-tiles), block 256.  All outputs bf16 [h][s][64].
__global__ __launch_bounds__(256) void qkv_gemm(
    const unsigned short* __restrict__ Xb, const unsigned short* __restrict__ Wt,
    const float* __restrict__ bq, const float* __restrict__ bk, const float* __restrict__ bv,
    unsigned short* __restrict__ Qb, unsigned short* __restrict__ Kb,
    unsigned short* __restrict__ Vb) {
    __shared__ unsigned short As[128 * 64];     // unpadded: required by gll
    __shared__ unsigned short Bs[64 * 64];
    const int n0 = blockIdx.x * 64;
    const int row0 = blockIdx.y * 128;
    const int tid = threadIdx.x;
    const int wave = tid >> 6, lane = tid & 63;
    const int wm = wave & 1, wn = wave >> 1;
    const int q = lane >> 4, c = lane & 15;
    const int lrow = lane >> 3, lk8 = (lane & 7) * 8;
    const unsigned short* Wb = Wt + (size_t)n0 * E_DIM;
    f32x4 acc[4][2] = {};
    for (int kt = 0; kt < E_DIM; kt += 64) {
        __syncthreads();
#if HAS_GLL
#pragma unroll
        for (int p = 0; p < 4; ++p)
            gll16(&Xb[(size_t)(row0 + p * 32 + wave * 8 + lrow) * E_DIM + kt + lk8],
                  &As[(p * 32 + wave * 8) * 64]);
#pragma unroll
        for (int p = 0; p < 2; ++p)
            gll16(&Wb[(size_t)(p * 32 + wave * 8 + lrow) * E_DIM + kt + lk8],
                  &Bs[(p * 32 + wave * 8) * 64]);
#else
        {
            uint4 ta[4], tb[2];
#pragma unroll
            for (int p = 0; p < 4; ++p)
                ta[p] = *(const uint4*)&Xb[(size_t)(row0 + p * 32 + wave * 8 + lrow) * E_DIM + kt + lk8];
#pragma unroll
            for (int p = 0; p < 2; ++p)
                tb[p] = *(const uint4*)&Wb[(size_t)(p * 32 + wave * 8 + lrow) * E_DIM + kt + lk8];
#pragma unroll
            for (int p = 0; p < 4; ++p) *(uint4*)&As[(p * 32 + wave * 8 + lrow) * 64 + lk8] = ta[p];
#pragma unroll
            for (int p = 0; p < 2; ++p) *(uint4*)&Bs[(p * 32 + wave * 8 + lrow) * 64 + lk8] = tb[p];
        }
#endif
        __syncthreads();
#pragma unroll
        for (int ks = 0; ks < 2; ++ks) {
            bf16x8 af[4], bfr[2];
#pragma unroll
            for (int mi = 0; mi < 4; ++mi)
                af[mi] = *(const bf16x8*)&As[(wm * 64 + mi * 16 + c) * 64 + ks * 32 + q * 8];
#pragma unroll
            for (int ni = 0; ni < 2; ++ni)
                bfr[ni] = *(const bf16x8*)&Bs[(wn * 32 + ni * 16 + c) * 64 + ks * 32 + q * 8];
#pragma unroll
            for (int mi = 0; mi < 4; ++mi)
#pragma unroll
                for (int ni = 0; ni < 2; ++ni)
                    acc[mi][ni] = __builtin_amdgcn_mfma_f32_16x16x32_bf16(
                        af[mi], bfr[ni], acc[mi][ni], 0, 0, 0);
        }
    }
    const int z = n0 / E_DIM;
    const int h = (n0 % E_DIM) >> 6;
    const float* bias = (z == 0) ? bq : (z == 1) ? bk : bv;
    unsigned short* outp = (z == 0) ? Qb : (z == 1) ? Kb : Vb;
    __syncthreads();
    unsigned short* Cs = As;                    // reuse 16 KB for repack
#pragma unroll
    for (int ni = 0; ni < 2; ++ni) {
        const int col = wn * 32 + ni * 16 + c;
        const float bb = bias[h * 64 + col];
#pragma unroll
        for (int mi = 0; mi < 4; ++mi)
#pragma unroll
            for (int r = 0; r < 4; ++r)
                Cs[(wm * 64 + mi * 16 + q * 4 + r) * 64 + col] = f2bf(acc[mi][ni][r] + bb);
    }
    __syncthreads();
#pragma unroll
    for (int pp = 0; pp < 4; ++pp) {
        int row = pp * 32 + (tid >> 3);
        *(uint4*)&outp[((size_t)h * S_LEN + row0 + row) * HD + (tid & 7) * 8] =
            *(const uint4*)&Cs[row * 64 + (tid & 7) * 8];
    }
}

// ---------------------------------------------------------------------------
// E = exp(QK^T/8) -> fp8.  SWAPPED operands (A=K, B=Q): D[m=j][n=i], so each
// lane's 4 acc values are 4 consecutive j of one row i -> dword packs, cheap
// in-lane row sums.  LDS-staged Q/K (HD=64 = full K-dim, staged once).
// grid (16 j-tiles(128), 32 i-tiles(64), 12 h), block 256.
__global__ __launch_bounds__(256) void score_exp(
    const unsigned short* __restrict__ Qb, const unsigned short* __restrict__ Kb,
    unsigned char* __restrict__ E, float* __restrict__ rp) {
    const int h = blockIdx.z;
    const int i0 = blockIdx.y * 64, j0 = blockIdx.x * 128;
    const int tid = threadIdx.x;
    const int wave = tid >> 6, lane = tid & 63;
    const int q = lane >> 4, c = lane & 15;
    __shared__ unsigned short Qs[64 * 64];
    __shared__ unsigned short Ks[128 * 64];
    __shared__ unsigned char  Es[64 * 144];     // row stride 144 B (pad: 2-way max)
    __shared__ float red[4][64];
    const unsigned short* Qh = Qb + (size_t)h * S_LEN * HD;
    const unsigned short* Kh = Kb + (size_t)h * S_LEN * HD;
    const int lrow = lane >> 3, lk8 = (lane & 7) * 8;
#if HAS_GLL
#pragma unroll
    for (int p = 0; p < 2; ++p)
        gll16(&Qh[(size_t)(i0 + p * 32 + wave * 8 + lrow) * HD + lk8],
              &Qs[(p * 32 + wave * 8) * 64]);
#pragma unroll
    for (int p = 0; p < 4; ++p)
        gll16(&Kh[(size_t)(j0 + p * 32 + wave * 8 + lrow) * HD + lk8],
              &Ks[(p * 32 + wave * 8) * 64]);
#else
    {
        uint4 tq[2], tk[4];
#pragma unroll
        for (int p = 0; p < 2; ++p)
            tq[p] = *(const uint4*)&Qh[(size_t)(i0 + p * 32 + wave * 8 + lrow) * HD + lk8];
#pragma unroll
        for (int p = 0; p < 4; ++p)
            tk[p] = *(const uint4*)&Kh[(size_t)(j0 + p * 32 + wave * 8 + lrow) * HD + lk8];
#pragma unroll
        for (int p = 0; p < 2; ++p) *(uint4*)&Qs[(p * 32 + wave * 8 + lrow) * 64 + lk8] = tq[p];
#pragma unroll
        for (int p = 0; p < 4; ++p) *(uint4*)&Ks[(p * 32 + wave * 8 + lrow) * 64 + lk8] = tk[p];
    }
#endif
    __syncthreads();
    f32x4 acc[2][4] = {};                       // [jt][it]; wave covers j = wave*32 + jt*16
#pragma unroll
    for (int dt = 0; dt < HD; dt += 32) {
        bf16x8 af[2], bq_[4];
#pragma unroll
        for (int jt = 0; jt < 2; ++jt)
            af[jt] = *(const bf16x8*)&Ks[(wave * 32 + jt * 16 + c) * 64 + dt + q * 8];
#pragma unroll
        for (int it = 0; it < 4; ++it)
            bq_[it] = *(const bf16x8*)&Qs[(it * 16 + c) * 64 + dt + q * 8];
#pragma unroll
        for (int jt = 0; jt < 2; ++jt)
#pragma unroll
            for (int it = 0; it < 4; ++it)
                acc[jt][it] = __builtin_amdgcn_mfma_f32_16x16x32_bf16(
                    af[jt], bq_[it], acc[jt][it], 0, 0, 0);
    }
    // exp, pack 4 j-bytes/dword, accumulate in-lane row sums (row i = it*16+c)
    float rsum[4] = {0.f, 0.f, 0.f, 0.f};
#pragma unroll
    for (int jt = 0; jt < 2; ++jt)
#pragma unroll
        for (int it = 0; it < 4; ++it) {
            float e0 = __expf(acc[jt][it][0] * 0.125f);
            float e1 = __expf(acc[jt][it][1] * 0.125f);
            float e2 = __expf(acc[jt][it][2] * 0.125f);
            float e3 = __expf(acc[jt][it][3] * 0.125f);
            rsum[it] += (e0 + e1) + (e2 + e3);
            *(unsigned*)&Es[(it * 16 + c) * 144 + wave * 32 + jt * 16 + q * 4] =
                fp8_pack4(e0, e1, e2, e3);
        }
#pragma unroll
    for (int it = 0; it < 4; ++it) {
        rsum[it] += __shfl_xor(rsum[it], 16, 64);
        rsum[it] += __shfl_xor(rsum[it], 32, 64);
    }
    if (q == 0) {
#pragma unroll
        for (int it = 0; it < 4; ++it) red[wave][it * 16 + c] = rsum[it];
    }
    __syncthreads();
    {   // coalesced full-line E stores: 4 threads cover one 128-B row
        const int row = tid >> 2, off = (tid & 3) * 32;
        uint4 v0 = *(const uint4*)&Es[row * 144 + off];
        uint4 v1 = *(const uint4*)&Es[row * 144 + off + 16];
        unsigned char* dst = E + ((size_t)h * S_LEN + i0 + row) * S_LEN + j0 + off;
        *(uint4*)dst = v0;
        *(uint4*)(dst + 16) = v1;
    }
    if (tid < 64)
        rp[((size_t)h * 16 + blockIdx.x) * S_LEN + i0 + tid] =
            (red[0][tid] + red[1][tid]) + (red[2][tid] + red[3][tid]);
}

// ---------------------------------------------------------------------------
// tp[h][chunk][j] = sum_{i in 32-row chunk} E[h][i][j]*a[h][i]
// use_rp: derive a for this chunk from rp (fused first row pass, a=mu/rowsum)
// grid (64, 12), block 128
__global__ __launch_bounds__(128) void col_part(
    const unsigned char* __restrict__ E, const float* __restrict__ a,
    const float* __restrict__ rp, float* __restrict__ tpart, int use_rp) {
    const int h = blockIdx.y, chunk = blockIdx.x;
    __shared__ float la[32];
    if (use_rp) {
        int row = threadIdx.x >> 2, seg = threadIdx.x & 3;
        float s = 0.f;
#pragma unroll
        for (int jt = 0; jt < 4; ++jt)
            s += rp[((size_t)h * 16 + seg * 4 + jt) * S_LEN + chunk * 32 + row];
        s += __shfl_down(s, 2, 4);
        s += __shfl_down(s, 1, 4);
        if (seg == 0) la[row] = MU / s;
    } else {
        if (threadIdx.x < 32) la[threadIdx.x] = a[(size_t)h * S_LEN + chunk * 32 + threadIdx.x];
    }
    __syncthreads();
    const int j0 = threadIdx.x * 16;
    const unsigned char* eb = E + ((size_t)h * S_LEN + chunk * 32) * S_LEN + j0;
    float acc[16] = {};
    for (int ii = 0; ii < 32; ii += 8) {
        uint4 e[8];
#pragma unroll
        for (int t = 0; t < 8; ++t) e[t] = *(const uint4*)&eb[(size_t)(ii + t) * S_LEN];
#pragma unroll
        for (int t = 0; t < 8; ++t) {
            float ai = la[ii + t];
            unsigned w[4] = {e[t].x, e[t].y, e[t].z, e[t].w};
#pragma unroll
            for (int k = 0; k < 4; ++k) {
                f32x2 lo = fp8_dec_lo(w[k]), hi = fp8_dec_hi(w[k]);
                acc[k * 4 + 0] += lo.x * ai; acc[k * 4 + 1] += lo.y * ai;
                acc[k * 4 + 2] += hi.x * ai; acc[k * 4 + 3] += hi.y * ai;
            }
        }
    }
    float* outp = tpart + ((size_t)h * 64 + chunk) * S_LEN + j0;
#pragma unroll
    for (int k = 0; k < 4; ++k) {
        float4 o = {acc[k * 4], acc[k * 4 + 1], acc[k * 4 + 2], acc[k * 4 + 3]};
        *(float4*)&outp[k * 4] = o;
    }
}

// b[h][j] = mu / sum_chunk tp.  grid (NH*S/256), block 256
__global__ __launch_bounds__(256) void col_combine(
    const float* __restrict__ tpart, float* __restrict__ bout) {
    int g = blockIdx.x * 256 + threadIdx.x;
    int h = g >> 11, j = g & 2047;
    float s = 0.f;
#pragma unroll 8
    for (int c = 0; c < 64; ++c) s += tpart[((size_t)h * 64 + c) * S_LEN + j];
    bout[g] = MU / s;
}

// ---------------------------------------------------------------------------
// a[h][i] = mu / sum_j E[h][i][j]*b[h][j].  grid (S/4, 12), block 256
__global__ __launch_bounds__(256) void row_gemv(
    const unsigned char* __restrict__ E, const float* __restrict__ bvec,
    float* __restrict__ aout) {
    const int h = blockIdx.y;
    const int wave = threadIdx.x >> 6, lane = threadIdx.x & 63;
    const int row = blockIdx.x * 4 + wave;
    const unsigned char* er = E + ((size_t)h * S_LEN + row) * S_LEN;
    const float* bh = bvec + (size_t)h * S_LEN;
    float sum = 0.f;
#pragma unroll
    for (int ch = 0; ch < 2; ++ch) {
        int j = ch * 1024 + lane * 16;
        uint4 e = *(const uint4*)&er[j];
        unsigned w[4] = {e.x, e.y, e.z, e.w};
#pragma unroll
        for (int k = 0; k < 4; ++k) {
            f32x2 lo = fp8_dec_lo(w[k]), hi = fp8_dec_hi(w[k]);
            float4 b0 = *(const float4*)&bh[j + k * 4];
            sum += lo.x * b0.x + lo.y * b0.y + hi.x * b0.z + hi.y * b0.w;
        }
    }
#pragma unroll
    for (int off = 32; off; off >>= 1) sum += __shfl_down(sum, off, 64);
    if (lane == 0) aout[(size_t)h * S_LEN + row] = MU / sum;
}

// ---------------------------------------------------------------------------
// V't[h][d][j] = fp8( b[h][j] * V[h][j][d] ), V bf16.  grid (S/64, 12), 256
__global__ __launch_bounds__(256) void scale_v(
    const unsigned short* __restrict__ Vb, const float* __restrict__ b,
    unsigned char* __restrict__ Vt) {
    const int h = blockIdx.y, j0 = blockIdx.x * 64;
    __shared__ unsigned char t[64][80];
    {
        const int r = threadIdx.x >> 2, dc = (threadIdx.x & 3) * 16;
        float bj = b[(size_t)h * S_LEN + j0 + r];
        const unsigned short* vrow = Vb + ((size_t)h * S_LEN + j0 + r) * HD + dc;
#pragma unroll
        for (int k = 0; k < 16; ++k) t[dc + k][r] = fp8_enc(bf2f(vrow[k]) * bj);
    }
    __syncthreads();
    const int d = threadIdx.x >> 2, jc = (threadIdx.x & 3) * 16;
    unsigned char* out = Vt + ((size_t)h * HD + d) * S_LEN + j0 + jc;
    *(uint4*)out = *(const uint4*)&t[d][jc];
}

// ---------------------------------------------------------------------------
// ctx[i][h*64+d] = a_i*n * sum_j E[h][i][j]*V't[h][d][j].  fp8 MFMA,
// 4-way j-split, pipelined.  grid (128, 12), block 256
__global__ __launch_bounds__(256) void attn_av(
    const unsigned char* __restrict__ E, const float* __restrict__ a,
    const unsigned char* __restrict__ Vt, unsigned short* __restrict__ ctxb) {
    const int h = blockIdx.y;
    const int wave = threadIdx.x >> 6, lane = threadIdx.x & 63;
    const int q = lane >> 4, c = lane & 15;
    const int i0 = blockIdx.x * 16;
    const unsigned char* Eh = E + (size_t)h * S_LEN * S_LEN + (size_t)(i0 + c) * S_LEN;
    const unsigned char* Vh = Vt + (size_t)h * HD * S_LEN;
    const int jb = wave * 512;
    f32x4 acc[4] = {};
    i64_t av = *(const i64_t*)&Eh[jb + q * 8];
    i64_t bv[4];
#pragma unroll
    for (int s = 0; s < 4; ++s) bv[s] = *(const i64_t*)&Vh[(size_t)(s * 16 + c) * S_LEN + jb + q * 8];
    for (int jt = jb; jt < jb + 512; jt += 32) {
        i64_t av_n = av, bn0 = bv[0], bn1 = bv[1], bn2 = bv[2], bn3 = bv[3];
        if (jt + 32 < jb + 512) {
            av_n = *(const i64_t*)&Eh[jt + 32 + q * 8];
            bn0 = *(const i64_t*)&Vh[(size_t)(0 * 16 + c) * S_LEN + jt + 32 + q * 8];
            bn1 = *(const i64_t*)&Vh[(size_t)(1 * 16 + c) * S_LEN + jt + 32 + q * 8];
            bn2 = *(const i64_t*)&Vh[(size_t)(2 * 16 + c) * S_LEN + jt + 32 + q * 8];
            bn3 = *(const i64_t*)&Vh[(size_t)(3 * 16 + c) * S_LEN + jt + 32 + q * 8];
        }
        acc[0] = __builtin_amdgcn_mfma_f32_16x16x32_fp8_fp8(av, bv[0], acc[0], 0, 0, 0);
        acc[1] = __builtin_amdgcn_mfma_f32_16x16x32_fp8_fp8(av, bv[1], acc[1], 0, 0, 0);
        acc[2] = __builtin_amdgcn_mfma_f32_16x16x32_fp8_fp8(av, bv[2], acc[2], 0, 0, 0);
        acc[3] = __builtin_amdgcn_mfma_f32_16x16x32_fp8_fp8(av, bv[3], acc[3], 0, 0, 0);
        av = av_n; bv[0] = bn0; bv[1] = bn1; bv[2] = bn2; bv[3] = bn3;
    }
    __shared__ float lred[4][16][64];
#pragma unroll
    for (int s = 0; s < 4; ++s)
#pragma unroll
        for (int r = 0; r < 4; ++r) lred[wave][s * 4 + r][lane] = acc[s][r];
    __syncthreads();
    if (wave == 0) {
        float ais[4];
#pragma unroll
        for (int r = 0; r < 4; ++r) ais[r] = a[(size_t)h * S_LEN + i0 + q * 4 + r] * 2048.f;
#pragma unroll
        for (int s = 0; s < 4; ++s)
#pragma unroll
            for (int r = 0; r < 4; ++r) {
                float v = ((lred[0][s * 4 + r][lane] + lred[1][s * 4 + r][lane]) +
                           (lred[2][s * 4 + r][lane] + lred[3][s * 4 + r][lane])) * ais[r];
                ctxb[(size_t)(i0 + q * 4 + r) * E_DIM + h * 64 + s * 16 + c] = f2bf(v);
            }
    }
}

// ---------------------------------------------------------------------------
// Y = ctx @ Wo + bo + X (fp32), gll staging, tile 128x64.  grid (12, 16), 256
__global__ __launch_bounds__(256) void out_gemm(
    const unsigned short* __restrict__ ctxb, const unsigned short* __restrict__ Wt,
    const float* __restrict__ bo, const float* __restrict__ X, float* __restrict__ Y) {
    __shared__ unsigned short As[128 * 64];
    __shared__ unsigned short Bs[64 * 64];
    __shared__ float Csf[64 * 64];
    const int n0 = blockIdx.x * 64;
    const int row0 = blockIdx.y * 128;
    const int tid = threadIdx.x;
    const int wave = tid >> 6, lane = tid & 63;
    const int wm = wave & 1, wn = wave >> 1;
    const int q = lane >> 4, c = lane & 15;
    const int lrow = lane >> 3, lk8 = (lane & 7) * 8;
    const unsigned short* Wo3 = Wt + (size_t)3 * E_DIM * E_DIM + (size_t)n0 * E_DIM;
    f32x4 acc[4][2] = {};
    for (int kt = 0; kt < E_DIM; kt += 64) {
        __syncthreads();
#if HAS_GLL
#pragma unroll
        for (int p = 0; p < 4; ++p)
            gll16(&ctxb[(size_t)(row0 + p * 32 + wave * 8 + lrow) * E_DIM + kt + lk8],
                  &As[(p * 32 + wave * 8) * 64]);
#pragma unroll
        for (int p = 0; p < 2; ++p)
            gll16(&Wo3[(size_t)(p * 32 + wave * 8 + lrow) * E_DIM + kt + lk8],
                  &Bs[(p * 32 + wave * 8) * 64]);
#else
        {
            uint4 ta[4], tb[2];
#pragma unroll
            for (int p = 0; p < 4; ++p)
                ta[p] = *(const uint4*)&ctxb[(size_t)(row0 + p * 32 + wave * 8 + lrow) * E_DIM + kt + lk8];
#pragma unroll
            for (int p = 0; p < 2; ++p)
                tb[p] = *(const uint4*)&Wo3[(size_t)(p * 32 + wave * 8 + lrow) * E_DIM + kt + lk8];
#pragma unroll
            for (int p = 0; p < 4; ++p) *(uint4*)&As[(p * 32 + wave * 8 + lrow) * 64 + lk8] = ta[p];
#pragma unroll
            for (int p = 0; p < 2; ++p) *(uint4*)&Bs[(p * 32 + wave * 8 + lrow) * 64 + lk8] = tb[p];
        }
#endif
        __syncthreads();
#pragma unroll
        for (int ks = 0; ks < 2; ++ks) {
            bf16x8 af[4], bfr[2];
#pragma unroll
            for (int mi = 0; mi < 4; ++mi)
                af[mi] = *(const bf16x8*)&As[(wm * 64 + mi * 16 + c) * 64 + ks * 32 + q * 8];
#pragma unroll
            for (int ni = 0; ni < 2; ++ni)
                bfr[ni] = *(const bf16x8*)&Bs[(wn * 32 + ni * 16 + c) * 64 + ks * 32 + q * 8];
#pragma unroll
            for (int mi = 0; mi < 4; ++mi)
#pragma unroll
                for (int ni = 0; ni < 2; ++ni)
                    acc[mi][ni] = __builtin_amdgcn_mfma_f32_16x16x32_bf16(
                        af[mi], bfr[ni], acc[mi][ni], 0, 0, 0);
        }
    }
#pragma unroll
    for (int pp = 0; pp < 2; ++pp) {
        __syncthreads();
        if (wm == pp) {
#pragma unroll
            for (int mi = 0; mi < 4; ++mi)
#pragma unroll
                for (int ni = 0; ni < 2; ++ni)
#pragma unroll
                    for (int r = 0; r < 4; ++r)
                        Csf[(mi * 16 + q * 4 + r) * 64 + wn * 32 + ni * 16 + c] = acc[mi][ni][r];
        }
        __syncthreads();
#pragma unroll
        for (int sp = 0; sp < 4; ++sp) {
            int row = sp * 16 + (tid >> 4);
            int col = (tid & 15) * 4;
            int grow = row0 + pp * 64 + row;
            float4 v = *(const float4*)&Csf[row * 64 + col];
            const float4 xr = *(const float4*)&X[(size_t)grow * E_DIM + n0 + col];
            const float4 bb = *(const float4*)&bo[n0 + col];
            float4 o = {v.x + bb.x + xr.x, v.y + bb.y + xr.y,
                        v.z + bb.z + xr.z, v.w + bb.w + xr.w};
            *(float4*)&Y[(size_t)grow * E_DIM + n0 + col] = o;
        }
    }
}

// ---------------------------------------------------------------------------
// LayerNorm per row.  grid (S), block 256
__global__ __launch_bounds__(256) void layernorm(
    const float* __restrict__ Y, const float* __restrict__ g,
    const float* __restrict__ b, float* __restrict__ out) {
    __shared__ float red[4];
    const int srow = blockIdx.x;
    const float* yr = Y + (size_t)srow * E_DIM;
    const int t = threadIdx.x;
    float xs[3];
    float sum = 0.f;
#pragma unroll
    for (int r = 0; r < 3; ++r) { xs[r] = yr[t + r * 256]; sum += xs[r]; }
#pragma unroll
    for (int off = 32; off; off >>= 1) sum += __shfl_down(sum, off, 64);
    if ((t & 63) == 0) red[t >> 6] = sum;
    __syncthreads();
    sum = red[0] + red[1] + red[2] + red[3];
    const float mu = sum * (1.f / 768.f);
    float vs = 0.f;
#pragma unroll
    for (int r = 0; r < 3; ++r) { float d = xs[r] - mu; vs += d * d; }
    __syncthreads();
#pragma unroll
    for (int off = 32; off; off >>= 1) vs += __shfl_down(vs, off, 64);
    if ((t & 63) == 0) red[t >> 6] = vs;
    __syncthreads();
    vs = red[0] + red[1] + red[2] + red[3];
    const float inv = rsqrtf(vs * (1.f / 768.f) + LN_EPS);
#pragma unroll
    for (int r = 0; r < 3; ++r) {
        int c = t + r * 256;
        out[(size_t)srow * E_DIM + c] = g[c] * (xs[r] - mu) * inv + b[c];
    }
}

// ---------------------------------------------------------------------------
extern "C" void kernel_launch(void* const* d_in, const int* in_sizes, int n_in,
                              void* d_out, int out_size, void* d_ws, size_t ws_size,
                              hipStream_t stream) {
    const float* X    = (const float*)d_in[0];
    const float* Wq   = (const float*)d_in[1];
    const float* bq   = (const float*)d_in[2];
    const float* Wk   = (const float*)d_in[3];
    const float* bk   = (const float*)d_in[4];
    const float* Wv   = (const float*)d_in[5];
    const float* bv   = (const float*)d_in[6];
    const float* Wo   = (const float*)d_in[7];
    const float* bo   = (const float*)d_in[8];
    const float* ln_g = (const float*)d_in[9];
    const float* ln_b = (const float*)d_in[10];
    float* out = (float*)d_out;

    char* p = (char*)d_ws;
    auto alloc = [&](size_t bytes) { char* r = p; p += (bytes + 255) & ~(size_t)255; return r; };
    unsigned short* Xb   = (unsigned short*)alloc((size_t)S_LEN * E_DIM * 2);
    unsigned short* Wt   = (unsigned short*)alloc((size_t)4 * E_DIM * E_DIM * 2);
    unsigned short* Qb   = (unsigned short*)alloc((size_t)NH * S_LEN * HD * 2);
    unsigned short* Kb   = (unsigned short*)alloc((size_t)NH * S_LEN * HD * 2);
    unsigned short* Vb   = (unsigned short*)alloc((size_t)NH * S_LEN * HD * 2);
    unsigned char*  E    = (unsigned char*)alloc((size_t)NH * S_LEN * S_LEN);   // 48 MB fp8
    float*          rp   = (float*)alloc((size_t)NH * 16 * S_LEN * 4);
    float*          av   = (float*)alloc((size_t)NH * S_LEN * 4);
    float*          bv_  = (float*)alloc((size_t)NH * S_LEN * 4);
    float*          tp   = (float*)alloc((size_t)NH * 64 * S_LEN * 4);
    unsigned char*  Vt   = (unsigned char*)alloc((size_t)NH * HD * S_LEN);
    unsigned short* ctxb = (unsigned short*)alloc((size_t)S_LEN * E_DIM * 2);
    float*          Y    = (float*)alloc((size_t)S_LEN * E_DIM * 4);

    quant_x<<<S_LEN * E_DIM / 1024, 256, 0, stream>>>(X, Xb);
    quant_wt<<<dim3(24, 24, 4), 256, 0, stream>>>(Wq, Wk, Wv, Wo, Wt);
    qkv_gemm<<<dim3(36, 16), 256, 0, stream>>>(Xb, Wt, bq, bk, bv, Qb, Kb, Vb);
    score_exp<<<dim3(16, 32, NH), 256, 0, stream>>>(Qb, Kb, E, rp);

    // Sinkhorn: a1 fused into first col pass via rp
    col_part<<<dim3(64, NH), 128, 0, stream>>>(E, av, rp, tp, 1);
    col_combine<<<NH * S_LEN / 256, 256, 0, stream>>>(tp, bv_);                  // b1
    row_gemv<<<dim3(S_LEN / 4, NH), 256, 0, stream>>>(E, bv_, av);               // a2
    col_part<<<dim3(64, NH), 128, 0, stream>>>(E, av, rp, tp, 0);
    col_combine<<<NH * S_LEN / 256, 256, 0, stream>>>(tp, bv_);                  // b2
    row_gemv<<<dim3(S_LEN / 4, NH), 256, 0, stream>>>(E, bv_, av);               // a3
    col_part<<<dim3(64, NH), 128, 0, stream>>>(E, av, rp, tp, 0);
    col_combine<<<NH * S_LEN / 256, 256, 0, stream>>>(tp, bv_);                  // b3

    scale_v<<<dim3(S_LEN / 64, NH), 256, 0, stream>>>(Vb, bv_, Vt);
    attn_av<<<dim3(S_LEN / 16, NH), 256, 0, stream>>>(E, av, Vt, ctxb);
    out_gemm<<<dim3(12, 16), 256, 0, stream>>>(ctxb, Wt, bo, X, Y);
    layernorm<<<S_LEN, 256, 0, stream>>>(Y, ln_g, ln_b, out);
}

// Round 8
// 252.661 us; speedup vs baseline: 2.7462x; 1.1003x over previous
//
#include <hip/hip_runtime.h>
#include <math.h>

#define S_LEN 2048
#define E_DIM 768
#define NH    12
#define HD    64
#define MU    (1.0f/2048.0f)
#define LN_EPS 1e-12f

typedef __attribute__((ext_vector_type(8))) short bf16x8;   // 8 bf16 (4 VGPRs)
typedef __attribute__((ext_vector_type(4))) float f32x4;    // MFMA accumulator
typedef __attribute__((ext_vector_type(2))) float f32x2;
typedef long i64_t;                                          // 8 fp8 (2 VGPRs)

__device__ __forceinline__ unsigned short f2bf(float f) {   // RNE fp32->bf16
    unsigned u = __float_as_uint(f);
    u += 0x7fff + ((u >> 16) & 1);
    return (unsigned short)(u >> 16);
}
__device__ __forceinline__ float bf2f(unsigned short h) {
    return __uint_as_float(((unsigned)h) << 16);
}

// ---- fp8 e4m3 (OCP) helpers ----
__device__ __forceinline__ unsigned char fp8_enc(float f) {
#if __has_builtin(__builtin_amdgcn_cvt_pk_fp8_f32)
    return (unsigned char)(__builtin_amdgcn_cvt_pk_fp8_f32(f, f, 0, false) & 0xFF);
#else
    float m = fminf(fabsf(f), 448.f) * 0x1p-120f;
    unsigned b = __float_as_uint(m);
    unsigned s = (__float_as_uint(f) >> 24) & 0x80u;
    b += 0x7FFFFu + ((b >> 20) & 1u);
    return (unsigned char)(s | ((b >> 20) & 0x7Fu));
#endif
}
// pack 4 floats -> 4 fp8 bytes in one dword
__device__ __forceinline__ unsigned fp8_pack4(float e0, float e1, float e2, float e3) {
#if __has_builtin(__builtin_amdgcn_cvt_pk_fp8_f32)
    unsigned u = __builtin_amdgcn_cvt_pk_fp8_f32(e0, e1, 0, false);
    u = __builtin_amdgcn_cvt_pk_fp8_f32(e2, e3, u, true);
    return u;
#else
    return (unsigned)fp8_enc(e0) | ((unsigned)fp8_enc(e1) << 8) |
           ((unsigned)fp8_enc(e2) << 16) | ((unsigned)fp8_enc(e3) << 24);
#endif
}
__device__ __forceinline__ float fp8_dec1(unsigned char u) {
    unsigned bits = ((u & 0x80u) << 24) | ((u & 0x7Fu) << 20);
    return __uint_as_float(bits) * 0x1p+120f;
}
__device__ __forceinline__ f32x2 fp8_dec_lo(unsigned v) {
#if __has_builtin(__builtin_amdgcn_cvt_pk_f32_fp8)
    return __builtin_amdgcn_cvt_pk_f32_fp8(v, false);
#else
    f32x2 r; r.x = fp8_dec1(v & 0xFF); r.y = fp8_dec1((v >> 8) & 0xFF); return r;
#endif
}
__device__ __forceinline__ f32x2 fp8_dec_hi(unsigned v) {
#if __has_builtin(__builtin_amdgcn_cvt_pk_f32_fp8)
    return __builtin_amdgcn_cvt_pk_f32_fp8(v, true);
#else
    f32x2 r; r.x = fp8_dec1((v >> 16) & 0xFF); r.y = fp8_dec1(v >> 24); return r;
#endif
}

// ---- async global->LDS, 16 B per lane (dest = wave-uniform base + lane*16) ----
#if defined(__has_builtin)
#if __has_builtin(__builtin_amdgcn_global_load_lds)
#define HAS_GLL 1
#endif
#endif
#if HAS_GLL
__device__ __forceinline__ void gll16(const void* g, void* l) {
    __builtin_amdgcn_global_load_lds(
        (__attribute__((address_space(1))) void*)(void*)g,
        (__attribute__((address_space(3))) void*)l, 16, 0, 0);
}
#endif

// ---------------------------------------------------------------------------
__global__ __launch_bounds__(256) void quant_x(const float* __restrict__ X,
                                               unsigned short* __restrict__ Xb) {
    int i = blockIdx.x * 256 + threadIdx.x;
    const float4 v = ((const float4*)X)[i];
    ushort4 o = { f2bf(v.x), f2bf(v.y), f2bf(v.z), f2bf(v.w) };
    ((ushort4*)Xb)[i] = o;
}

// W[k][n] fp32 -> Wt[z][n][k] bf16.  grid (24,24,4), block 256
__global__ __launch_bounds__(256) void quant_wt(
    const float* __restrict__ W0, const float* __restrict__ W1,
    const float* __restrict__ W2, const float* __restrict__ W3,
    unsigned short* __restrict__ Wt) {
    const float* W = (blockIdx.z == 0) ? W0 : (blockIdx.z == 1) ? W1
                   : (blockIdx.z == 2) ? W2 : W3;
    __shared__ unsigned short t[32][33];
    const int n0 = blockIdx.x * 32, k0 = blockIdx.y * 32;
    const int c = threadIdx.x & 31, r8 = threadIdx.x >> 5;
#pragma unroll
    for (int rr = 0; rr < 32; rr += 8) {
        int k = k0 + r8 + rr;
        t[c][r8 + rr] = f2bf(W[(size_t)k * E_DIM + n0 + c]);
    }
    __syncthreads();
    unsigned short* out = Wt + (size_t)blockIdx.z * E_DIM * E_DIM;
#pragma unroll
    for (int rr = 0; rr < 32; rr += 8) {
        int n = n0 + r8 + rr;
        out[(size_t)n * E_DIM + k0 + c] = t[r8 + rr][c];
    }
}

// ---------------------------------------------------------------------------
// Fused QKV GEMM, global_load_lds staging, tile 128x64, BK=64.
// grid (36 n-tiles, 16 row-tiles), block 256.  All outputs bf16 [h][s][64].
__global__ __launch_bounds__(256) void qkv_gemm(
    const unsigned short* __restrict__ Xb, const unsigned short* __restrict__ Wt,
    const float* __restrict__ bq, const float* __restrict__ bk, const float* __restrict__ bv,
    unsigned short* __restrict__ Qb, unsigned short* __restrict__ Kb,
    unsigned short* __restrict__ Vb) {
    __shared__ unsigned short As[128 * 64];     // unpadded: required by gll
    __shared__ unsigned short Bs[64 * 64];
    const int n0 = blockIdx.x * 64;
    const int row0 = blockIdx.y * 128;
    const int tid = threadIdx.x;
    const int wave = tid >> 6, lane = tid & 63;
    const int wm = wave & 1, wn = wave >> 1;
    const int q = lane >> 4, c = lane & 15;
    const int lrow = lane >> 3, lk8 = (lane & 7) * 8;
    const unsigned short* Wb = Wt + (size_t)n0 * E_DIM;
    f32x4 acc[4][2] = {};
    for (int kt = 0; kt < E_DIM; kt += 64) {
        __syncthreads();
#if HAS_GLL
#pragma unroll
        for (int p = 0; p < 4; ++p)
            gll16(&Xb[(size_t)(row0 + p * 32 + wave * 8 + lrow) * E_DIM + kt + lk8],
                  &As[(p * 32 + wave * 8) * 64]);
#pragma unroll
        for (int p = 0; p < 2; ++p)
            gll16(&Wb[(size_t)(p * 32 + wave * 8 + lrow) * E_DIM + kt + lk8],
                  &Bs[(p * 32 + wave * 8) * 64]);
#else
        {
            uint4 ta[4], tb[2];
#pragma unroll
            for (int p = 0; p < 4; ++p)
                ta[p] = *(const uint4*)&Xb[(size_t)(row0 + p * 32 + wave * 8 + lrow) * E_DIM + kt + lk8];
#pragma unroll
            for (int p = 0; p < 2; ++p)
                tb[p] = *(const uint4*)&Wb[(size_t)(p * 32 + wave * 8 + lrow) * E_DIM + kt + lk8];
#pragma unroll
            for (int p = 0; p < 4; ++p) *(uint4*)&As[(p * 32 + wave * 8 + lrow) * 64 + lk8] = ta[p];
#pragma unroll
            for (int p = 0; p < 2; ++p) *(uint4*)&Bs[(p * 32 + wave * 8 + lrow) * 64 + lk8] = tb[p];
        }
#endif
        __syncthreads();
#pragma unroll
        for (int ks = 0; ks < 2; ++ks) {
            bf16x8 af[4], bfr[2];
#pragma unroll
            for (int mi = 0; mi < 4; ++mi)
                af[mi] = *(const bf16x8*)&As[(wm * 64 + mi * 16 + c) * 64 + ks * 32 + q * 8];
#pragma unroll
            for (int ni = 0; ni < 2; ++ni)
                bfr[ni] = *(const bf16x8*)&Bs[(wn * 32 + ni * 16 + c) * 64 + ks * 32 + q * 8];
#pragma unroll
            for (int mi = 0; mi < 4; ++mi)
#pragma unroll
                for (int ni = 0; ni < 2; ++ni)
                    acc[mi][ni] = __builtin_amdgcn_mfma_f32_16x16x32_bf16(
                        af[mi], bfr[ni], acc[mi][ni], 0, 0, 0);
        }
    }
    const int z = n0 / E_DIM;
    const int h = (n0 % E_DIM) >> 6;
    const float* bias = (z == 0) ? bq : (z == 1) ? bk : bv;
    unsigned short* outp = (z == 0) ? Qb : (z == 1) ? Kb : Vb;
    __syncthreads();
    unsigned short* Cs = As;                    // reuse 16 KB for repack
#pragma unroll
    for (int ni = 0; ni < 2; ++ni) {
        const int col = wn * 32 + ni * 16 + c;
        const float bb = bias[h * 64 + col];
#pragma unroll
        for (int mi = 0; mi < 4; ++mi)
#pragma unroll
            for (int r = 0; r < 4; ++r)
                Cs[(wm * 64 + mi * 16 + q * 4 + r) * 64 + col] = f2bf(acc[mi][ni][r] + bb);
    }
    __syncthreads();
#pragma unroll
    for (int pp = 0; pp < 4; ++pp) {
        int row = pp * 32 + (tid >> 3);
        *(uint4*)&outp[((size_t)h * S_LEN + row0 + row) * HD + (tid & 7) * 8] =
            *(const uint4*)&Cs[row * 64 + (tid & 7) * 8];
    }
}

// ---------------------------------------------------------------------------
// E = exp(QK^T/8) -> fp8.  SWAPPED operands (A=K, B=Q): D[m=j][n=i].
// grid (16 j-tiles(128), 32 i-tiles(64), 12 h), block 256.
__global__ __launch_bounds__(256) void score_exp(
    const unsigned short* __restrict__ Qb, const unsigned short* __restrict__ Kb,
    unsigned char* __restrict__ E, float* __restrict__ rp) {
    const int h = blockIdx.z;
    const int i0 = blockIdx.y * 64, j0 = blockIdx.x * 128;
    const int tid = threadIdx.x;
    const int wave = tid >> 6, lane = tid & 63;
    const int q = lane >> 4, c = lane & 15;
    __shared__ unsigned short Qs[64 * 64];
    __shared__ unsigned short Ks[128 * 64];
    __shared__ unsigned char  Es[64 * 144];     // row stride 144 B (pad: 2-way max)
    __shared__ float red[4][64];
    const unsigned short* Qh = Qb + (size_t)h * S_LEN * HD;
    const unsigned short* Kh = Kb + (size_t)h * S_LEN * HD;
    const int lrow = lane >> 3, lk8 = (lane & 7) * 8;
#if HAS_GLL
#pragma unroll
    for (int p = 0; p < 2; ++p)
        gll16(&Qh[(size_t)(i0 + p * 32 + wave * 8 + lrow) * HD + lk8],
              &Qs[(p * 32 + wave * 8) * 64]);
#pragma unroll
    for (int p = 0; p < 4; ++p)
        gll16(&Kh[(size_t)(j0 + p * 32 + wave * 8 + lrow) * HD + lk8],
              &Ks[(p * 32 + wave * 8) * 64]);
#else
    {
        uint4 tq[2], tk[4];
#pragma unroll
        for (int p = 0; p < 2; ++p)
            tq[p] = *(const uint4*)&Qh[(size_t)(i0 + p * 32 + wave * 8 + lrow) * HD + lk8];
#pragma unroll
        for (int p = 0; p < 4; ++p)
            tk[p] = *(const uint4*)&Kh[(size_t)(j0 + p * 32 + wave * 8 + lrow) * HD + lk8];
#pragma unroll
        for (int p = 0; p < 2; ++p) *(uint4*)&Qs[(p * 32 + wave * 8 + lrow) * 64 + lk8] = tq[p];
#pragma unroll
        for (int p = 0; p < 4; ++p) *(uint4*)&Ks[(p * 32 + wave * 8 + lrow) * 64 + lk8] = tk[p];
    }
#endif
    __syncthreads();
    f32x4 acc[2][4] = {};                       // [jt][it]; wave covers j = wave*32 + jt*16
#pragma unroll
    for (int dt = 0; dt < HD; dt += 32) {
        bf16x8 af[2], bq_[4];
#pragma unroll
        for (int jt = 0; jt < 2; ++jt)
            af[jt] = *(const bf16x8*)&Ks[(wave * 32 + jt * 16 + c) * 64 + dt + q * 8];
#pragma unroll
        for (int it = 0; it < 4; ++it)
            bq_[it] = *(const bf16x8*)&Qs[(it * 16 + c) * 64 + dt + q * 8];
#pragma unroll
        for (int jt = 0; jt < 2; ++jt)
#pragma unroll
            for (int it = 0; it < 4; ++it)
                acc[jt][it] = __builtin_amdgcn_mfma_f32_16x16x32_bf16(
                    af[jt], bq_[it], acc[jt][it], 0, 0, 0);
    }
    float rsum[4] = {0.f, 0.f, 0.f, 0.f};
#pragma unroll
    for (int jt = 0; jt < 2; ++jt)
#pragma unroll
        for (int it = 0; it < 4; ++it) {
            float e0 = __expf(acc[jt][it][0] * 0.125f);
            float e1 = __expf(acc[jt][it][1] * 0.125f);
            float e2 = __expf(acc[jt][it][2] * 0.125f);
            float e3 = __expf(acc[jt][it][3] * 0.125f);
            rsum[it] += (e0 + e1) + (e2 + e3);
            *(unsigned*)&Es[(it * 16 + c) * 144 + wave * 32 + jt * 16 + q * 4] =
                fp8_pack4(e0, e1, e2, e3);
        }
#pragma unroll
    for (int it = 0; it < 4; ++it) {
        rsum[it] += __shfl_xor(rsum[it], 16, 64);
        rsum[it] += __shfl_xor(rsum[it], 32, 64);
    }
    if (q == 0) {
#pragma unroll
        for (int it = 0; it < 4; ++it) red[wave][it * 16 + c] = rsum[it];
    }
    __syncthreads();
    {   // coalesced full-line E stores: 4 threads cover one 128-B row
        const int row = tid >> 2, off = (tid & 3) * 32;
        uint4 v0 = *(const uint4*)&Es[row * 144 + off];
        uint4 v1 = *(const uint4*)&Es[row * 144 + off + 16];
        unsigned char* dst = E + ((size_t)h * S_LEN + i0 + row) * S_LEN + j0 + off;
        *(uint4*)dst = v0;
        *(uint4*)(dst + 16) = v1;
    }
    if (tid < 64)
        rp[((size_t)h * 16 + blockIdx.x) * S_LEN + i0 + tid] =
            (red[0][tid] + red[1][tid]) + (red[2][tid] + red[3][tid]);
}

// ---------------------------------------------------------------------------
// tp[h][chunk][j] = sum_{i in 32-row chunk} E[h][i][j]*a[h][i]
// use_rp: derive a for this chunk from rp (fused first row pass, a=mu/rowsum)
// grid (64, 12), block 128
__global__ __launch_bounds__(128) void col_part(
    const unsigned char* __restrict__ E, const float* __restrict__ a,
    const float* __restrict__ rp, float* __restrict__ tpart, int use_rp) {
    const int h = blockIdx.y, chunk = blockIdx.x;
    __shared__ float la[32];
    if (use_rp) {
        int row = threadIdx.x >> 2, seg = threadIdx.x & 3;
        float s = 0.f;
#pragma unroll
        for (int jt = 0; jt < 4; ++jt)
            s += rp[((size_t)h * 16 + seg * 4 + jt) * S_LEN + chunk * 32 + row];
        s += __shfl_down(s, 2, 4);
        s += __shfl_down(s, 1, 4);
        if (seg == 0) la[row] = MU / s;
    } else {
        if (threadIdx.x < 32) la[threadIdx.x] = a[(size_t)h * S_LEN + chunk * 32 + threadIdx.x];
    }
    __syncthreads();
    const int j0 = threadIdx.x * 16;
    const unsigned char* eb = E + ((size_t)h * S_LEN + chunk * 32) * S_LEN + j0;
    float acc[16] = {};
    for (int ii = 0; ii < 32; ii += 8) {
        uint4 e[8];
#pragma unroll
        for (int t = 0; t < 8; ++t) e[t] = *(const uint4*)&eb[(size_t)(ii + t) * S_LEN];
#pragma unroll
        for (int t = 0; t < 8; ++t) {
            float ai = la[ii + t];
            unsigned w[4] = {e[t].x, e[t].y, e[t].z, e[t].w};
#pragma unroll
            for (int k = 0; k < 4; ++k) {
                f32x2 lo = fp8_dec_lo(w[k]), hi = fp8_dec_hi(w[k]);
                acc[k * 4 + 0] += lo.x * ai; acc[k * 4 + 1] += lo.y * ai;
                acc[k * 4 + 2] += hi.x * ai; acc[k * 4 + 3] += hi.y * ai;
            }
        }
    }
    float* outp = tpart + ((size_t)h * 64 + chunk) * S_LEN + j0;
#pragma unroll
    for (int k = 0; k < 4; ++k) {
        float4 o = {acc[k * 4], acc[k * 4 + 1], acc[k * 4 + 2], acc[k * 4 + 3]};
        *(float4*)&outp[k * 4] = o;
    }
}

// b[h][j] = mu / sum_chunk tp.  grid (NH*S/256), block 256
__global__ __launch_bounds__(256) void col_combine(
    const float* __restrict__ tpart, float* __restrict__ bout) {
    int g = blockIdx.x * 256 + threadIdx.x;
    int h = g >> 11, j = g & 2047;
    float s = 0.f;
#pragma unroll 8
    for (int c = 0; c < 64; ++c) s += tpart[((size_t)h * 64 + c) * S_LEN + j];
    bout[g] = MU / s;
}

// ---------------------------------------------------------------------------
// Fused b3-combine + V scaling: b[j]=mu/sum tp, V't[h][d][j]=fp8(b[j]*V[j][d])
// grid (S/64 = 32, 12), block 256
__global__ __launch_bounds__(256) void col_combine_scale(
    const float* __restrict__ tpart, const unsigned short* __restrict__ Vb,
    unsigned char* __restrict__ Vt) {
    const int h = blockIdx.y, j0 = blockIdx.x * 64;
    __shared__ float lb[64];
    __shared__ unsigned char t[64][80];
    {
        int j = threadIdx.x >> 2, seg = threadIdx.x & 3;
        float s = 0.f;
#pragma unroll
        for (int cc = 0; cc < 16; ++cc)
            s += tpart[((size_t)h * 64 + seg * 16 + cc) * S_LEN + j0 + j];
        s += __shfl_down(s, 2, 4);
        s += __shfl_down(s, 1, 4);
        if (seg == 0) lb[j] = MU / s;
    }
    __syncthreads();
    {
        const int r = threadIdx.x >> 2, dc = (threadIdx.x & 3) * 16;
        float bj = lb[r];
        const unsigned short* vrow = Vb + ((size_t)h * S_LEN + j0 + r) * HD + dc;
#pragma unroll
        for (int k = 0; k < 16; ++k) t[dc + k][r] = fp8_enc(bf2f(vrow[k]) * bj);
    }
    __syncthreads();
    const int d = threadIdx.x >> 2, jc = (threadIdx.x & 3) * 16;
    unsigned char* out = Vt + ((size_t)h * HD + d) * S_LEN + j0 + jc;
    *(uint4*)out = *(const uint4*)&t[d][jc];
}

// ---------------------------------------------------------------------------
// a[h][i] = mu / sum_j E[h][i][j]*b[h][j].  grid (S/4, 12), block 256
__global__ __launch_bounds__(256) void row_gemv(
    const unsigned char* __restrict__ E, const float* __restrict__ bvec,
    float* __restrict__ aout) {
    const int h = blockIdx.y;
    const int wave = threadIdx.x >> 6, lane = threadIdx.x & 63;
    const int row = blockIdx.x * 4 + wave;
    const unsigned char* er = E + ((size_t)h * S_LEN + row) * S_LEN;
    const float* bh = bvec + (size_t)h * S_LEN;
    float sum = 0.f;
#pragma unroll
    for (int ch = 0; ch < 2; ++ch) {
        int j = ch * 1024 + lane * 16;
        uint4 e = *(const uint4*)&er[j];
        unsigned w[4] = {e.x, e.y, e.z, e.w};
#pragma unroll
        for (int k = 0; k < 4; ++k) {
            f32x2 lo = fp8_dec_lo(w[k]), hi = fp8_dec_hi(w[k]);
            float4 b0 = *(const float4*)&bh[j + k * 4];
            sum += lo.x * b0.x + lo.y * b0.y + hi.x * b0.z + hi.y * b0.w;
        }
    }
#pragma unroll
    for (int off = 32; off; off >>= 1) sum += __shfl_down(sum, off, 64);
    if (lane == 0) aout[(size_t)h * S_LEN + row] = MU / sum;
}

// ---------------------------------------------------------------------------
// ctx[i][h*64+d] = a_i*n * sum_j E[h][i][j]*V't[h][d][j].  fp8 MFMA.
// 32 i-rows/block (2 i-tiles/wave, V-frags shared), 4-way j-split,
// 2-stage pipeline with 12 loads in flight.  grid (64, 12), block 256.
__global__ __launch_bounds__(256) void attn_av(
    const unsigned char* __restrict__ E, const float* __restrict__ a,
    const unsigned char* __restrict__ Vt, unsigned short* __restrict__ ctxb) {
    const int h = blockIdx.y;
    const int wave = threadIdx.x >> 6, lane = threadIdx.x & 63;
    const int q = lane >> 4, c = lane & 15;
    const int i0 = blockIdx.x * 32;
    const unsigned char* e0 = E + (size_t)h * S_LEN * S_LEN + (size_t)(i0 + c) * S_LEN;
    const unsigned char* e1 = e0 + (size_t)16 * S_LEN;
    const unsigned char* Vh = Vt + (size_t)h * HD * S_LEN;
    const int jb = wave * 512;
    f32x4 acc[2][4] = {};
    i64_t eN[2][2], vN[4][2];
#pragma unroll
    for (int kk = 0; kk < 2; ++kk) {
        eN[0][kk] = *(const i64_t*)&e0[jb + kk * 32 + q * 8];
        eN[1][kk] = *(const i64_t*)&e1[jb + kk * 32 + q * 8];
#pragma unroll
        for (int s = 0; s < 4; ++s)
            vN[s][kk] = *(const i64_t*)&Vh[(size_t)(s * 16 + c) * S_LEN + jb + kk * 32 + q * 8];
    }
    for (int jt = jb; jt < jb + 512; jt += 64) {
        i64_t eC[2][2], vC[4][2];
#pragma unroll
        for (int kk = 0; kk < 2; ++kk) {
            eC[0][kk] = eN[0][kk]; eC[1][kk] = eN[1][kk];
#pragma unroll
            for (int s = 0; s < 4; ++s) vC[s][kk] = vN[s][kk];
        }
        if (jt + 64 < jb + 512) {
            const int jn = jt + 64;
#pragma unroll
            for (int kk = 0; kk < 2; ++kk) {
                eN[0][kk] = *(const i64_t*)&e0[jn + kk * 32 + q * 8];
                eN[1][kk] = *(const i64_t*)&e1[jn + kk * 32 + q * 8];
#pragma unroll
                for (int s = 0; s < 4; ++s)
                    vN[s][kk] = *(const i64_t*)&Vh[(size_t)(s * 16 + c) * S_LEN + jn + kk * 32 + q * 8];
            }
        }
#pragma unroll
        for (int kk = 0; kk < 2; ++kk)
#pragma unroll
            for (int it = 0; it < 2; ++it)
#pragma unroll
                for (int s = 0; s < 4; ++s)
                    acc[it][s] = __builtin_amdgcn_mfma_f32_16x16x32_fp8_fp8(
                        eC[it][kk], vC[s][kk], acc[it][s], 0, 0, 0);
    }
    __shared__ float lred[3][2][16][64];        // 24 KB
    if (wave != 0) {
#pragma unroll
        for (int it = 0; it < 2; ++it)
#pragma unroll
            for (int s = 0; s < 4; ++s)
#pragma unroll
                for (int r = 0; r < 4; ++r)
                    lred[wave - 1][it][s * 4 + r][lane] = acc[it][s][r];
    }
    __syncthreads();
    if (wave == 0) {
#pragma unroll
        for (int it = 0; it < 2; ++it) {
            float ais[4];
#pragma unroll
            for (int r = 0; r < 4; ++r)
                ais[r] = a[(size_t)h * S_LEN + i0 + it * 16 + q * 4 + r] * 2048.f;
#pragma unroll
            for (int s = 0; s < 4; ++s)
#pragma unroll
                for (int r = 0; r < 4; ++r) {
                    float v = acc[it][s][r] +
                              ((lred[0][it][s * 4 + r][lane] + lred[1][it][s * 4 + r][lane]) +
                               lred[2][it][s * 4 + r][lane]);
                    ctxb[(size_t)(i0 + it * 16 + q * 4 + r) * E_DIM + h * 64 + s * 16 + c] =
                        f2bf(v * ais[r]);
                }
        }
    }
}

// ---------------------------------------------------------------------------
// Y = ctx @ Wo + bo + X (fp32), gll staging, tile 128x64.  grid (12, 16), 256
__global__ __launch_bounds__(256) void out_gemm(
    const unsigned short* __restrict__ ctxb, const unsigned short* __restrict__ Wt,
    const float* __restrict__ bo, const float* __restrict__ X, float* __restrict__ Y) {
    __shared__ unsigned short As[128 * 64];
    __shared__ unsigned short Bs[64 * 64];
    __shared__ float Csf[64 * 64];
    const int n0 = blockIdx.x * 64;
    const int row0 = blockIdx.y * 128;
    const int tid = threadIdx.x;
    const int wave = tid >> 6, lane = tid & 63;
    const int wm = wave & 1, wn = wave >> 1;
    const int q = lane >> 4, c = lane & 15;
    const int lrow = lane >> 3, lk8 = (lane & 7) * 8;
    const unsigned short* Wo3 = Wt + (size_t)3 * E_DIM * E_DIM + (size_t)n0 * E_DIM;
    f32x4 acc[4][2] = {};
    for (int kt = 0; kt < E_DIM; kt += 64) {
        __syncthreads();
#if HAS_GLL
#pragma unroll
        for (int p = 0; p < 4; ++p)
            gll16(&ctxb[(size_t)(row0 + p * 32 + wave * 8 + lrow) * E_DIM + kt + lk8],
                  &As[(p * 32 + wave * 8) * 64]);
#pragma unroll
        for (int p = 0; p < 2; ++p)
            gll16(&Wo3[(size_t)(p * 32 + wave * 8 + lrow) * E_DIM + kt + lk8],
                  &Bs[(p * 32 + wave * 8) * 64]);
#else
        {
            uint4 ta[4], tb[2];
#pragma unroll
            for (int p = 0; p < 4; ++p)
                ta[p] = *(const uint4*)&ctxb[(size_t)(row0 + p * 32 + wave * 8 + lrow) * E_DIM + kt + lk8];
#pragma unroll
            for (int p = 0; p < 2; ++p)
                tb[p] = *(const uint4*)&Wo3[(size_t)(p * 32 + wave * 8 + lrow) * E_DIM + kt + lk8];
#pragma unroll
            for (int p = 0; p < 4; ++p) *(uint4*)&As[(p * 32 + wave * 8 + lrow) * 64 + lk8] = ta[p];
#pragma unroll
            for (int p = 0; p < 2; ++p) *(uint4*)&Bs[(p * 32 + wave * 8 + lrow) * 64 + lk8] = tb[p];
        }
#endif
        __syncthreads();
#pragma unroll
        for (int ks = 0; ks < 2; ++ks) {
            bf16x8 af[4], bfr[2];
#pragma unroll
            for (int mi = 0; mi < 4; ++mi)
                af[mi] = *(const bf16x8*)&As[(wm * 64 + mi * 16 + c) * 64 + ks * 32 + q * 8];
#pragma unroll
            for (int ni = 0; ni < 2; ++ni)
                bfr[ni] = *(const bf16x8*)&Bs[(wn * 32 + ni * 16 + c) * 64 + ks * 32 + q * 8];
#pragma unroll
            for (int mi = 0; mi < 4; ++mi)
#pragma unroll
                for (int ni = 0; ni < 2; ++ni)
                    acc[mi][ni] = __builtin_amdgcn_mfma_f32_16x16x32_bf16(
                        af[mi], bfr[ni], acc[mi][ni], 0, 0, 0);
        }
    }
#pragma unroll
    for (int pp = 0; pp < 2; ++pp) {
        __syncthreads();
        if (wm == pp) {
#pragma unroll
            for (int mi = 0; mi < 4; ++mi)
#pragma unroll
                for (int ni = 0; ni < 2; ++ni)
#pragma unroll
                    for (int r = 0; r < 4; ++r)
                        Csf[(mi * 16 + q * 4 + r) * 64 + wn * 32 + ni * 16 + c] = acc[mi][ni][r];
        }
        __syncthreads();
#pragma unroll
        for (int sp = 0; sp < 4; ++sp) {
            int row = sp * 16 + (tid >> 4);
            int col = (tid & 15) * 4;
            int grow = row0 + pp * 64 + row;
            float4 v = *(const float4*)&Csf[row * 64 + col];
            const float4 xr = *(const float4*)&X[(size_t)grow * E_DIM + n0 + col];
            const float4 bb = *(const float4*)&bo[n0 + col];
            float4 o = {v.x + bb.x + xr.x, v.y + bb.y + xr.y,
                        v.z + bb.z + xr.z, v.w + bb.w + xr.w};
            *(float4*)&Y[(size_t)grow * E_DIM + n0 + col] = o;
        }
    }
}

// ---------------------------------------------------------------------------
// LayerNorm per row.  grid (S), block 256
__global__ __launch_bounds__(256) void layernorm(
    const float* __restrict__ Y, const float* __restrict__ g,
    const float* __restrict__ b, float* __restrict__ out) {
    __shared__ float red[4];
    const int srow = blockIdx.x;
    const float* yr = Y + (size_t)srow * E_DIM;
    const int t = threadIdx.x;
    float xs[3];
    float sum = 0.f;
#pragma unroll
    for (int r = 0; r < 3; ++r) { xs[r] = yr[t + r * 256]; sum += xs[r]; }
#pragma unroll
    for (int off = 32; off; off >>= 1) sum += __shfl_down(sum, off, 64);
    if ((t & 63) == 0) red[t >> 6] = sum;
    __syncthreads();
    sum = red[0] + red[1] + red[2] + red[3];
    const float mu = sum * (1.f / 768.f);
    float vs = 0.f;
#pragma unroll
    for (int r = 0; r < 3; ++r) { float d = xs[r] - mu; vs += d * d; }
    __syncthreads();
#pragma unroll
    for (int off = 32; off; off >>= 1) vs += __shfl_down(vs, off, 64);
    if ((t & 63) == 0) red[t >> 6] = vs;
    __syncthreads();
    vs = red[0] + red[1] + red[2] + red[3];
    const float inv = rsqrtf(vs * (1.f / 768.f) + LN_EPS);
#pragma unroll
    for (int r = 0; r < 3; ++r) {
        int c = t + r * 256;
        out[(size_t)srow * E_DIM + c] = g[c] * (xs[r] - mu) * inv + b[c];
    }
}

// ---------------------------------------------------------------------------
extern "C" void kernel_launch(void* const* d_in, const int* in_sizes, int n_in,
                              void* d_out, int out_size, void* d_ws, size_t ws_size,
                              hipStream_t stream) {
    const float* X    = (const float*)d_in[0];
    const float* Wq   = (const float*)d_in[1];
    const float* bq   = (const float*)d_in[2];
    const float* Wk   = (const float*)d_in[3];
    const float* bk   = (const float*)d_in[4];
    const float* Wv   = (const float*)d_in[5];
    const float* bv   = (const float*)d_in[6];
    const float* Wo   = (const float*)d_in[7];
    const float* bo   = (const float*)d_in[8];
    const float* ln_g = (const float*)d_in[9];
    const float* ln_b = (const float*)d_in[10];
    float* out = (float*)d_out;

    char* p = (char*)d_ws;
    auto alloc = [&](size_t bytes) { char* r = p; p += (bytes + 255) & ~(size_t)255; return r; };
    unsigned short* Xb   = (unsigned short*)alloc((size_t)S_LEN * E_DIM * 2);
    unsigned short* Wt   = (unsigned short*)alloc((size_t)4 * E_DIM * E_DIM * 2);
    unsigned short* Qb   = (unsigned short*)alloc((size_t)NH * S_LEN * HD * 2);
    unsigned short* Kb   = (unsigned short*)alloc((size_t)NH * S_LEN * HD * 2);
    unsigned short* Vb   = (unsigned short*)alloc((size_t)NH * S_LEN * HD * 2);
    unsigned char*  E    = (unsigned char*)alloc((size_t)NH * S_LEN * S_LEN);   // 48 MB fp8
    float*          rp   = (float*)alloc((size_t)NH * 16 * S_LEN * 4);
    float*          av   = (float*)alloc((size_t)NH * S_LEN * 4);
    float*          bv_  = (float*)alloc((size_t)NH * S_LEN * 4);
    float*          tp   = (float*)alloc((size_t)NH * 64 * S_LEN * 4);
    unsigned char*  Vt   = (unsigned char*)alloc((size_t)NH * HD * S_LEN);
    unsigned short* ctxb = (unsigned short*)alloc((size_t)S_LEN * E_DIM * 2);
    float*          Y    = (float*)alloc((size_t)S_LEN * E_DIM * 4);

    quant_x<<<S_LEN * E_DIM / 1024, 256, 0, stream>>>(X, Xb);
    quant_wt<<<dim3(24, 24, 4), 256, 0, stream>>>(Wq, Wk, Wv, Wo, Wt);
    qkv_gemm<<<dim3(36, 16), 256, 0, stream>>>(Xb, Wt, bq, bk, bv, Qb, Kb, Vb);
    score_exp<<<dim3(16, 32, NH), 256, 0, stream>>>(Qb, Kb, E, rp);

    // Sinkhorn: a1 fused into first col pass via rp
    col_part<<<dim3(64, NH), 128, 0, stream>>>(E, av, rp, tp, 1);
    col_combine<<<NH * S_LEN / 256, 256, 0, stream>>>(tp, bv_);                  // b1
    row_gemv<<<dim3(S_LEN / 4, NH), 256, 0, stream>>>(E, bv_, av);               // a2
    col_part<<<dim3(64, NH), 128, 0, stream>>>(E, av, rp, tp, 0);
    col_combine<<<NH * S_LEN / 256, 256, 0, stream>>>(tp, bv_);                  // b2
    row_gemv<<<dim3(S_LEN / 4, NH), 256, 0, stream>>>(E, bv_, av);               // a3
    col_part<<<dim3(64, NH), 128, 0, stream>>>(E, av, rp, tp, 0);
    col_combine_scale<<<dim3(S_LEN / 64, NH), 256, 0, stream>>>(tp, Vb, Vt);     // b3 + scale V

    attn_av<<<dim3(S_LEN / 32, NH), 256, 0, stream>>>(E, av, Vt, ctxb);
    out_gemm<<<dim3(12, 16), 256, 0, stream>>>(ctxb, Wt, bo, X, Y);
    layernorm<<<S_LEN, 256, 0, stream>>>(Y, ln_g, ln_b, out);
}

// Round 9
// 246.781 us; speedup vs baseline: 2.8117x; 1.0238x over previous
//
#include <hip/hip_runtime.h>
#include <math.h>

#define S_LEN 2048
#define E_DIM 768
#define NH    12
#define HD    64
#define MU    (1.0f/2048.0f)
#define LN_EPS 1e-12f
#define CH    16            // sink_pass chunk rows
#define NCH   (S_LEN/CH)    // 128 chunks

typedef __attribute__((ext_vector_type(8))) short bf16x8;   // 8 bf16 (4 VGPRs)
typedef __attribute__((ext_vector_type(4))) float f32x4;    // MFMA accumulator
typedef __attribute__((ext_vector_type(2))) float f32x2;
typedef long i64_t;                                          // 8 fp8 (2 VGPRs)

__device__ __forceinline__ unsigned short f2bf(float f) {   // RNE fp32->bf16
    unsigned u = __float_as_uint(f);
    u += 0x7fff + ((u >> 16) & 1);
    return (unsigned short)(u >> 16);
}
__device__ __forceinline__ float bf2f(unsigned short h) {
    return __uint_as_float(((unsigned)h) << 16);
}

// ---- fp8 e4m3 (OCP) helpers ----
__device__ __forceinline__ unsigned char fp8_enc(float f) {
#if __has_builtin(__builtin_amdgcn_cvt_pk_fp8_f32)
    return (unsigned char)(__builtin_amdgcn_cvt_pk_fp8_f32(f, f, 0, false) & 0xFF);
#else
    float m = fminf(fabsf(f), 448.f) * 0x1p-120f;
    unsigned b = __float_as_uint(m);
    unsigned s = (__float_as_uint(f) >> 24) & 0x80u;
    b += 0x7FFFFu + ((b >> 20) & 1u);
    return (unsigned char)(s | ((b >> 20) & 0x7Fu));
#endif
}
// pack 4 floats -> 4 fp8 bytes in one dword
__device__ __forceinline__ unsigned fp8_pack4(float e0, float e1, float e2, float e3) {
#if __has_builtin(__builtin_amdgcn_cvt_pk_fp8_f32)
    unsigned u = __builtin_amdgcn_cvt_pk_fp8_f32(e0, e1, 0, false);
    u = __builtin_amdgcn_cvt_pk_fp8_f32(e2, e3, u, true);
    return u;
#else
    return (unsigned)fp8_enc(e0) | ((unsigned)fp8_enc(e1) << 8) |
           ((unsigned)fp8_enc(e2) << 16) | ((unsigned)fp8_enc(e3) << 24);
#endif
}
__device__ __forceinline__ float fp8_dec1(unsigned char u) {
    unsigned bits = ((u & 0x80u) << 24) | ((u & 0x7Fu) << 20);
    return __uint_as_float(bits) * 0x1p+120f;
}
__device__ __forceinline__ f32x2 fp8_dec_lo(unsigned v) {
#if __has_builtin(__builtin_amdgcn_cvt_pk_f32_fp8)
    return __builtin_amdgcn_cvt_pk_f32_fp8(v, false);
#else
    f32x2 r; r.x = fp8_dec1(v & 0xFF); r.y = fp8_dec1((v >> 8) & 0xFF); return r;
#endif
}
__device__ __forceinline__ f32x2 fp8_dec_hi(unsigned v) {
#if __has_builtin(__builtin_amdgcn_cvt_pk_f32_fp8)
    return __builtin_amdgcn_cvt_pk_f32_fp8(v, true);
#else
    f32x2 r; r.x = fp8_dec1((v >> 16) & 0xFF); r.y = fp8_dec1(v >> 24); return r;
#endif
}

// ---- async global->LDS, 16 B per lane (dest = wave-uniform base + lane*16) ----
#if defined(__has_builtin)
#if __has_builtin(__builtin_amdgcn_global_load_lds)
#define HAS_GLL 1
#endif
#endif
#if HAS_GLL
__device__ __forceinline__ void gll16(const void* g, void* l) {
    __builtin_amdgcn_global_load_lds(
        (__attribute__((address_space(1))) void*)(void*)g,
        (__attribute__((address_space(3))) void*)l, 16, 0, 0);
}
#endif

// ---------------------------------------------------------------------------
__global__ __launch_bounds__(256) void quant_x(const float* __restrict__ X,
                                               unsigned short* __restrict__ Xb) {
    int i = blockIdx.x * 256 + threadIdx.x;
    const float4 v = ((const float4*)X)[i];
    ushort4 o = { f2bf(v.x), f2bf(v.y), f2bf(v.z), f2bf(v.w) };
    ((ushort4*)Xb)[i] = o;
}

// W[k][n] fp32 -> Wt[z][n][k] bf16.  grid (24,24,4), block 256
__global__ __launch_bounds__(256) void quant_wt(
    const float* __restrict__ W0, const float* __restrict__ W1,
    const float* __restrict__ W2, const float* __restrict__ W3,
    unsigned short* __restrict__ Wt) {
    const float* W = (blockIdx.z == 0) ? W0 : (blockIdx.z == 1) ? W1
                   : (blockIdx.z == 2) ? W2 : W3;
    __shared__ unsigned short t[32][33];
    const int n0 = blockIdx.x * 32, k0 = blockIdx.y * 32;
    const int c = threadIdx.x & 31, r8 = threadIdx.x >> 5;
#pragma unroll
    for (int rr = 0; rr < 32; rr += 8) {
        int k = k0 + r8 + rr;
        t[c][r8 + rr] = f2bf(W[(size_t)k * E_DIM + n0 + c]);
    }
    __syncthreads();
    unsigned short* out = Wt + (size_t)blockIdx.z * E_DIM * E_DIM;
#pragma unroll
    for (int rr = 0; rr < 32; rr += 8) {
        int n = n0 + r8 + rr;
        out[(size_t)n * E_DIM + k0 + c] = t[r8 + rr][c];
    }
}

// ---------------------------------------------------------------------------
// Fused QKV GEMM, global_load_lds staging, tile 128x64, BK=64.
// grid (36 n-tiles, 16 row-tiles), block 256.  All outputs bf16 [h][s][64].
__global__ __launch_bounds__(256) void qkv_gemm(
    const unsigned short* __restrict__ Xb, const unsigned short* __restrict__ Wt,
    const float* __restrict__ bq, const float* __restrict__ bk, const float* __restrict__ bv,
    unsigned short* __restrict__ Qb, unsigned short* __restrict__ Kb,
    unsigned short* __restrict__ Vb) {
    __shared__ unsigned short As[128 * 64];     // unpadded: required by gll
    __shared__ unsigned short Bs[64 * 64];
    const int n0 = blockIdx.x * 64;
    const int row0 = blockIdx.y * 128;
    const int tid = threadIdx.x;
    const int wave = tid >> 6, lane = tid & 63;
    const int wm = wave & 1, wn = wave >> 1;
    const int q = lane >> 4, c = lane & 15;
    const int lrow = lane >> 3, lk8 = (lane & 7) * 8;
    const unsigned short* Wb = Wt + (size_t)n0 * E_DIM;
    f32x4 acc[4][2] = {};
    for (int kt = 0; kt < E_DIM; kt += 64) {
        __syncthreads();
#if HAS_GLL
#pragma unroll
        for (int p = 0; p < 4; ++p)
            gll16(&Xb[(size_t)(row0 + p * 32 + wave * 8 + lrow) * E_DIM + kt + lk8],
                  &As[(p * 32 + wave * 8) * 64]);
#pragma unroll
        for (int p = 0; p < 2; ++p)
            gll16(&Wb[(size_t)(p * 32 + wave * 8 + lrow) * E_DIM + kt + lk8],
                  &Bs[(p * 32 + wave * 8) * 64]);
#else
        {
            uint4 ta[4], tb[2];
#pragma unroll
            for (int p = 0; p < 4; ++p)
                ta[p] = *(const uint4*)&Xb[(size_t)(row0 + p * 32 + wave * 8 + lrow) * E_DIM + kt + lk8];
#pragma unroll
            for (int p = 0; p < 2; ++p)
                tb[p] = *(const uint4*)&Wb[(size_t)(p * 32 + wave * 8 + lrow) * E_DIM + kt + lk8];
#pragma unroll
            for (int p = 0; p < 4; ++p) *(uint4*)&As[(p * 32 + wave * 8 + lrow) * 64 + lk8] = ta[p];
#pragma unroll
            for (int p = 0; p < 2; ++p) *(uint4*)&Bs[(p * 32 + wave * 8 + lrow) * 64 + lk8] = tb[p];
        }
#endif
        __syncthreads();
#pragma unroll
        for (int ks = 0; ks < 2; ++ks) {
            bf16x8 af[4], bfr[2];
#pragma unroll
            for (int mi = 0; mi < 4; ++mi)
                af[mi] = *(const bf16x8*)&As[(wm * 64 + mi * 16 + c) * 64 + ks * 32 + q * 8];
#pragma unroll
            for (int ni = 0; ni < 2; ++ni)
                bfr[ni] = *(const bf16x8*)&Bs[(wn * 32 + ni * 16 + c) * 64 + ks * 32 + q * 8];
#pragma unroll
            for (int mi = 0; mi < 4; ++mi)
#pragma unroll
                for (int ni = 0; ni < 2; ++ni)
                    acc[mi][ni] = __builtin_amdgcn_mfma_f32_16x16x32_bf16(
                        af[mi], bfr[ni], acc[mi][ni], 0, 0, 0);
        }
    }
    const int z = n0 / E_DIM;
    const int h = (n0 % E_DIM) >> 6;
    const float* bias = (z == 0) ? bq : (z == 1) ? bk : bv;
    unsigned short* outp = (z == 0) ? Qb : (z == 1) ? Kb : Vb;
    __syncthreads();
    unsigned short* Cs = As;                    // reuse 16 KB for repack
#pragma unroll
    for (int ni = 0; ni < 2; ++ni) {
        const int col = wn * 32 + ni * 16 + c;
        const float bb = bias[h * 64 + col];
#pragma unroll
        for (int mi = 0; mi < 4; ++mi)
#pragma unroll
            for (int r = 0; r < 4; ++r)
                Cs[(wm * 64 + mi * 16 + q * 4 + r) * 64 + col] = f2bf(acc[mi][ni][r] + bb);
    }
    __syncthreads();
#pragma unroll
    for (int pp = 0; pp < 4; ++pp) {
        int row = pp * 32 + (tid >> 3);
        *(uint4*)&outp[((size_t)h * S_LEN + row0 + row) * HD + (tid & 7) * 8] =
            *(const uint4*)&Cs[row * 64 + (tid & 7) * 8];
    }
}

// ---------------------------------------------------------------------------
// E = exp(QK^T/8) -> fp8.  SWAPPED operands (A=K, B=Q): D[m=j][n=i].
// grid (16 j-tiles(128), 32 i-tiles(64), 12 h), block 256.
__global__ __launch_bounds__(256) void score_exp(
    const unsigned short* __restrict__ Qb, const unsigned short* __restrict__ Kb,
    unsigned char* __restrict__ E, float* __restrict__ rp) {
    const int h = blockIdx.z;
    const int i0 = blockIdx.y * 64, j0 = blockIdx.x * 128;
    const int tid = threadIdx.x;
    const int wave = tid >> 6, lane = tid & 63;
    const int q = lane >> 4, c = lane & 15;
    __shared__ unsigned short Qs[64 * 64];
    __shared__ unsigned short Ks[128 * 64];
    __shared__ unsigned char  Es[64 * 144];     // row stride 144 B (pad: 2-way max)
    __shared__ float red[4][64];
    const unsigned short* Qh = Qb + (size_t)h * S_LEN * HD;
    const unsigned short* Kh = Kb + (size_t)h * S_LEN * HD;
    const int lrow = lane >> 3, lk8 = (lane & 7) * 8;
#if HAS_GLL
#pragma unroll
    for (int p = 0; p < 2; ++p)
        gll16(&Qh[(size_t)(i0 + p * 32 + wave * 8 + lrow) * HD + lk8],
              &Qs[(p * 32 + wave * 8) * 64]);
#pragma unroll
    for (int p = 0; p < 4; ++p)
        gll16(&Kh[(size_t)(j0 + p * 32 + wave * 8 + lrow) * HD + lk8],
              &Ks[(p * 32 + wave * 8) * 64]);
#else
    {
        uint4 tq[2], tk[4];
#pragma unroll
        for (int p = 0; p < 2; ++p)
            tq[p] = *(const uint4*)&Qh[(size_t)(i0 + p * 32 + wave * 8 + lrow) * HD + lk8];
#pragma unroll
        for (int p = 0; p < 4; ++p)
            tk[p] = *(const uint4*)&Kh[(size_t)(j0 + p * 32 + wave * 8 + lrow) * HD + lk8];
#pragma unroll
        for (int p = 0; p < 2; ++p) *(uint4*)&Qs[(p * 32 + wave * 8 + lrow) * 64 + lk8] = tq[p];
#pragma unroll
        for (int p = 0; p < 4; ++p) *(uint4*)&Ks[(p * 32 + wave * 8 + lrow) * 64 + lk8] = tk[p];
    }
#endif
    __syncthreads();
    f32x4 acc[2][4] = {};                       // [jt][it]; wave covers j = wave*32 + jt*16
#pragma unroll
    for (int dt = 0; dt < HD; dt += 32) {
        bf16x8 af[2], bq_[4];
#pragma unroll
        for (int jt = 0; jt < 2; ++jt)
            af[jt] = *(const bf16x8*)&Ks[(wave * 32 + jt * 16 + c) * 64 + dt + q * 8];
#pragma unroll
        for (int it = 0; it < 4; ++it)
            bq_[it] = *(const bf16x8*)&Qs[(it * 16 + c) * 64 + dt + q * 8];
#pragma unroll
        for (int jt = 0; jt < 2; ++jt)
#pragma unroll
            for (int it = 0; it < 4; ++it)
                acc[jt][it] = __builtin_amdgcn_mfma_f32_16x16x32_bf16(
                    af[jt], bq_[it], acc[jt][it], 0, 0, 0);
    }
    float rsum[4] = {0.f, 0.f, 0.f, 0.f};
#pragma unroll
    for (int jt = 0; jt < 2; ++jt)
#pragma unroll
        for (int it = 0; it < 4; ++it) {
            float e0 = __expf(acc[jt][it][0] * 0.125f);
            float e1 = __expf(acc[jt][it][1] * 0.125f);
            float e2 = __expf(acc[jt][it][2] * 0.125f);
            float e3 = __expf(acc[jt][it][3] * 0.125f);
            rsum[it] += (e0 + e1) + (e2 + e3);
            *(unsigned*)&Es[(it * 16 + c) * 144 + wave * 32 + jt * 16 + q * 4] =
                fp8_pack4(e0, e1, e2, e3);
        }
#pragma unroll
    for (int it = 0; it < 4; ++it) {
        rsum[it] += __shfl_xor(rsum[it], 16, 64);
        rsum[it] += __shfl_xor(rsum[it], 32, 64);
    }
    if (q == 0) {
#pragma unroll
        for (int it = 0; it < 4; ++it) red[wave][it * 16 + c] = rsum[it];
    }
    __syncthreads();
    {   // coalesced full-line E stores: 4 threads cover one 128-B row
        const int row = tid >> 2, off = (tid & 3) * 32;
        uint4 v0 = *(const uint4*)&Es[row * 144 + off];
        uint4 v1 = *(const uint4*)&Es[row * 144 + off + 16];
        unsigned char* dst = E + ((size_t)h * S_LEN + i0 + row) * S_LEN + j0 + off;
        *(uint4*)dst = v0;
        *(uint4*)(dst + 16) = v1;
    }
    if (tid < 64)
        rp[((size_t)h * 16 + blockIdx.x) * S_LEN + i0 + tid] =
            (red[0][tid] + red[1][tid]) + (red[2][tid] + red[3][tid]);
}

// ---------------------------------------------------------------------------
// Fused Sinkhorn pass over a 16-row E chunk staged ONCE in LDS:
//   a[i] = mu / (E·b)[i]   (or from rp on the first pass)
//   tp[h][chunk][j] = sum_i a[i] * E[i][j]
// Optionally writes a out (needed for the last pass -> attn_av).
// grid (NCH=128, 12), block 256.  LDS ~40 KB -> 4 blocks/CU.
__global__ __launch_bounds__(256) void sink_pass(
    const unsigned char* __restrict__ E, const float* __restrict__ bvec,
    const float* __restrict__ rp, float* __restrict__ aout,
    float* __restrict__ tpart, int use_rp) {
    __shared__ unsigned char Ech[CH * 2048];    // 32 KB, contiguous (gll layout)
    __shared__ float lb[2048];                  // 8 KB
    __shared__ float la[CH];
    const int h = blockIdx.y, chunk = blockIdx.x;
    const int tid = threadIdx.x, wave = tid >> 6, lane = tid & 63;
    const unsigned char* gbase = E + ((size_t)h * S_LEN + chunk * CH) * S_LEN;
#if HAS_GLL
#pragma unroll
    for (int it = 0; it < 8; ++it)
        gll16(gbase + (wave * 8 + it) * 1024 + lane * 16, &Ech[(wave * 8 + it) * 1024]);
#else
#pragma unroll
    for (int it = 0; it < 8; ++it)
        *(uint4*)&Ech[(wave * 8 + it) * 1024 + lane * 16] =
            *(const uint4*)&gbase[(wave * 8 + it) * 1024 + lane * 16];
#endif
    if (!use_rp) {
        const float4* bg = (const float4*)(bvec + (size_t)h * S_LEN);
        ((float4*)lb)[tid] = bg[tid];
        ((float4*)lb)[tid + 256] = bg[tid + 256];
    }
    __syncthreads();
    if (use_rp) {
        if (tid < CH) {
            float s = 0.f;
#pragma unroll
            for (int jt = 0; jt < 16; ++jt)
                s += rp[((size_t)h * 16 + jt) * S_LEN + chunk * CH + tid];
            la[tid] = MU / s;
        }
        __syncthreads();
    } else {
        // wave w computes rows w*4 .. w*4+3 (full-row dot with b, shuffle-reduce)
#pragma unroll
        for (int rr = 0; rr < 4; ++rr) {
            const int row = wave * 4 + rr;
            const unsigned char* er = &Ech[row * 2048 + lane * 16];
            const float* bj = &lb[lane * 16];
            float s = 0.f;
#pragma unroll
            for (int half = 0; half < 2; ++half) {
                uint4 e = *(const uint4*)&er[half * 1024];
                const float* bh2 = &bj[half * 1024];
                unsigned w[4] = {e.x, e.y, e.z, e.w};
#pragma unroll
                for (int m = 0; m < 4; ++m) {
                    f32x2 lo = fp8_dec_lo(w[m]), hi = fp8_dec_hi(w[m]);
                    float4 b4 = *(const float4*)&bh2[m * 4];
                    s += lo.x * b4.x + lo.y * b4.y + hi.x * b4.z + hi.y * b4.w;
                }
            }
#pragma unroll
            for (int off = 32; off; off >>= 1) s += __shfl_xor(s, off, 64);
            if (lane == 0) la[row] = MU / s;
        }
        __syncthreads();
    }
    if (aout != nullptr && tid < CH)
        aout[(size_t)h * S_LEN + chunk * CH + tid] = la[tid];
    // column partials from the same LDS copy
    {
        const int j0 = tid * 8;
        float acc[8] = {};
#pragma unroll
        for (int r = 0; r < CH; ++r) {
            float ar = la[r];
            uint2 e = *(const uint2*)&Ech[r * 2048 + j0];
            f32x2 lo = fp8_dec_lo(e.x), hi = fp8_dec_hi(e.x);
            acc[0] += lo.x * ar; acc[1] += lo.y * ar; acc[2] += hi.x * ar; acc[3] += hi.y * ar;
            lo = fp8_dec_lo(e.y); hi = fp8_dec_hi(e.y);
            acc[4] += lo.x * ar; acc[5] += lo.y * ar; acc[6] += hi.x * ar; acc[7] += hi.y * ar;
        }
        float* outp = tpart + ((size_t)h * NCH + chunk) * S_LEN + j0;
        float4 o0 = {acc[0], acc[1], acc[2], acc[3]};
        float4 o1 = {acc[4], acc[5], acc[6], acc[7]};
        *(float4*)&outp[0] = o0;
        *(float4*)&outp[4] = o1;
    }
}

// b[h][j] = mu / sum_chunk tp.  grid (NH*S/256), block 256
__global__ __launch_bounds__(256) void col_combine(
    const float* __restrict__ tpart, float* __restrict__ bout) {
    int g = blockIdx.x * 256 + threadIdx.x;
    int h = g >> 11, j = g & 2047;
    float s = 0.f;
#pragma unroll 8
    for (int c = 0; c < NCH; ++c) s += tpart[((size_t)h * NCH + c) * S_LEN + j];
    bout[g] = MU / s;
}

// ---------------------------------------------------------------------------
// Fused b3-combine + V scaling: b[j]=mu/sum tp, V't[h][d][j]=fp8(b[j]*V[j][d])
// grid (S/64 = 32, 12), block 256
__global__ __launch_bounds__(256) void col_combine_scale(
    const float* __restrict__ tpart, const unsigned short* __restrict__ Vb,
    unsigned char* __restrict__ Vt) {
    const int h = blockIdx.y, j0 = blockIdx.x * 64;
    __shared__ float lb[64];
    __shared__ unsigned char t[64][80];
    {
        int j = threadIdx.x >> 2, seg = threadIdx.x & 3;
        float s = 0.f;
#pragma unroll
        for (int cc = 0; cc < NCH / 4; ++cc)
            s += tpart[((size_t)h * NCH + seg * (NCH / 4) + cc) * S_LEN + j0 + j];
        s += __shfl_down(s, 2, 4);
        s += __shfl_down(s, 1, 4);
        if (seg == 0) lb[j] = MU / s;
    }
    __syncthreads();
    {
        const int r = threadIdx.x >> 2, dc = (threadIdx.x & 3) * 16;
        float bj = lb[r];
        const unsigned short* vrow = Vb + ((size_t)h * S_LEN + j0 + r) * HD + dc;
#pragma unroll
        for (int k = 0; k < 16; ++k) t[dc + k][r] = fp8_enc(bf2f(vrow[k]) * bj);
    }
    __syncthreads();
    const int d = threadIdx.x >> 2, jc = (threadIdx.x & 3) * 16;
    unsigned char* out = Vt + ((size_t)h * HD + d) * S_LEN + j0 + jc;
    *(uint4*)out = *(const uint4*)&t[d][jc];
}

// ---------------------------------------------------------------------------
// ctx[i][h*64+d] = a_i*n * sum_j E[h][i][j]*V't[h][d][j].  fp8 MFMA.
// 32 i-rows/block (2 i-tiles/wave, V-frags shared), 4-way j-split,
// 2-stage pipeline with 12 loads in flight.  grid (64, 12), block 256.
__global__ __launch_bounds__(256) void attn_av(
    const unsigned char* __restrict__ E, const float* __restrict__ a,
    const unsigned char* __restrict__ Vt, unsigned short* __restrict__ ctxb) {
    const int h = blockIdx.y;
    const int wave = threadIdx.x >> 6, lane = threadIdx.x & 63;
    const int q = lane >> 4, c = lane & 15;
    const int i0 = blockIdx.x * 32;
    const unsigned char* e0 = E + (size_t)h * S_LEN * S_LEN + (size_t)(i0 + c) * S_LEN;
    const unsigned char* e1 = e0 + (size_t)16 * S_LEN;
    const unsigned char* Vh = Vt + (size_t)h * HD * S_LEN;
    const int jb = wave * 512;
    f32x4 acc[2][4] = {};
    i64_t eN[2][2], vN[4][2];
#pragma unroll
    for (int kk = 0; kk < 2; ++kk) {
        eN[0][kk] = *(const i64_t*)&e0[jb + kk * 32 + q * 8];
        eN[1][kk] = *(const i64_t*)&e1[jb + kk * 32 + q * 8];
#pragma unroll
        for (int s = 0; s < 4; ++s)
            vN[s][kk] = *(const i64_t*)&Vh[(size_t)(s * 16 + c) * S_LEN + jb + kk * 32 + q * 8];
    }
    for (int jt = jb; jt < jb + 512; jt += 64) {
        i64_t eC[2][2], vC[4][2];
#pragma unroll
        for (int kk = 0; kk < 2; ++kk) {
            eC[0][kk] = eN[0][kk]; eC[1][kk] = eN[1][kk];
#pragma unroll
            for (int s = 0; s < 4; ++s) vC[s][kk] = vN[s][kk];
        }
        if (jt + 64 < jb + 512) {
            const int jn = jt + 64;
#pragma unroll
            for (int kk = 0; kk < 2; ++kk) {
                eN[0][kk] = *(const i64_t*)&e0[jn + kk * 32 + q * 8];
                eN[1][kk] = *(const i64_t*)&e1[jn + kk * 32 + q * 8];
#pragma unroll
                for (int s = 0; s < 4; ++s)
                    vN[s][kk] = *(const i64_t*)&Vh[(size_t)(s * 16 + c) * S_LEN + jn + kk * 32 + q * 8];
            }
        }
#pragma unroll
        for (int kk = 0; kk < 2; ++kk)
#pragma unroll
            for (int it = 0; it < 2; ++it)
#pragma unroll
                for (int s = 0; s < 4; ++s)
                    acc[it][s] = __builtin_amdgcn_mfma_f32_16x16x32_fp8_fp8(
                        eC[it][kk], vC[s][kk], acc[it][s], 0, 0, 0);
    }
    __shared__ float lred[3][2][16][64];        // 24 KB
    if (wave != 0) {
#pragma unroll
        for (int it = 0; it < 2; ++it)
#pragma unroll
            for (int s = 0; s < 4; ++s)
#pragma unroll
                for (int r = 0; r < 4; ++r)
                    lred[wave - 1][it][s * 4 + r][lane] = acc[it][s][r];
    }
    __syncthreads();
    if (wave == 0) {
#pragma unroll
        for (int it = 0; it < 2; ++it) {
            float ais[4];
#pragma unroll
            for (int r = 0; r < 4; ++r)
                ais[r] = a[(size_t)h * S_LEN + i0 + it * 16 + q * 4 + r] * 2048.f;
#pragma unroll
            for (int s = 0; s < 4; ++s)
#pragma unroll
                for (int r = 0; r < 4; ++r) {
                    float v = acc[it][s][r] +
                              ((lred[0][it][s * 4 + r][lane] + lred[1][it][s * 4 + r][lane]) +
                               lred[2][it][s * 4 + r][lane]);
                    ctxb[(size_t)(i0 + it * 16 + q * 4 + r) * E_DIM + h * 64 + s * 16 + c] =
                        f2bf(v * ais[r]);
                }
        }
    }
}

// ---------------------------------------------------------------------------
// Y = ctx @ Wo + bo + X (fp32), gll staging, tile 128x64.  grid (12, 16), 256
__global__ __launch_bounds__(256) void out_gemm(
    const unsigned short* __restrict__ ctxb, const unsigned short* __restrict__ Wt,
    const float* __restrict__ bo, const float* __restrict__ X, float* __restrict__ Y) {
    __shared__ unsigned short As[128 * 64];
    __shared__ unsigned short Bs[64 * 64];
    __shared__ float Csf[64 * 64];
    const int n0 = blockIdx.x * 64;
    const int row0 = blockIdx.y * 128;
    const int tid = threadIdx.x;
    const int wave = tid >> 6, lane = tid & 63;
    const int wm = wave & 1, wn = wave >> 1;
    const int q = lane >> 4, c = lane & 15;
    const int lrow = lane >> 3, lk8 = (lane & 7) * 8;
    const unsigned short* Wo3 = Wt + (size_t)3 * E_DIM * E_DIM + (size_t)n0 * E_DIM;
    f32x4 acc[4][2] = {};
    for (int kt = 0; kt < E_DIM; kt += 64) {
        __syncthreads();
#if HAS_GLL
#pragma unroll
        for (int p = 0; p < 4; ++p)
            gll16(&ctxb[(size_t)(row0 + p * 32 + wave * 8 + lrow) * E_DIM + kt + lk8],
                  &As[(p * 32 + wave * 8) * 64]);
#pragma unroll
        for (int p = 0; p < 2; ++p)
            gll16(&Wo3[(size_t)(p * 32 + wave * 8 + lrow) * E_DIM + kt + lk8],
                  &Bs[(p * 32 + wave * 8) * 64]);
#else
        {
            uint4 ta[4], tb[2];
#pragma unroll
            for (int p = 0; p < 4; ++p)
                ta[p] = *(const uint4*)&ctxb[(size_t)(row0 + p * 32 + wave * 8 + lrow) * E_DIM + kt + lk8];
#pragma unroll
            for (int p = 0; p < 2; ++p)
                tb[p] = *(const uint4*)&Wo3[(size_t)(p * 32 + wave * 8 + lrow) * E_DIM + kt + lk8];
#pragma unroll
            for (int p = 0; p < 4; ++p) *(uint4*)&As[(p * 32 + wave * 8 + lrow) * 64 + lk8] = ta[p];
#pragma unroll
            for (int p = 0; p < 2; ++p) *(uint4*)&Bs[(p * 32 + wave * 8 + lrow) * 64 + lk8] = tb[p];
        }
#endif
        __syncthreads();
#pragma unroll
        for (int ks = 0; ks < 2; ++ks) {
            bf16x8 af[4], bfr[2];
#pragma unroll
            for (int mi = 0; mi < 4; ++mi)
                af[mi] = *(const bf16x8*)&As[(wm * 64 + mi * 16 + c) * 64 + ks * 32 + q * 8];
#pragma unroll
            for (int ni = 0; ni < 2; ++ni)
                bfr[ni] = *(const bf16x8*)&Bs[(wn * 32 + ni * 16 + c) * 64 + ks * 32 + q * 8];
#pragma unroll
            for (int mi = 0; mi < 4; ++mi)
#pragma unroll
                for (int ni = 0; ni < 2; ++ni)
                    acc[mi][ni] = __builtin_amdgcn_mfma_f32_16x16x32_bf16(
                        af[mi], bfr[ni], acc[mi][ni], 0, 0, 0);
        }
    }
#pragma unroll
    for (int pp = 0; pp < 2; ++pp) {
        __syncthreads();
        if (wm == pp) {
#pragma unroll
            for (int mi = 0; mi < 4; ++mi)
#pragma unroll
                for (int ni = 0; ni < 2; ++ni)
#pragma unroll
                    for (int r = 0; r < 4; ++r)
                        Csf[(mi * 16 + q * 4 + r) * 64 + wn * 32 + ni * 16 + c] = acc[mi][ni][r];
        }
        __syncthreads();
#pragma unroll
        for (int sp = 0; sp < 4; ++sp) {
            int row = sp * 16 + (tid >> 4);
            int col = (tid & 15) * 4;
            int grow = row0 + pp * 64 + row;
            float4 v = *(const float4*)&Csf[row * 64 + col];
            const float4 xr = *(const float4*)&X[(size_t)grow * E_DIM + n0 + col];
            const float4 bb = *(const float4*)&bo[n0 + col];
            float4 o = {v.x + bb.x + xr.x, v.y + bb.y + xr.y,
                        v.z + bb.z + xr.z, v.w + bb.w + xr.w};
            *(float4*)&Y[(size_t)grow * E_DIM + n0 + col] = o;
        }
    }
}

// ---------------------------------------------------------------------------
// LayerNorm per row.  grid (S), block 256
__global__ __launch_bounds__(256) void layernorm(
    const float* __restrict__ Y, const float* __restrict__ g,
    const float* __restrict__ b, float* __restrict__ out) {
    __shared__ float red[4];
    const int srow = blockIdx.x;
    const float* yr = Y + (size_t)srow * E_DIM;
    const int t = threadIdx.x;
    float xs[3];
    float sum = 0.f;
#pragma unroll
    for (int r = 0; r < 3; ++r) { xs[r] = yr[t + r * 256]; sum += xs[r]; }
#pragma unroll
    for (int off = 32; off; off >>= 1) sum += __shfl_down(sum, off, 64);
    if ((t & 63) == 0) red[t >> 6] = sum;
    __syncthreads();
    sum = red[0] + red[1] + red[2] + red[3];
    const float mu = sum * (1.f / 768.f);
    float vs = 0.f;
#pragma unroll
    for (int r = 0; r < 3; ++r) { float d = xs[r] - mu; vs += d * d; }
    __syncthreads();
#pragma unroll
    for (int off = 32; off; off >>= 1) vs += __shfl_down(vs, off, 64);
    if ((t & 63) == 0) red[t >> 6] = vs;
    __syncthreads();
    vs = red[0] + red[1] + red[2] + red[3];
    const float inv = rsqrtf(vs * (1.f / 768.f) + LN_EPS);
#pragma unroll
    for (int r = 0; r < 3; ++r) {
        int c = t + r * 256;
        out[(size_t)srow * E_DIM + c] = g[c] * (xs[r] - mu) * inv + b[c];
    }
}

// ---------------------------------------------------------------------------
extern "C" void kernel_launch(void* const* d_in, const int* in_sizes, int n_in,
                              void* d_out, int out_size, void* d_ws, size_t ws_size,
                              hipStream_t stream) {
    const float* X    = (const float*)d_in[0];
    const float* Wq   = (const float*)d_in[1];
    const float* bq   = (const float*)d_in[2];
    const float* Wk   = (const float*)d_in[3];
    const float* bk   = (const float*)d_in[4];
    const float* Wv   = (const float*)d_in[5];
    const float* bv   = (const float*)d_in[6];
    const float* Wo   = (const float*)d_in[7];
    const float* bo   = (const float*)d_in[8];
    const float* ln_g = (const float*)d_in[9];
    const float* ln_b = (const float*)d_in[10];
    float* out = (float*)d_out;

    char* p = (char*)d_ws;
    auto alloc = [&](size_t bytes) { char* r = p; p += (bytes + 255) & ~(size_t)255; return r; };
    unsigned short* Xb   = (unsigned short*)alloc((size_t)S_LEN * E_DIM * 2);
    unsigned short* Wt   = (unsigned short*)alloc((size_t)4 * E_DIM * E_DIM * 2);
    unsigned short* Qb   = (unsigned short*)alloc((size_t)NH * S_LEN * HD * 2);
    unsigned short* Kb   = (unsigned short*)alloc((size_t)NH * S_LEN * HD * 2);
    unsigned short* Vb   = (unsigned short*)alloc((size_t)NH * S_LEN * HD * 2);
    unsigned char*  E    = (unsigned char*)alloc((size_t)NH * S_LEN * S_LEN);   // 48 MB fp8
    float*          rp   = (float*)alloc((size_t)NH * 16 * S_LEN * 4);
    float*          av   = (float*)alloc((size_t)NH * S_LEN * 4);
    float*          bv_  = (float*)alloc((size_t)NH * S_LEN * 4);
    float*          tp   = (float*)alloc((size_t)NH * NCH * S_LEN * 4);         // 12 MB
    unsigned char*  Vt   = (unsigned char*)alloc((size_t)NH * HD * S_LEN);
    unsigned short* ctxb = (unsigned short*)alloc((size_t)S_LEN * E_DIM * 2);
    float*          Y    = (float*)alloc((size_t)S_LEN * E_DIM * 4);

    quant_x<<<S_LEN * E_DIM / 1024, 256, 0, stream>>>(X, Xb);
    quant_wt<<<dim3(24, 24, 4), 256, 0, stream>>>(Wq, Wk, Wv, Wo, Wt);
    qkv_gemm<<<dim3(36, 16), 256, 0, stream>>>(Xb, Wt, bq, bk, bv, Qb, Kb, Vb);
    score_exp<<<dim3(16, 32, NH), 256, 0, stream>>>(Qb, Kb, E, rp);

    // Sinkhorn: 3 fused passes, each reads E once from global
    sink_pass<<<dim3(NCH, NH), 256, 0, stream>>>(E, bv_, rp, nullptr, tp, 1);    // a1->tp
    col_combine<<<NH * S_LEN / 256, 256, 0, stream>>>(tp, bv_);                  // b1
    sink_pass<<<dim3(NCH, NH), 256, 0, stream>>>(E, bv_, rp, nullptr, tp, 0);    // a2->tp
    col_combine<<<NH * S_LEN / 256, 256, 0, stream>>>(tp, bv_);                  // b2
    sink_pass<<<dim3(NCH, NH), 256, 0, stream>>>(E, bv_, rp, av, tp, 0);         // a3->tp (+a3 out)
    col_combine_scale<<<dim3(S_LEN / 64, NH), 256, 0, stream>>>(tp, Vb, Vt);     // b3 + scale V

    attn_av<<<dim3(S_LEN / 32, NH), 256, 0, stream>>>(E, av, Vt, ctxb);
    out_gemm<<<dim3(12, 16), 256, 0, stream>>>(ctxb, Wt, bo, X, Y);
    layernorm<<<S_LEN, 256, 0, stream>>>(Y, ln_g, ln_b, out);
}

// Round 10
// 238.955 us; speedup vs baseline: 2.9038x; 1.0328x over previous
//
#include <hip/hip_runtime.h>
#include <math.h>

#define S_LEN 2048
#define E_DIM 768
#define NH    12
#define HD    64
#define MU    (1.0f/2048.0f)
#define LN_EPS 1e-12f
#define CH    16            // sink_pass chunk rows
#define NCH   (S_LEN/CH)    // 128 chunks

typedef __attribute__((ext_vector_type(8))) short bf16x8;   // 8 bf16 (4 VGPRs)
typedef __attribute__((ext_vector_type(4))) float f32x4;    // MFMA accumulator
typedef __attribute__((ext_vector_type(2))) float f32x2;
typedef long i64_t;                                          // 8 fp8 (2 VGPRs)

__device__ __forceinline__ unsigned short f2bf(float f) {   // RNE fp32->bf16
    unsigned u = __float_as_uint(f);
    u += 0x7fff + ((u >> 16) & 1);
    return (unsigned short)(u >> 16);
}
__device__ __forceinline__ float bf2f(unsigned short h) {
    return __uint_as_float(((unsigned)h) << 16);
}

// ---- fp8 e4m3 (OCP) helpers ----
__device__ __forceinline__ unsigned char fp8_enc(float f) {
#if __has_builtin(__builtin_amdgcn_cvt_pk_fp8_f32)
    return (unsigned char)(__builtin_amdgcn_cvt_pk_fp8_f32(f, f, 0, false) & 0xFF);
#else
    float m = fminf(fabsf(f), 448.f) * 0x1p-120f;
    unsigned b = __float_as_uint(m);
    unsigned s = (__float_as_uint(f) >> 24) & 0x80u;
    b += 0x7FFFFu + ((b >> 20) & 1u);
    return (unsigned char)(s | ((b >> 20) & 0x7Fu));
#endif
}
// pack 4 floats -> 4 fp8 bytes in one dword
__device__ __forceinline__ unsigned fp8_pack4(float e0, float e1, float e2, float e3) {
#if __has_builtin(__builtin_amdgcn_cvt_pk_fp8_f32)
    unsigned u = __builtin_amdgcn_cvt_pk_fp8_f32(e0, e1, 0, false);
    u = __builtin_amdgcn_cvt_pk_fp8_f32(e2, e3, u, true);
    return u;
#else
    return (unsigned)fp8_enc(e0) | ((unsigned)fp8_enc(e1) << 8) |
           ((unsigned)fp8_enc(e2) << 16) | ((unsigned)fp8_enc(e3) << 24);
#endif
}
__device__ __forceinline__ float fp8_dec1(unsigned char u) {
    unsigned bits = ((u & 0x80u) << 24) | ((u & 0x7Fu) << 20);
    return __uint_as_float(bits) * 0x1p+120f;
}
__device__ __forceinline__ f32x2 fp8_dec_lo(unsigned v) {
#if __has_builtin(__builtin_amdgcn_cvt_pk_f32_fp8)
    return __builtin_amdgcn_cvt_pk_f32_fp8(v, false);
#else
    f32x2 r; r.x = fp8_dec1(v & 0xFF); r.y = fp8_dec1((v >> 8) & 0xFF); return r;
#endif
}
__device__ __forceinline__ f32x2 fp8_dec_hi(unsigned v) {
#if __has_builtin(__builtin_amdgcn_cvt_pk_f32_fp8)
    return __builtin_amdgcn_cvt_pk_f32_fp8(v, true);
#else
    f32x2 r; r.x = fp8_dec1((v >> 16) & 0xFF); r.y = fp8_dec1(v >> 24); return r;
#endif
}

// ---- async global->LDS, 16 B per lane (dest = wave-uniform base + lane*16) ----
#if defined(__has_builtin)
#if __has_builtin(__builtin_amdgcn_global_load_lds)
#define HAS_GLL 1
#endif
#endif
#if HAS_GLL
__device__ __forceinline__ void gll16(const void* g, void* l) {
    __builtin_amdgcn_global_load_lds(
        (__attribute__((address_space(1))) void*)(void*)g,
        (__attribute__((address_space(3))) void*)l, 16, 0, 0);
}
#endif

// ---------------------------------------------------------------------------
__global__ __launch_bounds__(256) void quant_x(const float* __restrict__ X,
                                               unsigned short* __restrict__ Xb) {
    int i = blockIdx.x * 256 + threadIdx.x;
    const float4 v = ((const float4*)X)[i];
    ushort4 o = { f2bf(v.x), f2bf(v.y), f2bf(v.z), f2bf(v.w) };
    ((ushort4*)Xb)[i] = o;
}

// W[k][n] fp32 -> Wt[z][n][k] bf16.  grid (24,24,4), block 256
__global__ __launch_bounds__(256) void quant_wt(
    const float* __restrict__ W0, const float* __restrict__ W1,
    const float* __restrict__ W2, const float* __restrict__ W3,
    unsigned short* __restrict__ Wt) {
    const float* W = (blockIdx.z == 0) ? W0 : (blockIdx.z == 1) ? W1
                   : (blockIdx.z == 2) ? W2 : W3;
    __shared__ unsigned short t[32][33];
    const int n0 = blockIdx.x * 32, k0 = blockIdx.y * 32;
    const int c = threadIdx.x & 31, r8 = threadIdx.x >> 5;
#pragma unroll
    for (int rr = 0; rr < 32; rr += 8) {
        int k = k0 + r8 + rr;
        t[c][r8 + rr] = f2bf(W[(size_t)k * E_DIM + n0 + c]);
    }
    __syncthreads();
    unsigned short* out = Wt + (size_t)blockIdx.z * E_DIM * E_DIM;
#pragma unroll
    for (int rr = 0; rr < 32; rr += 8) {
        int n = n0 + r8 + rr;
        out[(size_t)n * E_DIM + k0 + c] = t[r8 + rr][c];
    }
}

// ---------------------------------------------------------------------------
// Fused QKV GEMM, global_load_lds staging, tile 128x64, BK=64.
// grid (36 n-tiles, 16 row-tiles), block 256.  All outputs bf16 [h][s][64].
__global__ __launch_bounds__(256) void qkv_gemm(
    const unsigned short* __restrict__ Xb, const unsigned short* __restrict__ Wt,
    const float* __restrict__ bq, const float* __restrict__ bk, const float* __restrict__ bv,
    unsigned short* __restrict__ Qb, unsigned short* __restrict__ Kb,
    unsigned short* __restrict__ Vb) {
    __shared__ unsigned short As[128 * 64];     // unpadded: required by gll
    __shared__ unsigned short Bs[64 * 64];
    const int n0 = blockIdx.x * 64;
    const int row0 = blockIdx.y * 128;
    const int tid = threadIdx.x;
    const int wave = tid >> 6, lane = tid & 63;
    const int wm = wave & 1, wn = wave >> 1;
    const int q = lane >> 4, c = lane & 15;
    const int lrow = lane >> 3, lk8 = (lane & 7) * 8;
    const unsigned short* Wb = Wt + (size_t)n0 * E_DIM;
    f32x4 acc[4][2] = {};
    for (int kt = 0; kt < E_DIM; kt += 64) {
        __syncthreads();
#if HAS_GLL
#pragma unroll
        for (int p = 0; p < 4; ++p)
            gll16(&Xb[(size_t)(row0 + p * 32 + wave * 8 + lrow) * E_DIM + kt + lk8],
                  &As[(p * 32 + wave * 8) * 64]);
#pragma unroll
        for (int p = 0; p < 2; ++p)
            gll16(&Wb[(size_t)(p * 32 + wave * 8 + lrow) * E_DIM + kt + lk8],
                  &Bs[(p * 32 + wave * 8) * 64]);
#else
        {
            uint4 ta[4], tb[2];
#pragma unroll
            for (int p = 0; p < 4; ++p)
                ta[p] = *(const uint4*)&Xb[(size_t)(row0 + p * 32 + wave * 8 + lrow) * E_DIM + kt + lk8];
#pragma unroll
            for (int p = 0; p < 2; ++p)
                tb[p] = *(const uint4*)&Wb[(size_t)(p * 32 + wave * 8 + lrow) * E_DIM + kt + lk8];
#pragma unroll
            for (int p = 0; p < 4; ++p) *(uint4*)&As[(p * 32 + wave * 8 + lrow) * 64 + lk8] = ta[p];
#pragma unroll
            for (int p = 0; p < 2; ++p) *(uint4*)&Bs[(p * 32 + wave * 8 + lrow) * 64 + lk8] = tb[p];
        }
#endif
        __syncthreads();
#pragma unroll
        for (int ks = 0; ks < 2; ++ks) {
            bf16x8 af[4], bfr[2];
#pragma unroll
            for (int mi = 0; mi < 4; ++mi)
                af[mi] = *(const bf16x8*)&As[(wm * 64 + mi * 16 + c) * 64 + ks * 32 + q * 8];
#pragma unroll
            for (int ni = 0; ni < 2; ++ni)
                bfr[ni] = *(const bf16x8*)&Bs[(wn * 32 + ni * 16 + c) * 64 + ks * 32 + q * 8];
#pragma unroll
            for (int mi = 0; mi < 4; ++mi)
#pragma unroll
                for (int ni = 0; ni < 2; ++ni)
                    acc[mi][ni] = __builtin_amdgcn_mfma_f32_16x16x32_bf16(
                        af[mi], bfr[ni], acc[mi][ni], 0, 0, 0);
        }
    }
    const int z = n0 / E_DIM;
    const int h = (n0 % E_DIM) >> 6;
    const float* bias = (z == 0) ? bq : (z == 1) ? bk : bv;
    unsigned short* outp = (z == 0) ? Qb : (z == 1) ? Kb : Vb;
    __syncthreads();
    unsigned short* Cs = As;                    // reuse 16 KB for repack
#pragma unroll
    for (int ni = 0; ni < 2; ++ni) {
        const int col = wn * 32 + ni * 16 + c;
        const float bb = bias[h * 64 + col];
#pragma unroll
        for (int mi = 0; mi < 4; ++mi)
#pragma unroll
            for (int r = 0; r < 4; ++r)
                Cs[(wm * 64 + mi * 16 + q * 4 + r) * 64 + col] = f2bf(acc[mi][ni][r] + bb);
    }
    __syncthreads();
#pragma unroll
    for (int pp = 0; pp < 4; ++pp) {
        int row = pp * 32 + (tid >> 3);
        *(uint4*)&outp[((size_t)h * S_LEN + row0 + row) * HD + (tid & 7) * 8] =
            *(const uint4*)&Cs[row * 64 + (tid & 7) * 8];
    }
}

// ---------------------------------------------------------------------------
// E = exp(QK^T/8) -> fp8.  SWAPPED operands (A=K, B=Q): D[m=j][n=i].
// grid (16 j-tiles(128), 32 i-tiles(64), 12 h), block 256.
__global__ __launch_bounds__(256) void score_exp(
    const unsigned short* __restrict__ Qb, const unsigned short* __restrict__ Kb,
    unsigned char* __restrict__ E, float* __restrict__ rp) {
    const int h = blockIdx.z;
    const int i0 = blockIdx.y * 64, j0 = blockIdx.x * 128;
    const int tid = threadIdx.x;
    const int wave = tid >> 6, lane = tid & 63;
    const int q = lane >> 4, c = lane & 15;
    __shared__ unsigned short Qs[64 * 64];
    __shared__ unsigned short Ks[128 * 64];
    __shared__ unsigned char  Es[64 * 144];     // row stride 144 B (pad: 2-way max)
    __shared__ float red[4][64];
    const unsigned short* Qh = Qb + (size_t)h * S_LEN * HD;
    const unsigned short* Kh = Kb + (size_t)h * S_LEN * HD;
    const int lrow = lane >> 3, lk8 = (lane & 7) * 8;
#if HAS_GLL
#pragma unroll
    for (int p = 0; p < 2; ++p)
        gll16(&Qh[(size_t)(i0 + p * 32 + wave * 8 + lrow) * HD + lk8],
              &Qs[(p * 32 + wave * 8) * 64]);
#pragma unroll
    for (int p = 0; p < 4; ++p)
        gll16(&Kh[(size_t)(j0 + p * 32 + wave * 8 + lrow) * HD + lk8],
              &Ks[(p * 32 + wave * 8) * 64]);
#else
    {
        uint4 tq[2], tk[4];
#pragma unroll
        for (int p = 0; p < 2; ++p)
            tq[p] = *(const uint4*)&Qh[(size_t)(i0 + p * 32 + wave * 8 + lrow) * HD + lk8];
#pragma unroll
        for (int p = 0; p < 4; ++p)
            tk[p] = *(const uint4*)&Kh[(size_t)(j0 + p * 32 + wave * 8 + lrow) * HD + lk8];
#pragma unroll
        for (int p = 0; p < 2; ++p) *(uint4*)&Qs[(p * 32 + wave * 8 + lrow) * 64 + lk8] = tq[p];
#pragma unroll
        for (int p = 0; p < 4; ++p) *(uint4*)&Ks[(p * 32 + wave * 8 + lrow) * 64 + lk8] = tk[p];
    }
#endif
    __syncthreads();
    f32x4 acc[2][4] = {};                       // [jt][it]; wave covers j = wave*32 + jt*16
#pragma unroll
    for (int dt = 0; dt < HD; dt += 32) {
        bf16x8 af[2], bq_[4];
#pragma unroll
        for (int jt = 0; jt < 2; ++jt)
            af[jt] = *(const bf16x8*)&Ks[(wave * 32 + jt * 16 + c) * 64 + dt + q * 8];
#pragma unroll
        for (int it = 0; it < 4; ++it)
            bq_[it] = *(const bf16x8*)&Qs[(it * 16 + c) * 64 + dt + q * 8];
#pragma unroll
        for (int jt = 0; jt < 2; ++jt)
#pragma unroll
            for (int it = 0; it < 4; ++it)
                acc[jt][it] = __builtin_amdgcn_mfma_f32_16x16x32_bf16(
                    af[jt], bq_[it], acc[jt][it], 0, 0, 0);
    }
    float rsum[4] = {0.f, 0.f, 0.f, 0.f};
#pragma unroll
    for (int jt = 0; jt < 2; ++jt)
#pragma unroll
        for (int it = 0; it < 4; ++it) {
            float e0 = __expf(acc[jt][it][0] * 0.125f);
            float e1 = __expf(acc[jt][it][1] * 0.125f);
            float e2 = __expf(acc[jt][it][2] * 0.125f);
            float e3 = __expf(acc[jt][it][3] * 0.125f);
            rsum[it] += (e0 + e1) + (e2 + e3);
            *(unsigned*)&Es[(it * 16 + c) * 144 + wave * 32 + jt * 16 + q * 4] =
                fp8_pack4(e0, e1, e2, e3);
        }
#pragma unroll
    for (int it = 0; it < 4; ++it) {
        rsum[it] += __shfl_xor(rsum[it], 16, 64);
        rsum[it] += __shfl_xor(rsum[it], 32, 64);
    }
    if (q == 0) {
#pragma unroll
        for (int it = 0; it < 4; ++it) red[wave][it * 16 + c] = rsum[it];
    }
    __syncthreads();
    {   // coalesced full-line E stores: 4 threads cover one 128-B row
        const int row = tid >> 2, off = (tid & 3) * 32;
        uint4 v0 = *(const uint4*)&Es[row * 144 + off];
        uint4 v1 = *(const uint4*)&Es[row * 144 + off + 16];
        unsigned char* dst = E + ((size_t)h * S_LEN + i0 + row) * S_LEN + j0 + off;
        *(uint4*)dst = v0;
        *(uint4*)(dst + 16) = v1;
    }
    if (tid < 64)
        rp[((size_t)h * 16 + blockIdx.x) * S_LEN + i0 + tid] =
            (red[0][tid] + red[1][tid]) + (red[2][tid] + red[3][tid]);
}

// ---------------------------------------------------------------------------
// Fused Sinkhorn pass, streaming (no E in LDS):
//   phase 1: a[i] = mu / (E·b)[i]  (rows direct global->VGPR, b in padded LDS)
//   phase 2: tp[h][chunk][j] = sum_i a[i]*E[i][j]  (re-read rows, L2-hot)
// grid (NCH=128, 12), block 256 (4 waves, 4 rows/wave).  LDS ~9 KB.
#define BPAD(j) ((j) + ((j) >> 4))              // +1 float pad per 16 -> conflict-free
__global__ __launch_bounds__(256) void sink_pass(
    const unsigned char* __restrict__ E, const float* __restrict__ bvec,
    const float* __restrict__ rp, float* __restrict__ aout,
    float* __restrict__ tpart, int use_rp) {
    __shared__ float lb[2048 + 128];            // padded b
    __shared__ float la[CH];
    const int h = blockIdx.y, chunk = blockIdx.x;
    const int tid = threadIdx.x, wave = tid >> 6, lane = tid & 63;
    const unsigned char* gbase = E + ((size_t)h * S_LEN + chunk * CH) * S_LEN;
    if (use_rp) {
        if (tid < CH) {
            float s = 0.f;
#pragma unroll
            for (int jt = 0; jt < 16; ++jt)
                s += rp[((size_t)h * 16 + jt) * S_LEN + chunk * CH + tid];
            la[tid] = MU / s;
        }
        __syncthreads();
    } else {
        {   // stage b (padded layout)
            const float* bg = bvec + (size_t)h * S_LEN;
#pragma unroll
            for (int p = 0; p < 8; ++p) {
                int j = p * 256 + tid;
                lb[BPAD(j)] = bg[j];
            }
        }
        __syncthreads();
        // phase 1: wave w -> rows w*4..w*4+3; lane covers j = lane*16 (+1024)
        const int jA = lane * 16, jB = 1024 + lane * 16;
        uint4 eA[4], eB[4];
#pragma unroll
        for (int rr = 0; rr < 4; ++rr) {
            const unsigned char* er = gbase + (size_t)(wave * 4 + rr) * S_LEN;
            eA[rr] = *(const uint4*)&er[jA];
            eB[rr] = *(const uint4*)&er[jB];
        }
        float bA[16], bB[16];
#pragma unroll
        for (int m = 0; m < 16; ++m) { bA[m] = lb[BPAD(jA + m)]; bB[m] = lb[BPAD(jB + m)]; }
#pragma unroll
        for (int rr = 0; rr < 4; ++rr) {
            float s = 0.f;
            unsigned wA[4] = {eA[rr].x, eA[rr].y, eA[rr].z, eA[rr].w};
            unsigned wB[4] = {eB[rr].x, eB[rr].y, eB[rr].z, eB[rr].w};
#pragma unroll
            for (int m = 0; m < 4; ++m) {
                f32x2 lo = fp8_dec_lo(wA[m]), hi = fp8_dec_hi(wA[m]);
                s += lo.x * bA[m*4] + lo.y * bA[m*4+1] + hi.x * bA[m*4+2] + hi.y * bA[m*4+3];
                lo = fp8_dec_lo(wB[m]); hi = fp8_dec_hi(wB[m]);
                s += lo.x * bB[m*4] + lo.y * bB[m*4+1] + hi.x * bB[m*4+2] + hi.y * bB[m*4+3];
            }
#pragma unroll
            for (int off = 32; off; off >>= 1) s += __shfl_xor(s, off, 64);
            if (lane == 0) la[wave * 4 + rr] = MU / s;
        }
        __syncthreads();
    }
    if (aout != nullptr && tid < CH)
        aout[(size_t)h * S_LEN + chunk * CH + tid] = la[tid];
    // phase 2: column partials; re-read rows from global (L2-hot), 8-batched
    {
        const int j0 = tid * 8;
        const unsigned char* eb = gbase + j0;
        float acc[8] = {};
#pragma unroll
        for (int g = 0; g < 2; ++g) {
            uint2 e[8];
#pragma unroll
            for (int r = 0; r < 8; ++r)
                e[r] = *(const uint2*)&eb[(size_t)(g * 8 + r) * S_LEN];
#pragma unroll
            for (int r = 0; r < 8; ++r) {
                float ar = la[g * 8 + r];
                f32x2 lo = fp8_dec_lo(e[r].x), hi = fp8_dec_hi(e[r].x);
                acc[0] += lo.x * ar; acc[1] += lo.y * ar; acc[2] += hi.x * ar; acc[3] += hi.y * ar;
                lo = fp8_dec_lo(e[r].y); hi = fp8_dec_hi(e[r].y);
                acc[4] += lo.x * ar; acc[5] += lo.y * ar; acc[6] += hi.x * ar; acc[7] += hi.y * ar;
            }
        }
        float* outp = tpart + ((size_t)h * NCH + chunk) * S_LEN + j0;
        float4 o0 = {acc[0], acc[1], acc[2], acc[3]};
        float4 o1 = {acc[4], acc[5], acc[6], acc[7]};
        *(float4*)&outp[0] = o0;
        *(float4*)&outp[4] = o1;
    }
}

// b[h][j] = mu / sum_chunk tp.  grid (NH*S/256), block 256
__global__ __launch_bounds__(256) void col_combine(
    const float* __restrict__ tpart, float* __restrict__ bout) {
    int g = blockIdx.x * 256 + threadIdx.x;
    int h = g >> 11, j = g & 2047;
    float s = 0.f;
#pragma unroll 8
    for (int c = 0; c < NCH; ++c) s += tpart[((size_t)h * NCH + c) * S_LEN + j];
    bout[g] = MU / s;
}

// ---------------------------------------------------------------------------
// Fused b3-combine + V scaling: b[j]=mu/sum tp, V't[h][d][j]=fp8(b[j]*V[j][d])
// grid (S/64 = 32, 12), block 256
__global__ __launch_bounds__(256) void col_combine_scale(
    const float* __restrict__ tpart, const unsigned short* __restrict__ Vb,
    unsigned char* __restrict__ Vt) {
    const int h = blockIdx.y, j0 = blockIdx.x * 64;
    __shared__ float lb[64];
    __shared__ unsigned char t[64][80];
    {
        int j = threadIdx.x >> 2, seg = threadIdx.x & 3;
        float s = 0.f;
#pragma unroll
        for (int cc = 0; cc < NCH / 4; ++cc)
            s += tpart[((size_t)h * NCH + seg * (NCH / 4) + cc) * S_LEN + j0 + j];
        s += __shfl_down(s, 2, 4);
        s += __shfl_down(s, 1, 4);
        if (seg == 0) lb[j] = MU / s;
    }
    __syncthreads();
    {
        const int r = threadIdx.x >> 2, dc = (threadIdx.x & 3) * 16;
        float bj = lb[r];
        const unsigned short* vrow = Vb + ((size_t)h * S_LEN + j0 + r) * HD + dc;
#pragma unroll
        for (int k = 0; k < 16; ++k) t[dc + k][r] = fp8_enc(bf2f(vrow[k]) * bj);
    }
    __syncthreads();
    const int d = threadIdx.x >> 2, jc = (threadIdx.x & 3) * 16;
    unsigned char* out = Vt + ((size_t)h * HD + d) * S_LEN + j0 + jc;
    *(uint4*)out = *(const uint4*)&t[d][jc];
}

// ---------------------------------------------------------------------------
// ctx[i][h*64+d] = a_i*n * sum_j E[h][i][j]*V't[h][d][j].  fp8 MFMA.
// 32 i-rows/block (2 i-tiles/wave, V-frags shared), 4-way j-split,
// 2-stage pipeline with 12 loads in flight.  grid (64, 12), block 256.
__global__ __launch_bounds__(256) void attn_av(
    const unsigned char* __restrict__ E, const float* __restrict__ a,
    const unsigned char* __restrict__ Vt, unsigned short* __restrict__ ctxb) {
    const int h = blockIdx.y;
    const int wave = threadIdx.x >> 6, lane = threadIdx.x & 63;
    const int q = lane >> 4, c = lane & 15;
    const int i0 = blockIdx.x * 32;
    const unsigned char* e0 = E + (size_t)h * S_LEN * S_LEN + (size_t)(i0 + c) * S_LEN;
    const unsigned char* e1 = e0 + (size_t)16 * S_LEN;
    const unsigned char* Vh = Vt + (size_t)h * HD * S_LEN;
    const int jb = wave * 512;
    f32x4 acc[2][4] = {};
    i64_t eN[2][2], vN[4][2];
#pragma unroll
    for (int kk = 0; kk < 2; ++kk) {
        eN[0][kk] = *(const i64_t*)&e0[jb + kk * 32 + q * 8];
        eN[1][kk] = *(const i64_t*)&e1[jb + kk * 32 + q * 8];
#pragma unroll
        for (int s = 0; s < 4; ++s)
            vN[s][kk] = *(const i64_t*)&Vh[(size_t)(s * 16 + c) * S_LEN + jb + kk * 32 + q * 8];
    }
    for (int jt = jb; jt < jb + 512; jt += 64) {
        i64_t eC[2][2], vC[4][2];
#pragma unroll
        for (int kk = 0; kk < 2; ++kk) {
            eC[0][kk] = eN[0][kk]; eC[1][kk] = eN[1][kk];
#pragma unroll
            for (int s = 0; s < 4; ++s) vC[s][kk] = vN[s][kk];
        }
        if (jt + 64 < jb + 512) {
            const int jn = jt + 64;
#pragma unroll
            for (int kk = 0; kk < 2; ++kk) {
                eN[0][kk] = *(const i64_t*)&e0[jn + kk * 32 + q * 8];
                eN[1][kk] = *(const i64_t*)&e1[jn + kk * 32 + q * 8];
#pragma unroll
                for (int s = 0; s < 4; ++s)
                    vN[s][kk] = *(const i64_t*)&Vh[(size_t)(s * 16 + c) * S_LEN + jn + kk * 32 + q * 8];
            }
        }
#pragma unroll
        for (int kk = 0; kk < 2; ++kk)
#pragma unroll
            for (int it = 0; it < 2; ++it)
#pragma unroll
                for (int s = 0; s < 4; ++s)
                    acc[it][s] = __builtin_amdgcn_mfma_f32_16x16x32_fp8_fp8(
                        eC[it][kk], vC[s][kk], acc[it][s], 0, 0, 0);
    }
    __shared__ float lred[3][2][16][64];        // 24 KB
    if (wave != 0) {
#pragma unroll
        for (int it = 0; it < 2; ++it)
#pragma unroll
            for (int s = 0; s < 4; ++s)
#pragma unroll
                for (int r = 0; r < 4; ++r)
                    lred[wave - 1][it][s * 4 + r][lane] = acc[it][s][r];
    }
    __syncthreads();
    if (wave == 0) {
#pragma unroll
        for (int it = 0; it < 2; ++it) {
            float ais[4];
#pragma unroll
            for (int r = 0; r < 4; ++r)
                ais[r] = a[(size_t)h * S_LEN + i0 + it * 16 + q * 4 + r] * 2048.f;
#pragma unroll
            for (int s = 0; s < 4; ++s)
#pragma unroll
                for (int r = 0; r < 4; ++r) {
                    float v = acc[it][s][r] +
                              ((lred[0][it][s * 4 + r][lane] + lred[1][it][s * 4 + r][lane]) +
                               lred[2][it][s * 4 + r][lane]);
                    ctxb[(size_t)(i0 + it * 16 + q * 4 + r) * E_DIM + h * 64 + s * 16 + c] =
                        f2bf(v * ais[r]);
                }
        }
    }
}

// ---------------------------------------------------------------------------
// Y = ctx @ Wo + bo + X (fp32), gll staging, tile 128x64.  grid (12, 16), 256
__global__ __launch_bounds__(256) void out_gemm(
    const unsigned short* __restrict__ ctxb, const unsigned short* __restrict__ Wt,
    const float* __restrict__ bo, const float* __restrict__ X, float* __restrict__ Y) {
    __shared__ unsigned short As[128 * 64];
    __shared__ unsigned short Bs[64 * 64];
    __shared__ float Csf[64 * 64];
    const int n0 = blockIdx.x * 64;
    const int row0 = blockIdx.y * 128;
    const int tid = threadIdx.x;
    const int wave = tid >> 6, lane = tid & 63;
    const int wm = wave & 1, wn = wave >> 1;
    const int q = lane >> 4, c = lane & 15;
    const int lrow = lane >> 3, lk8 = (lane & 7) * 8;
    const unsigned short* Wo3 = Wt + (size_t)3 * E_DIM * E_DIM + (size_t)n0 * E_DIM;
    f32x4 acc[4][2] = {};
    for (int kt = 0; kt < E_DIM; kt += 64) {
        __syncthreads();
#if HAS_GLL
#pragma unroll
        for (int p = 0; p < 4; ++p)
            gll16(&ctxb[(size_t)(row0 + p * 32 + wave * 8 + lrow) * E_DIM + kt + lk8],
                  &As[(p * 32 + wave * 8) * 64]);
#pragma unroll
        for (int p = 0; p < 2; ++p)
            gll16(&Wo3[(size_t)(p * 32 + wave * 8 + lrow) * E_DIM + kt + lk8],
                  &Bs[(p * 32 + wave * 8) * 64]);
#else
        {
            uint4 ta[4], tb[2];
#pragma unroll
            for (int p = 0; p < 4; ++p)
                ta[p] = *(const uint4*)&ctxb[(size_t)(row0 + p * 32 + wave * 8 + lrow) * E_DIM + kt + lk8];
#pragma unroll
            for (int p = 0; p < 2; ++p)
                tb[p] = *(const uint4*)&Wo3[(size_t)(p * 32 + wave * 8 + lrow) * E_DIM + kt + lk8];
#pragma unroll
            for (int p = 0; p < 4; ++p) *(uint4*)&As[(p * 32 + wave * 8 + lrow) * 64 + lk8] = ta[p];
#pragma unroll
            for (int p = 0; p < 2; ++p) *(uint4*)&Bs[(p * 32 + wave * 8 + lrow) * 64 + lk8] = tb[p];
        }
#endif
        __syncthreads();
#pragma unroll
        for (int ks = 0; ks < 2; ++ks) {
            bf16x8 af[4], bfr[2];
#pragma unroll
            for (int mi = 0; mi < 4; ++mi)
                af[mi] = *(const bf16x8*)&As[(wm * 64 + mi * 16 + c) * 64 + ks * 32 + q * 8];
#pragma unroll
            for (int ni = 0; ni < 2; ++ni)
                bfr[ni] = *(const bf16x8*)&Bs[(wn * 32 + ni * 16 + c) * 64 + ks * 32 + q * 8];
#pragma unroll
            for (int mi = 0; mi < 4; ++mi)
#pragma unroll
                for (int ni = 0; ni < 2; ++ni)
                    acc[mi][ni] = __builtin_amdgcn_mfma_f32_16x16x32_bf16(
                        af[mi], bfr[ni], acc[mi][ni], 0, 0, 0);
        }
    }
#pragma unroll
    for (int pp = 0; pp < 2; ++pp) {
        __syncthreads();
        if (wm == pp) {
#pragma unroll
            for (int mi = 0; mi < 4; ++mi)
#pragma unroll
                for (int ni = 0; ni < 2; ++ni)
#pragma unroll
                    for (int r = 0; r < 4; ++r)
                        Csf[(mi * 16 + q * 4 + r) * 64 + wn * 32 + ni * 16 + c] = acc[mi][ni][r];
        }
        __syncthreads();
#pragma unroll
        for (int sp = 0; sp < 4; ++sp) {
            int row = sp * 16 + (tid >> 4);
            int col = (tid & 15) * 4;
            int grow = row0 + pp * 64 + row;
            float4 v = *(const float4*)&Csf[row * 64 + col];
            const float4 xr = *(const float4*)&X[(size_t)grow * E_DIM + n0 + col];
            const float4 bb = *(const float4*)&bo[n0 + col];
            float4 o = {v.x + bb.x + xr.x, v.y + bb.y + xr.y,
                        v.z + bb.z + xr.z, v.w + bb.w + xr.w};
            *(float4*)&Y[(size_t)grow * E_DIM + n0 + col] = o;
        }
    }
}

// ---------------------------------------------------------------------------
// LayerNorm per row.  grid (S), block 256
__global__ __launch_bounds__(256) void layernorm(
    const float* __restrict__ Y, const float* __restrict__ g,
    const float* __restrict__ b, float* __restrict__ out) {
    __shared__ float red[4];
    const int srow = blockIdx.x;
    const float* yr = Y + (size_t)srow * E_DIM;
    const int t = threadIdx.x;
    float xs[3];
    float sum = 0.f;
#pragma unroll
    for (int r = 0; r < 3; ++r) { xs[r] = yr[t + r * 256]; sum += xs[r]; }
#pragma unroll
    for (int off = 32; off; off >>= 1) sum += __shfl_down(sum, off, 64);
    if ((t & 63) == 0) red[t >> 6] = sum;
    __syncthreads();
    sum = red[0] + red[1] + red[2] + red[3];
    const float mu = sum * (1.f / 768.f);
    float vs = 0.f;
#pragma unroll
    for (int r = 0; r < 3; ++r) { float d = xs[r] - mu; vs += d * d; }
    __syncthreads();
#pragma unroll
    for (int off = 32; off; off >>= 1) vs += __shfl_down(vs, off, 64);
    if ((t & 63) == 0) red[t >> 6] = vs;
    __syncthreads();
    vs = red[0] + red[1] + red[2] + red[3];
    const float inv = rsqrtf(vs * (1.f / 768.f) + LN_EPS);
#pragma unroll
    for (int r = 0; r < 3; ++r) {
        int c = t + r * 256;
        out[(size_t)srow * E_DIM + c] = g[c] * (xs[r] - mu) * inv + b[c];
    }
}

// ---------------------------------------------------------------------------
extern "C" void kernel_launch(void* const* d_in, const int* in_sizes, int n_in,
                              void* d_out, int out_size, void* d_ws, size_t ws_size,
                              hipStream_t stream) {
    const float* X    = (const float*)d_in[0];
    const float* Wq   = (const float*)d_in[1];
    const float* bq   = (const float*)d_in[2];
    const float* Wk   = (const float*)d_in[3];
    const float* bk   = (const float*)d_in[4];
    const float* Wv   = (const float*)d_in[5];
    const float* bv   = (const float*)d_in[6];
    const float* Wo   = (const float*)d_in[7];
    const float* bo   = (const float*)d_in[8];
    const float* ln_g = (const float*)d_in[9];
    const float* ln_b = (const float*)d_in[10];
    float* out = (float*)d_out;

    char* p = (char*)d_ws;
    auto alloc = [&](size_t bytes) { char* r = p; p += (bytes + 255) & ~(size_t)255; return r; };
    unsigned short* Xb   = (unsigned short*)alloc((size_t)S_LEN * E_DIM * 2);
    unsigned short* Wt   = (unsigned short*)alloc((size_t)4 * E_DIM * E_DIM * 2);
    unsigned short* Qb   = (unsigned short*)alloc((size_t)NH * S_LEN * HD * 2);
    unsigned short* Kb   = (unsigned short*)alloc((size_t)NH * S_LEN * HD * 2);
    unsigned short* Vb   = (unsigned short*)alloc((size_t)NH * S_LEN * HD * 2);
    unsigned char*  E    = (unsigned char*)alloc((size_t)NH * S_LEN * S_LEN);   // 48 MB fp8
    float*          rp   = (float*)alloc((size_t)NH * 16 * S_LEN * 4);
    float*          av   = (float*)alloc((size_t)NH * S_LEN * 4);
    float*          bv_  = (float*)alloc((size_t)NH * S_LEN * 4);
    float*          tp   = (float*)alloc((size_t)NH * NCH * S_LEN * 4);         // 12 MB
    unsigned char*  Vt   = (unsigned char*)alloc((size_t)NH * HD * S_LEN);
    unsigned short* ctxb = (unsigned short*)alloc((size_t)S_LEN * E_DIM * 2);
    float*          Y    = (float*)alloc((size_t)S_LEN * E_DIM * 4);

    quant_x<<<S_LEN * E_DIM / 1024, 256, 0, stream>>>(X, Xb);
    quant_wt<<<dim3(24, 24, 4), 256, 0, stream>>>(Wq, Wk, Wv, Wo, Wt);
    qkv_gemm<<<dim3(36, 16), 256, 0, stream>>>(Xb, Wt, bq, bk, bv, Qb, Kb, Vb);
    score_exp<<<dim3(16, 32, NH), 256, 0, stream>>>(Qb, Kb, E, rp);

    // Sinkhorn: 3 fused streaming passes
    sink_pass<<<dim3(NCH, NH), 256, 0, stream>>>(E, bv_, rp, nullptr, tp, 1);    // a1->tp
    col_combine<<<NH * S_LEN / 256, 256, 0, stream>>>(tp, bv_);                  // b1
    sink_pass<<<dim3(NCH, NH), 256, 0, stream>>>(E, bv_, rp, nullptr, tp, 0);    // a2->tp
    col_combine<<<NH * S_LEN / 256, 256, 0, stream>>>(tp, bv_);                  // b2
    sink_pass<<<dim3(NCH, NH), 256, 0, stream>>>(E, bv_, rp, av, tp, 0);         // a3->tp (+a3 out)
    col_combine_scale<<<dim3(S_LEN / 64, NH), 256, 0, stream>>>(tp, Vb, Vt);     // b3 + scale V

    attn_av<<<dim3(S_LEN / 32, NH), 256, 0, stream>>>(E, av, Vt, ctxb);
    out_gemm<<<dim3(12, 16), 256, 0, stream>>>(ctxb, Wt, bo, X, Y);
    layernorm<<<S_LEN, 256, 0, stream>>>(Y, ln_g, ln_b, out);
}